// Round 12
// baseline (463.892 us; speedup 1.0000x reference)
//
#include <hip/hip_runtime.h>

typedef unsigned short u16;
typedef unsigned int u32;
typedef float f32x4 __attribute__((ext_vector_type(4)));
typedef float f32x16 __attribute__((ext_vector_type(16)));
typedef __bf16 bf16x8 __attribute__((ext_vector_type(8)));

#define MFMA16(a, b, c) __builtin_amdgcn_mfma_f32_16x16x32_bf16(a, b, c, 0, 0, 0)
#define MFMA32(a, b, c) __builtin_amdgcn_mfma_f32_32x32x16_bf16(a, b, c, 0, 0, 0)
#define PLSWAP(x, y) asm volatile("v_permlane32_swap_b32 %0, %1" : "+v"(x), "+v"(y))
#define CFENCE() asm volatile("" ::: "memory")
#define BAR()                         \
    {                                 \
        CFENCE();                     \
        __builtin_amdgcn_s_barrier(); \
        CFENCE();                     \
    }
#define WAITV(n) asm volatile("s_waitcnt vmcnt(" #n ")" ::: "memory")

__device__ __forceinline__ u16 f2b(float f) {
    u32 u = __builtin_bit_cast(u32, f);
    u += 0x7fffu + ((u >> 16) & 1u);   // round-to-nearest-even
    return (u16)(u >> 16);
}

__device__ __forceinline__ u32 pk2(float a, float b) {
    union { u32 u; __bf16 h[2]; } r;
    r.h[0] = (__bf16)a; r.h[1] = (__bf16)b;
    return r.u;   // v_cvt_pk_bf16_f32
}

__device__ __forceinline__ void gload16(const u16* g, u16* l) {
    __builtin_amdgcn_global_load_lds((const __attribute__((address_space(1))) void*)g,
                                     (__attribute__((address_space(3))) void*)l, 16, 0, 0);
}

// ---------------- weight transpose + f32->bf16 convert (all 10 in one launch) ----------------
struct W10 { const float* p[10]; };
__global__ __launch_bounds__(256) void tcvt_k(W10 wp, u16* __restrict__ WT0) {
    const float* __restrict__ Wm = wp.p[blockIdx.z];
    u16* __restrict__ WT = WT0 + (size_t)blockIdx.z * 1048576;
    __shared__ float t[32][33];
    int bx = blockIdx.x, by = blockIdx.y;
    int tx = threadIdx.x, ty = threadIdx.y;   // (32,8)
#pragma unroll
    for (int j = 0; j < 32; j += 8)
        t[ty + j][tx] = Wm[(size_t)(by * 32 + ty + j) * 1024 + bx * 32 + tx];
    __syncthreads();
#pragma unroll
    for (int j = 0; j < 32; j += 8)
        WT[(size_t)(bx * 32 + ty + j) * 1024 + by * 32 + tx] = f2b(t[tx][ty + j]);
}

// ---------------- per-batch V transpose: V[b][key][c] -> VT[b][c][key]  (c = h*64+dh) ----------------
__global__ __launch_bounds__(256) void vtr_k(const u16* __restrict__ Vg, int ldv, u16* __restrict__ VT) {
    __shared__ u16 t[32][34];
    int bx = blockIdx.x, by = blockIdx.y, b = blockIdx.z;
    int tx = threadIdx.x, ty = threadIdx.y;   // (32,8)
#pragma unroll
    for (int j = 0; j < 32; j += 8)
        t[ty + j][tx] = Vg[(size_t)(b * 1024 + by * 32 + ty + j) * ldv + bx * 32 + tx];
    __syncthreads();
#pragma unroll
    for (int j = 0; j < 32; j += 8)
        VT[(size_t)(b * 1024 + bx * 32 + ty + j) * 1024 + by * 32 + tx] = t[tx][ty + j];
}

// ---------------- fused LayerNorm (r9 proven version: block-per-row) ----------------
// MODE bit0: x = in1 + in2 ; bit1: write f32 out (bit3: += post) ; bit2: write bf16 out
template <int MODE>
__global__ __launch_bounds__(256) void ln_k(const float* __restrict__ in1, const float* __restrict__ in2,
                                            const float* __restrict__ gg, const float* __restrict__ bb,
                                            const float* __restrict__ post,
                                            float* __restrict__ of, u16* __restrict__ ob) {
    int row = blockIdx.x, tid = threadIdx.x;
    size_t base = (size_t)row * 1024 + tid * 4;
    float4 x = *(const float4*)(in1 + base);
    if constexpr (MODE & 1) {
        float4 x2 = *(const float4*)(in2 + base);
        x.x += x2.x; x.y += x2.y; x.z += x2.z; x.w += x2.w;
    }
    float s1 = x.x + x.y + x.z + x.w;
    float s2 = x.x * x.x + x.y * x.y + x.z * x.z + x.w * x.w;
#pragma unroll
    for (int m = 32; m >= 1; m >>= 1) { s1 += __shfl_xor(s1, m); s2 += __shfl_xor(s2, m); }
    __shared__ float r1[4], r2[4];
    int lane = tid & 63, w = tid >> 6;
    if (lane == 0) { r1[w] = s1; r2[w] = s2; }
    __syncthreads();
    s1 = r1[0] + r1[1] + r1[2] + r1[3];
    s2 = r2[0] + r2[1] + r2[2] + r2[3];
    float mean = s1 * (1.0f / 1024.0f);
    float var = s2 * (1.0f / 1024.0f) - mean * mean;
    float rstd = rsqrtf(var + 1e-5f);
    float4 gv = *(const float4*)(gg + tid * 4);
    float4 bv = *(const float4*)(bb + tid * 4);
    float y0 = (x.x - mean) * rstd * gv.x + bv.x;
    float y1 = (x.y - mean) * rstd * gv.y + bv.y;
    float y2 = (x.z - mean) * rstd * gv.z + bv.z;
    float y3 = (x.w - mean) * rstd * gv.w + bv.w;
    if constexpr (MODE & 2) {
        float o0 = y0, o1 = y1, o2 = y2, o3 = y3;
        if constexpr (MODE & 8) {
            float4 p = *(const float4*)(post + base);
            o0 += p.x; o1 += p.y; o2 += p.z; o3 += p.w;
        }
        float4 o; o.x = o0; o.y = o1; o.z = o2; o.w = o3;
        *(float4*)(of + base) = o;
    }
    if constexpr (MODE & 4) {
        uint2 pk;
        pk.x = (u32)f2b(y0) | ((u32)f2b(y1) << 16);
        pk.y = (u32)f2b(y2) | ((u32)f2b(y3) << 16);
        *(uint2*)(ob + base) = pk;
    }
}

// ---------------- bf16 GEMM v512: BM=256/BN=128, 8 waves, phase-split, 3-slot 72KB ring ----------------
template <int EPI, int WN, int NBN>
__global__ __launch_bounds__(512) void gemm512_k(const u16* __restrict__ A, int lda,
                                                 const u16* __restrict__ WT,
                                                 const float* __restrict__ b0, const float* __restrict__ b1,
                                                 const float* __restrict__ b2,
                                                 float sc0, float sc1, float sc2,
                                                 const float* __restrict__ res,
                                                 void* __restrict__ outp, int ldc) {
    constexpr int ASZ = 8192;
    constexpr int BSZ = (WN == 4) ? 8192 : 4096;
    constexpr int SLOT = ASZ + BSZ;
    constexpr int MR = (WN == 4) ? 8 : 4;
    constexpr int WRS = (WN == 4) ? 128 : 64;
    __shared__ u16 lds[3 * SLOT];
    u16* ldsb = &lds[0];

    int id = blockIdx.x;
    constexpr int NWG = 32 * NBN;
    constexpr int CPX = NWG / 8;
    int swz = (id & 7) * CPX + (id >> 3);
    int bm = swz / NBN, bn = swz % NBN;
    const int m0 = bm * 256, n0 = bn * (WN * 64);
    int tid = threadIdx.x, lane = tid & 63, w = tid >> 6;
    int col = lane & 15, fg = lane >> 4;
    int wr = (WN == 4) ? (w >> 2) : (w >> 1);
    int wc = w & (WN - 1);

    int swzL = ((col * 32) + fg * 8) ^ ((col >> 1) << 3);
    int aoff0 = wr * WRS * 32 + swzL;
    int boff0 = ASZ + wc * 64 * 32 + swzL;

    int r = tid >> 2, g = tid & 3;
    int gr = r ^ ((r >> 3) & 1);
    int gc = g ^ ((r >> 1) & 3);
    const u16* pA = A + (size_t)(m0 + gr) * lda + gc * 8;
    const u16* pB = WT + (size_t)(n0 + gr) * 1024 + gc * 8;

#define STGA(t2, snO)                                                                 \
    {                                                                                 \
        gload16(pA + (size_t)(t2) * 32, ldsb + (snO) + w * 512);                      \
        gload16(pA + (size_t)(t2) * 32 + (size_t)128 * lda, ldsb + (snO) + 4096 + w * 512); \
    }
#define STGB(t2, snO)                                                                 \
    {                                                                                 \
        gload16(pB + (size_t)(t2) * 32, ldsb + (snO) + ASZ + w * 512);                \
        if constexpr (WN == 4) {                                                      \
            gload16(pB + (size_t)(t2) * 32 + (size_t)128 * 1024, ldsb + (snO) + ASZ + 4096 + w * 512); \
        }                                                                             \
    }

    f32x4 acc[MR][4];
#pragma unroll
    for (int m = 0; m < MR; m++)
#pragma unroll
        for (int n = 0; n < 4; n++) acc[m][n] = (f32x4){0.f, 0.f, 0.f, 0.f};

    STGA(0, 0); STGB(0, 0);
    STGA(1, SLOT); STGB(1, SLOT);
    if constexpr (WN == 4) { WAITV(4); } else { WAITV(3); }
    BAR();

    int sc = 0, sn = 2;
    for (int t = 0; t < 32; ++t) {
        int sCur = sc * SLOT, sNxt = sn * SLOT;
        bf16x8 a0[4], bfv[WN];
#pragma unroll
        for (int m = 0; m < 4; m++) a0[m] = *(const bf16x8*)&ldsb[sCur + aoff0 + m * 512];
#pragma unroll
        for (int n = 0; n < WN; n++) bfv[n] = *(const bf16x8*)&ldsb[sCur + boff0 + n * 512];
        if (t < 30) STGA(t + 2, sNxt);
        BAR();
        __builtin_amdgcn_s_setprio(1);
#pragma unroll
        for (int m = 0; m < 4; m++)
#pragma unroll
            for (int n = 0; n < WN; n++) acc[m][n] = MFMA16(a0[m], bfv[n], acc[m][n]);
        __builtin_amdgcn_s_setprio(0);
        BAR();
        if constexpr (WN == 4) {
            bf16x8 a1[4];
#pragma unroll
            for (int m = 0; m < 4; m++) a1[m] = *(const bf16x8*)&ldsb[sCur + aoff0 + (m + 4) * 512];
            if (t < 30) STGB(t + 2, sNxt);
            BAR();
            __builtin_amdgcn_s_setprio(1);
#pragma unroll
            for (int m = 0; m < 4; m++)
#pragma unroll
                for (int n = 0; n < 4; n++) acc[m + 4][n] = MFMA16(a1[m], bfv[n], acc[m + 4][n]);
            __builtin_amdgcn_s_setprio(0);
            if (t < 30) { WAITV(4); } else if (t == 30) { WAITV(0); }
            BAR();
        } else {
            bf16x8 b2[2];
#pragma unroll
            for (int n = 0; n < 2; n++) b2[n] = *(const bf16x8*)&ldsb[sCur + boff0 + (n + 2) * 512];
            if (t < 30) STGB(t + 2, sNxt);
            BAR();
            __builtin_amdgcn_s_setprio(1);
#pragma unroll
            for (int m = 0; m < 4; m++)
#pragma unroll
                for (int n = 0; n < 2; n++) acc[m][n + 2] = MFMA16(a0[m], b2[n], acc[m][n + 2]);
            __builtin_amdgcn_s_setprio(0);
            if (t < 30) { WAITV(3); } else if (t == 30) { WAITV(0); }
            BAR();
        }
        sc = (sc == 2) ? 0 : sc + 1;
        sn = (sn == 2) ? 0 : sn + 1;
    }
#undef STGA
#undef STGB

    int seg = n0 >> 10;
    const float* bp = (seg == 0) ? b0 : (seg == 1 ? b1 : b2);
    float sg = (seg == 0) ? sc0 : (seg == 1 ? sc1 : sc2);
    int nseg = n0 & 1023;
    float bv[4];
#pragma unroll
    for (int n = 0; n < 4; n++) bv[n] = bp[nseg + wc * 64 + n * 16 + col];
#pragma unroll
    for (int m = 0; m < MR; m++) {
#pragma unroll
        for (int rr = 0; rr < 4; rr++) {
            int row = m0 + wr * WRS + m * 16 + fg * 4 + rr;
#pragma unroll
            for (int n = 0; n < 4; n++) {
                int c = n0 + wc * 64 + n * 16 + col;
                size_t idx = (size_t)row * ldc + c;
                float v = (acc[m][n][rr] + bv[n]) * sg;
                if constexpr (EPI == 0) ((u16*)outp)[idx] = f2b(v);
                else if constexpr (EPI == 1) ((u16*)outp)[idx] = f2b(fmaxf(v, 0.f));
                else if constexpr (EPI == 2) ((float*)outp)[idx] = v + res[idx];
            }
        }
    }
}

// ---------------- bf16 GEMM v256: BM=128/BN=128, 4 waves, 3-slot 48KB ring (best for N=1024) ----------------
template <int EPI, int NBN>
__global__ __launch_bounds__(256) void gemm256_k(const u16* __restrict__ A, int lda,
                                                 const u16* __restrict__ WT,
                                                 const float* __restrict__ b0,
                                                 float sc0,
                                                 const float* __restrict__ res,
                                                 void* __restrict__ outp, int ldc) {
    constexpr int SLOT = 8192;
    __shared__ u16 lds[3 * SLOT];
    int id = blockIdx.x;
    constexpr int NWG = 64 * NBN;
    constexpr int CPX = NWG / 8;
    int swz = (id & 7) * CPX + (id >> 3);
    int bm = swz / NBN, bn = swz % NBN;
    const int m0 = bm * 128, n0 = bn * 128;
    int tid = threadIdx.x, lane = tid & 63, w = tid >> 6;
    int col = lane & 15, fg = lane >> 4;
    int wr = w >> 1, wc = w & 1;

    int swzL = ((col * 32) + fg * 8) ^ ((col >> 1) << 3);
    int aoff0 = wr * 64 * 32 + swzL;
    int boff0 = 4096 + wc * 64 * 32 + swzL;

    int r = tid >> 2, g = tid & 3;
    int gr = r ^ ((r >> 3) & 1);
    int gc = g ^ ((r >> 1) & 3);
    const u16* pA = A + (size_t)(m0 + gr) * lda + gc * 8;
    const u16* pB = WT + (size_t)(n0 + gr) * 1024 + gc * 8;

#define STGA(t2, snO)                                                                     \
    {                                                                                     \
        gload16(pA + (size_t)(t2) * 32, lds + (snO) + w * 512);                           \
        gload16(pA + (size_t)(t2) * 32 + (size_t)64 * lda, lds + (snO) + 2048 + w * 512); \
    }
#define STGB(t2, snO)                                                                             \
    {                                                                                             \
        gload16(pB + (size_t)(t2) * 32, lds + (snO) + 4096 + w * 512);                            \
        gload16(pB + (size_t)(t2) * 32 + (size_t)64 * 1024, lds + (snO) + 4096 + 2048 + w * 512); \
    }

    f32x4 acc[4][4];
#pragma unroll
    for (int m = 0; m < 4; m++)
#pragma unroll
        for (int n = 0; n < 4; n++) acc[m][n] = (f32x4){0.f, 0.f, 0.f, 0.f};

    STGA(0, 0); STGB(0, 0);
    STGA(1, SLOT); STGB(1, SLOT);
    WAITV(4);
    BAR();

    int sc = 0, sn = 2;
    for (int t = 0; t < 32; ++t) {
        int sCur = sc * SLOT, sNxt = sn * SLOT;
        bf16x8 a0[4], bfv[2];
#pragma unroll
        for (int m = 0; m < 4; m++) a0[m] = *(const bf16x8*)&lds[sCur + aoff0 + m * 512];
#pragma unroll
        for (int n = 0; n < 2; n++) bfv[n] = *(const bf16x8*)&lds[sCur + boff0 + n * 512];
        if (t < 30) STGA(t + 2, sNxt);
        BAR();
        __builtin_amdgcn_s_setprio(1);
#pragma unroll
        for (int m = 0; m < 4; m++)
#pragma unroll
            for (int n = 0; n < 2; n++) acc[m][n] = MFMA16(a0[m], bfv[n], acc[m][n]);
        __builtin_amdgcn_s_setprio(0);
        BAR();
        bf16x8 b2[2];
#pragma unroll
        for (int n = 0; n < 2; n++) b2[n] = *(const bf16x8*)&lds[sCur + boff0 + (n + 2) * 512];
        if (t < 30) STGB(t + 2, sNxt);
        BAR();
        __builtin_amdgcn_s_setprio(1);
#pragma unroll
        for (int m = 0; m < 4; m++)
#pragma unroll
            for (int n = 0; n < 2; n++) acc[m][n + 2] = MFMA16(a0[m], b2[n], acc[m][n + 2]);
        __builtin_amdgcn_s_setprio(0);
        if (t < 30) { WAITV(4); } else if (t == 30) { WAITV(0); }
        BAR();
        sc = (sc == 2) ? 0 : sc + 1;
        sn = (sn == 2) ? 0 : sn + 1;
    }
#undef STGA
#undef STGB

    float bv[4];
#pragma unroll
    for (int n = 0; n < 4; n++) bv[n] = b0[(n0 & 1023) + wc * 64 + n * 16 + col];
#pragma unroll
    for (int m = 0; m < 4; m++) {
#pragma unroll
        for (int rr = 0; rr < 4; rr++) {
            int row = m0 + wr * 64 + m * 16 + fg * 4 + rr;
#pragma unroll
            for (int n = 0; n < 4; n++) {
                int c = n0 + wc * 64 + n * 16 + col;
                size_t idx = (size_t)row * ldc + c;
                float v = (acc[m][n][rr] + bv[n]) * sc0;
                if constexpr (EPI == 0) ((u16*)outp)[idx] = f2b(v);
                else if constexpr (EPI == 1) ((u16*)outp)[idx] = f2b(fmaxf(v, 0.f));
                else if constexpr (EPI == 2) ((float*)outp)[idx] = v + res[idx];
            }
        }
    }
}

// ---------------- flash attention v6: KVBLK=128 double-buffer (8 barriers), 2x64 sub-tiles ----------------
// grid 512 = bq*128 + hh*8 + bb; 512 thr = 8 waves x 32 q-rows; no-max softmax (Q pre-scaled);
// V^T pre-transposed in global. LDS 71680 B -> still 2 blocks/CU (grid-limited anyway).
__global__ __launch_bounds__(512) void attn_k(const u16* __restrict__ Q, int ldq,
                                              const u16* __restrict__ Kc, int ldk,
                                              const u16* __restrict__ VT,   // [(b*16+h)*64+dh][1024]
                                              const int* __restrict__ mask,
                                              u16* __restrict__ O, int ldo) {
    const int S = 1024;
    int gid = blockIdx.x;
    int bq = gid >> 7, hh = (gid >> 3) & 15, bb = gid & 7;
    int tid = threadIdx.x, lane = tid & 63, w = tid >> 6;   // w 0..7
    int q = lane & 31, hl = lane >> 5;
    int q0w = bq * 256 + w * 32;

    __shared__ u16 sm[35840];   // 71680 B: 2 bufs x [ K 128x72 | V^T 64x136 ]
#define KT(b, r, c) sm[(b) * 17920 + (r) * 72 + (c)]
#define VTL(b, r, c) sm[(b) * 17920 + 9216 + (r) * 136 + (c)]

    const u16* Qrow = Q + ((size_t)bb * S + q0w + q) * ldq + hh * 64;
    bool mneg = (mask[bb * S + q0w + q] == 0);
    bf16x8 qf[4];
#pragma unroll
    for (int c = 0; c < 4; c++) {
        qf[c] = *(const bf16x8*)(Qrow + c * 16 + hl * 8);
        if (mneg) qf[c] = (bf16x8)(__bf16)0.f;   // -> sc==0 -> p==1 (uniform)
    }

    float l = 0.f;
    f32x16 oa[2];
#pragma unroll
    for (int i = 0; i < 16; i++) { oa[0][i] = 0.f; oa[1][i] = 0.f; }

    int kk = tid >> 2, k4 = tid & 3;   // K staging: row kk (0..127), chunk k4*16 of 64 dh
    int vk = tid >> 3, v8 = tid & 7;   // VT staging: row vk (0..63 dh), chunk v8*16 of 128 keys
    const u16* gK = Kc + ((size_t)bb * S + kk) * ldk + hh * 64 + k4 * 16;
    const u16* gVT = VT + ((size_t)(bb * 16 + hh) * 64 + vk) * 1024 + v8 * 16;
    uint4 kr0, kr1, vr0, vr1;

#define LOADT(t)                                                   \
    {                                                              \
        const u16* pk_ = gK + (size_t)(t) * 128 * ldk;             \
        kr0 = *(const uint4*)pk_; kr1 = *(const uint4*)(pk_ + 8);  \
        const u16* pv_ = gVT + (size_t)(t) * 128;                  \
        vr0 = *(const uint4*)pv_; vr1 = *(const uint4*)(pv_ + 8);  \
    }
#define STORET(bf)                                       \
    {                                                    \
        *(uint4*)&KT(bf, kk, k4 * 16) = kr0;             \
        *(uint4*)&KT(bf, kk, k4 * 16 + 8) = kr1;         \
        *(uint4*)&VTL(bf, vk, v8 * 16) = vr0;            \
        *(uint4*)&VTL(bf, vk, v8 * 16 + 8) = vr1;        \
    }

    LOADT(0);
    STORET(0);

    for (int t = 0; t < 8; ++t) {
        int cur = t & 1;
        if (t < 7) LOADT(t + 1);
        __syncthreads();   // buf[cur] staged; prior readers of buf[cur^1] done

#pragma unroll
        for (int sub = 0; sub < 2; ++sub) {
            // ---- QK^T: S^T[key][q] for 64 keys ----
            f32x16 sc[2];
#pragma unroll
            for (int i = 0; i < 16; i++) { sc[0][i] = 0.f; sc[1][i] = 0.f; }
            __builtin_amdgcn_s_setprio(1);
#pragma unroll
            for (int st = 0; st < 2; st++)
#pragma unroll
                for (int c = 0; c < 4; c++) {
                    bf16x8 kf = *(const bf16x8*)&KT(cur, sub * 64 + st * 32 + q, c * 16 + hl * 8);
                    sc[st] = MFMA32(kf, qf[c], sc[st]);
                }
            __builtin_amdgcn_s_setprio(0);

            // ---- p = exp2(sc); per-lane partial sum ----
#pragma unroll
            for (int st = 0; st < 2; st++)
#pragma unroll
                for (int rr = 0; rr < 16; rr++) sc[st][rr] = exp2f(sc[st][rr]);
            float ts[8];
#pragma unroll
            for (int i = 0; i < 8; i++)
                ts[i] = (sc[0][i] + sc[0][i + 8]) + (sc[1][i] + sc[1][i + 8]);
#pragma unroll
            for (int i = 0; i < 4; i++) ts[i] += ts[i + 4];
            l += (ts[0] + ts[2]) + (ts[1] + ts[3]);

            // ---- P -> bf16 B-frags via cvt_pk + permlane32_swap; PV: O^T += V^T x P ----
            __builtin_amdgcn_s_setprio(1);
#pragma unroll
            for (int st = 0; st < 2; st++) {
                u32 wv[8];
#pragma unroll
                for (int j = 0; j < 8; j++) wv[j] = pk2(sc[st][2 * j], sc[st][2 * j + 1]);
                PLSWAP(wv[0], wv[2]); PLSWAP(wv[1], wv[3]);
                PLSWAP(wv[4], wv[6]); PLSWAP(wv[5], wv[7]);
#pragma unroll
                for (int c = 0; c < 2; c++) {
                    union { u32 u[4]; bf16x8 v; } pb;
                    pb.u[0] = wv[c * 4 + 0]; pb.u[1] = wv[c * 4 + 1];
                    pb.u[2] = wv[c * 4 + 2]; pb.u[3] = wv[c * 4 + 3];
#pragma unroll
                    for (int dd = 0; dd < 2; dd++) {
                        bf16x8 vf = *(const bf16x8*)&VTL(cur, dd * 32 + q,
                                                         sub * 64 + st * 32 + c * 16 + hl * 8);
                        oa[dd] = MFMA32(vf, pb.v, oa[dd]);
                    }
                }
            }
            __builtin_amdgcn_s_setprio(0);
        }

        if (t < 7) STORET(cur ^ 1);
    }

    // ---- epilogue: finish l, normalize, transpose O^T -> O via per-wave LDS, coalesced store ----
    l += __shfl_xor(l, 32);
    __syncthreads();
    float inv = 1.0f / l;
    u16* otw = sm + w * 2304;   // per-wave [32 q][72]
#pragma unroll
    for (int dd = 0; dd < 2; dd++)
#pragma unroll
        for (int rr = 0; rr < 16; rr++) {
            int d = (rr & 3) + 8 * (rr >> 2) + 4 * hl + 32 * dd;
            otw[q * 72 + d] = f2b(oa[dd][rr] * inv);
        }
    __syncthreads();
    size_t obase = ((size_t)bb * S + q0w) * ldo + hh * 64;
#pragma unroll
    for (int i = 0; i < 4; i++) {
        int row = i * 8 + (lane >> 3);
        uint4 vdat = *(const uint4*)&otw[row * 72 + (lane & 7) * 8];
        *(uint4*)(O + obase + (size_t)row * ldo + (lane & 7) * 8) = vdat;
    }
#undef KT
#undef VTL
#undef LOADT
#undef STORET
}

extern "C" void kernel_launch(void* const* d_in, const int* in_sizes, int n_in,
                              void* d_out, int out_size, void* d_ws, size_t ws_size,
                              hipStream_t stream) {
    (void)in_sizes; (void)n_in; (void)out_size; (void)ws_size;
    const float* x = (const float*)d_in[0];
    const float* h = (const float*)d_in[1];
    const int* mask = (const int*)d_in[2];
    const float* W[10];
    const float* Bv[10];
    for (int i = 0; i < 10; i++) { W[i] = (const float*)d_in[3 + i]; Bv[i] = (const float*)d_in[13 + i]; }
    const float *ln1g = (const float*)d_in[23], *ln1b = (const float*)d_in[24];
    const float *ln2g = (const float*)d_in[25], *ln2b = (const float*)d_in[26];
    const float *ln3g = (const float*)d_in[27], *ln3b = (const float*)d_in[28];
    const float *lnhg = (const float*)d_in[29], *lnhb = (const float*)d_in[30];
    const float *flng = (const float*)d_in[31], *flnb = (const float*)d_in[32];

    const float SCLE = 0.18033688011112042f;   // log2(e)/sqrt(64)

    char* ws = (char*)d_ws;
    size_t off = 0;
    auto alloc = [&](size_t bytes) -> char* {
        char* p = ws + off;
        off += (bytes + 255) & ~(size_t)255;
        return p;
    };
    const size_t MT = (size_t)8192 * 1024;
    u16* wtb = (u16*)alloc((size_t)10 * 1048576 * 2);
    u16* wt[10];
    for (int i = 0; i < 10; i++) wt[i] = wtb + (size_t)i * 1048576;
    u16* qkv = (u16*)alloc((size_t)8192 * 3072 * 2);   // sa QKV; later ca kv + ff1
    u16* kv = qkv;
    u16* kb = qkv + (size_t)8192 * 2048;
    u16* bufA = (u16*)alloc(MT * 2);
    u16* qb   = (u16*)alloc(MT * 2);          // ca Q, then ca attention out
    float* hid_in  = (float*)alloc(MT * 4);
    float* hid_mid = (float*)alloc(MT * 4);
    float* yf      = (float*)alloc(MT * 4);
    u16* hn = (u16*)yf;                        // hn lifetime disjoint from yf (FFN)
    u16* vt_sa = bufA;                         // V^T alias: free between QKV-gemm and ln2
    u16* vt_ca = (u16*)hid_mid;                // V^T alias: free between kv-gemm and ca-wo gemm
    float* outF = (float*)d_out;

    W10 wp;
    for (int i = 0; i < 10; i++) wp.p[i] = W[i];
    tcvt_k<<<dim3(32, 32, 10), dim3(32, 8), 0, stream>>>(wp, wtb);

    // ---- self-attention block ----
    ln_k<4><<<8192, 256, 0, stream>>>(x, nullptr, ln1g, ln1b, nullptr, nullptr, bufA);
    gemm512_k<0, 2, 24><<<768, 512, 0, stream>>>(bufA, 1024, wt[0], Bv[0], Bv[1], Bv[2], SCLE, 1.f, 1.f, nullptr, qkv, 3072);
    vtr_k<<<dim3(32, 32, 8), dim3(32, 8), 0, stream>>>(qkv + 2048, 3072, vt_sa);
    attn_k<<<512, 512, 0, stream>>>(qkv, 3072, qkv + 1024, 3072, vt_sa, mask, qkv, 3072);
    gemm256_k<2, 8><<<512, 256, 0, stream>>>(qkv, 3072, wt[3], Bv[3], 1.f, x, hid_in, 1024);

    // ---- cross-attention block ----
    ln_k<4><<<8192, 256, 0, stream>>>(hid_in, nullptr, ln2g, ln2b, nullptr, nullptr, bufA);
    ln_k<4><<<8192, 256, 0, stream>>>(h, nullptr, lnhg, lnhb, nullptr, nullptr, hn);
    gemm256_k<0, 8><<<512, 256, 0, stream>>>(bufA, 1024, wt[4], Bv[4], SCLE, nullptr, qb, 1024);
    gemm512_k<0, 2, 16><<<512, 512, 0, stream>>>(hn, 1024, wt[5], Bv[5], Bv[6], Bv[6], 1.f, 1.f, 1.f, nullptr, kv, 2048);
    vtr_k<<<dim3(32, 32, 8), dim3(32, 8), 0, stream>>>(kv + 1024, 2048, vt_ca);
    attn_k<<<512, 512, 0, stream>>>(qb, 1024, kv, 2048, vt_ca, mask, qb, 1024);
    gemm256_k<2, 8><<<512, 256, 0, stream>>>(qb, 1024, wt[7], Bv[7], 1.f, hid_in, hid_mid, 1024);

    // ---- FFN block ----
    ln_k<6><<<8192, 256, 0, stream>>>(hid_mid, nullptr, ln3g, ln3b, nullptr, yf, bufA);
    gemm256_k<1, 8><<<512, 256, 0, stream>>>(bufA, 1024, wt[8], Bv[8], 1.f, nullptr, kb, 1024);
    gemm256_k<2, 8><<<512, 256, 0, stream>>>(kb, 1024, wt[9], Bv[9], 1.f, yf, hid_in, 1024);
    ln_k<10><<<8192, 256, 0, stream>>>(hid_in, nullptr, flng, flnb, hid_mid, outF, nullptr);
}

// Round 13
// 449.856 us; speedup vs baseline: 1.0312x; 1.0312x over previous
//
#include <hip/hip_runtime.h>

typedef unsigned short u16;
typedef unsigned int u32;
typedef float f32x4 __attribute__((ext_vector_type(4)));
typedef float f32x16 __attribute__((ext_vector_type(16)));
typedef __bf16 bf16x8 __attribute__((ext_vector_type(8)));

#define MFMA16(a, b, c) __builtin_amdgcn_mfma_f32_16x16x32_bf16(a, b, c, 0, 0, 0)
#define MFMA32(a, b, c) __builtin_amdgcn_mfma_f32_32x32x16_bf16(a, b, c, 0, 0, 0)
#define PLSWAP(x, y) asm volatile("v_permlane32_swap_b32 %0, %1" : "+v"(x), "+v"(y))
#define CFENCE() asm volatile("" ::: "memory")
#define BAR()                         \
    {                                 \
        CFENCE();                     \
        __builtin_amdgcn_s_barrier(); \
        CFENCE();                     \
    }
#define WAITV(n) asm volatile("s_waitcnt vmcnt(" #n ")" ::: "memory")

__device__ __forceinline__ u16 f2b(float f) {
    u32 u = __builtin_bit_cast(u32, f);
    u += 0x7fffu + ((u >> 16) & 1u);   // round-to-nearest-even
    return (u16)(u >> 16);
}

__device__ __forceinline__ u32 pk2(float a, float b) {
    union { u32 u; __bf16 h[2]; } r;
    r.h[0] = (__bf16)a; r.h[1] = (__bf16)b;
    return r.u;   // v_cvt_pk_bf16_f32
}

__device__ __forceinline__ void gload16(const u16* g, u16* l) {
    __builtin_amdgcn_global_load_lds((const __attribute__((address_space(1))) void*)g,
                                     (__attribute__((address_space(3))) void*)l, 16, 0, 0);
}

// ---------------- weight transpose + f32->bf16 convert (all 10 in one launch) ----------------
struct W10 { const float* p[10]; };
__global__ __launch_bounds__(256) void tcvt_k(W10 wp, u16* __restrict__ WT0) {
    const float* __restrict__ Wm = wp.p[blockIdx.z];
    u16* __restrict__ WT = WT0 + (size_t)blockIdx.z * 1048576;
    __shared__ float t[32][33];
    int bx = blockIdx.x, by = blockIdx.y;
    int tx = threadIdx.x, ty = threadIdx.y;   // (32,8)
#pragma unroll
    for (int j = 0; j < 32; j += 8)
        t[ty + j][tx] = Wm[(size_t)(by * 32 + ty + j) * 1024 + bx * 32 + tx];
    __syncthreads();
#pragma unroll
    for (int j = 0; j < 32; j += 8)
        WT[(size_t)(bx * 32 + ty + j) * 1024 + by * 32 + tx] = f2b(t[tx][ty + j]);
}

// ---------------- per-batch V transpose: V[b][key][c] -> VT[b][c][key]  (c = h*64+dh) ----------------
__global__ __launch_bounds__(256) void vtr_k(const u16* __restrict__ Vg, int ldv, u16* __restrict__ VT) {
    __shared__ u16 t[32][34];
    int bx = blockIdx.x, by = blockIdx.y, b = blockIdx.z;
    int tx = threadIdx.x, ty = threadIdx.y;   // (32,8)
#pragma unroll
    for (int j = 0; j < 32; j += 8)
        t[ty + j][tx] = Vg[(size_t)(b * 1024 + by * 32 + ty + j) * ldv + bx * 32 + tx];
    __syncthreads();
#pragma unroll
    for (int j = 0; j < 32; j += 8)
        VT[(size_t)(b * 1024 + bx * 32 + ty + j) * 1024 + by * 32 + tx] = t[tx][ty + j];
}

// ---------------- fused LayerNorm (r9 proven version: block-per-row) ----------------
// MODE bit0: x = in1 + in2 ; bit1: write f32 out (bit3: += post) ; bit2: write bf16 out
template <int MODE>
__global__ __launch_bounds__(256) void ln_k(const float* __restrict__ in1, const float* __restrict__ in2,
                                            const float* __restrict__ gg, const float* __restrict__ bb,
                                            const float* __restrict__ post,
                                            float* __restrict__ of, u16* __restrict__ ob) {
    int row = blockIdx.x, tid = threadIdx.x;
    size_t base = (size_t)row * 1024 + tid * 4;
    float4 x = *(const float4*)(in1 + base);
    if constexpr (MODE & 1) {
        float4 x2 = *(const float4*)(in2 + base);
        x.x += x2.x; x.y += x2.y; x.z += x2.z; x.w += x2.w;
    }
    float s1 = x.x + x.y + x.z + x.w;
    float s2 = x.x * x.x + x.y * x.y + x.z * x.z + x.w * x.w;
#pragma unroll
    for (int m = 32; m >= 1; m >>= 1) { s1 += __shfl_xor(s1, m); s2 += __shfl_xor(s2, m); }
    __shared__ float r1[4], r2[4];
    int lane = tid & 63, w = tid >> 6;
    if (lane == 0) { r1[w] = s1; r2[w] = s2; }
    __syncthreads();
    s1 = r1[0] + r1[1] + r1[2] + r1[3];
    s2 = r2[0] + r2[1] + r2[2] + r2[3];
    float mean = s1 * (1.0f / 1024.0f);
    float var = s2 * (1.0f / 1024.0f) - mean * mean;
    float rstd = rsqrtf(var + 1e-5f);
    float4 gv = *(const float4*)(gg + tid * 4);
    float4 bv = *(const float4*)(bb + tid * 4);
    float y0 = (x.x - mean) * rstd * gv.x + bv.x;
    float y1 = (x.y - mean) * rstd * gv.y + bv.y;
    float y2 = (x.z - mean) * rstd * gv.z + bv.z;
    float y3 = (x.w - mean) * rstd * gv.w + bv.w;
    if constexpr (MODE & 2) {
        float o0 = y0, o1 = y1, o2 = y2, o3 = y3;
        if constexpr (MODE & 8) {
            float4 p = *(const float4*)(post + base);
            o0 += p.x; o1 += p.y; o2 += p.z; o3 += p.w;
        }
        float4 o; o.x = o0; o.y = o1; o.z = o2; o.w = o3;
        *(float4*)(of + base) = o;
    }
    if constexpr (MODE & 4) {
        uint2 pk;
        pk.x = (u32)f2b(y0) | ((u32)f2b(y1) << 16);
        pk.y = (u32)f2b(y2) | ((u32)f2b(y3) << 16);
        *(uint2*)(ob + base) = pk;
    }
}

// ---------------- bf16 GEMM v512: BM=256/BN=128, 8 waves, phase-split, 3-slot 72KB ring ----------------
template <int EPI, int WN, int NBN>
__global__ __launch_bounds__(512) void gemm512_k(const u16* __restrict__ A, int lda,
                                                 const u16* __restrict__ WT,
                                                 const float* __restrict__ b0, const float* __restrict__ b1,
                                                 const float* __restrict__ b2,
                                                 float sc0, float sc1, float sc2,
                                                 const float* __restrict__ res,
                                                 void* __restrict__ outp, int ldc) {
    constexpr int ASZ = 8192;
    constexpr int BSZ = (WN == 4) ? 8192 : 4096;
    constexpr int SLOT = ASZ + BSZ;
    constexpr int MR = (WN == 4) ? 8 : 4;
    constexpr int WRS = (WN == 4) ? 128 : 64;
    __shared__ u16 lds[3 * SLOT];
    u16* ldsb = &lds[0];

    int id = blockIdx.x;
    constexpr int NWG = 32 * NBN;
    constexpr int CPX = NWG / 8;
    int swz = (id & 7) * CPX + (id >> 3);
    int bm = swz / NBN, bn = swz % NBN;
    const int m0 = bm * 256, n0 = bn * (WN * 64);
    int tid = threadIdx.x, lane = tid & 63, w = tid >> 6;
    int col = lane & 15, fg = lane >> 4;
    int wr = (WN == 4) ? (w >> 2) : (w >> 1);
    int wc = w & (WN - 1);

    int swzL = ((col * 32) + fg * 8) ^ ((col >> 1) << 3);
    int aoff0 = wr * WRS * 32 + swzL;
    int boff0 = ASZ + wc * 64 * 32 + swzL;

    int r = tid >> 2, g = tid & 3;
    int gr = r ^ ((r >> 3) & 1);
    int gc = g ^ ((r >> 1) & 3);
    const u16* pA = A + (size_t)(m0 + gr) * lda + gc * 8;
    const u16* pB = WT + (size_t)(n0 + gr) * 1024 + gc * 8;

#define STGA(t2, snO)                                                                 \
    {                                                                                 \
        gload16(pA + (size_t)(t2) * 32, ldsb + (snO) + w * 512);                      \
        gload16(pA + (size_t)(t2) * 32 + (size_t)128 * lda, ldsb + (snO) + 4096 + w * 512); \
    }
#define STGB(t2, snO)                                                                 \
    {                                                                                 \
        gload16(pB + (size_t)(t2) * 32, ldsb + (snO) + ASZ + w * 512);                \
        if constexpr (WN == 4) {                                                      \
            gload16(pB + (size_t)(t2) * 32 + (size_t)128 * 1024, ldsb + (snO) + ASZ + 4096 + w * 512); \
        }                                                                             \
    }

    f32x4 acc[MR][4];
#pragma unroll
    for (int m = 0; m < MR; m++)
#pragma unroll
        for (int n = 0; n < 4; n++) acc[m][n] = (f32x4){0.f, 0.f, 0.f, 0.f};

    STGA(0, 0); STGB(0, 0);
    STGA(1, SLOT); STGB(1, SLOT);
    if constexpr (WN == 4) { WAITV(4); } else { WAITV(3); }
    BAR();

    int sc = 0, sn = 2;
    for (int t = 0; t < 32; ++t) {
        int sCur = sc * SLOT, sNxt = sn * SLOT;
        bf16x8 a0[4], bfv[WN];
#pragma unroll
        for (int m = 0; m < 4; m++) a0[m] = *(const bf16x8*)&ldsb[sCur + aoff0 + m * 512];
#pragma unroll
        for (int n = 0; n < WN; n++) bfv[n] = *(const bf16x8*)&ldsb[sCur + boff0 + n * 512];
        if (t < 30) STGA(t + 2, sNxt);
        BAR();
        __builtin_amdgcn_s_setprio(1);
#pragma unroll
        for (int m = 0; m < 4; m++)
#pragma unroll
            for (int n = 0; n < WN; n++) acc[m][n] = MFMA16(a0[m], bfv[n], acc[m][n]);
        __builtin_amdgcn_s_setprio(0);
        BAR();
        if constexpr (WN == 4) {
            bf16x8 a1[4];
#pragma unroll
            for (int m = 0; m < 4; m++) a1[m] = *(const bf16x8*)&ldsb[sCur + aoff0 + (m + 4) * 512];
            if (t < 30) STGB(t + 2, sNxt);
            BAR();
            __builtin_amdgcn_s_setprio(1);
#pragma unroll
            for (int m = 0; m < 4; m++)
#pragma unroll
                for (int n = 0; n < 4; n++) acc[m + 4][n] = MFMA16(a1[m], bfv[n], acc[m + 4][n]);
            __builtin_amdgcn_s_setprio(0);
            if (t < 30) { WAITV(4); } else if (t == 30) { WAITV(0); }
            BAR();
        } else {
            bf16x8 b2[2];
#pragma unroll
            for (int n = 0; n < 2; n++) b2[n] = *(const bf16x8*)&ldsb[sCur + boff0 + (n + 2) * 512];
            if (t < 30) STGB(t + 2, sNxt);
            BAR();
            __builtin_amdgcn_s_setprio(1);
#pragma unroll
            for (int m = 0; m < 4; m++)
#pragma unroll
                for (int n = 0; n < 2; n++) acc[m][n + 2] = MFMA16(a0[m], b2[n], acc[m][n + 2]);
            __builtin_amdgcn_s_setprio(0);
            if (t < 30) { WAITV(3); } else if (t == 30) { WAITV(0); }
            BAR();
        }
        sc = (sc == 2) ? 0 : sc + 1;
        sn = (sn == 2) ? 0 : sn + 1;
    }
#undef STGA
#undef STGB

    int seg = n0 >> 10;
    const float* bp = (seg == 0) ? b0 : (seg == 1 ? b1 : b2);
    float sg = (seg == 0) ? sc0 : (seg == 1 ? sc1 : sc2);
    int nseg = n0 & 1023;
    float bv[4];
#pragma unroll
    for (int n = 0; n < 4; n++) bv[n] = bp[nseg + wc * 64 + n * 16 + col];
#pragma unroll
    for (int m = 0; m < MR; m++) {
#pragma unroll
        for (int rr = 0; rr < 4; rr++) {
            int row = m0 + wr * WRS + m * 16 + fg * 4 + rr;
#pragma unroll
            for (int n = 0; n < 4; n++) {
                int c = n0 + wc * 64 + n * 16 + col;
                size_t idx = (size_t)row * ldc + c;
                float v = (acc[m][n][rr] + bv[n]) * sg;
                if constexpr (EPI == 0) ((u16*)outp)[idx] = f2b(v);
                else if constexpr (EPI == 1) ((u16*)outp)[idx] = f2b(fmaxf(v, 0.f));
                else if constexpr (EPI == 2) ((float*)outp)[idx] = v + res[idx];
            }
        }
    }
}

// ---------------- bf16 GEMM v256: BM=128/BN=128, 4 waves, 3-slot 48KB ring (best for N=1024) ----------------
template <int EPI, int NBN>
__global__ __launch_bounds__(256) void gemm256_k(const u16* __restrict__ A, int lda,
                                                 const u16* __restrict__ WT,
                                                 const float* __restrict__ b0,
                                                 float sc0,
                                                 const float* __restrict__ res,
                                                 void* __restrict__ outp, int ldc) {
    constexpr int SLOT = 8192;
    __shared__ u16 lds[3 * SLOT];
    int id = blockIdx.x;
    constexpr int NWG = 64 * NBN;
    constexpr int CPX = NWG / 8;
    int swz = (id & 7) * CPX + (id >> 3);
    int bm = swz / NBN, bn = swz % NBN;
    const int m0 = bm * 128, n0 = bn * 128;
    int tid = threadIdx.x, lane = tid & 63, w = tid >> 6;
    int col = lane & 15, fg = lane >> 4;
    int wr = w >> 1, wc = w & 1;

    int swzL = ((col * 32) + fg * 8) ^ ((col >> 1) << 3);
    int aoff0 = wr * 64 * 32 + swzL;
    int boff0 = 4096 + wc * 64 * 32 + swzL;

    int r = tid >> 2, g = tid & 3;
    int gr = r ^ ((r >> 3) & 1);
    int gc = g ^ ((r >> 1) & 3);
    const u16* pA = A + (size_t)(m0 + gr) * lda + gc * 8;
    const u16* pB = WT + (size_t)(n0 + gr) * 1024 + gc * 8;

#define STGA(t2, snO)                                                                     \
    {                                                                                     \
        gload16(pA + (size_t)(t2) * 32, lds + (snO) + w * 512);                           \
        gload16(pA + (size_t)(t2) * 32 + (size_t)64 * lda, lds + (snO) + 2048 + w * 512); \
    }
#define STGB(t2, snO)                                                                             \
    {                                                                                             \
        gload16(pB + (size_t)(t2) * 32, lds + (snO) + 4096 + w * 512);                            \
        gload16(pB + (size_t)(t2) * 32 + (size_t)64 * 1024, lds + (snO) + 4096 + 2048 + w * 512); \
    }

    f32x4 acc[4][4];
#pragma unroll
    for (int m = 0; m < 4; m++)
#pragma unroll
        for (int n = 0; n < 4; n++) acc[m][n] = (f32x4){0.f, 0.f, 0.f, 0.f};

    STGA(0, 0); STGB(0, 0);
    STGA(1, SLOT); STGB(1, SLOT);
    WAITV(4);
    BAR();

    int sc = 0, sn = 2;
    for (int t = 0; t < 32; ++t) {
        int sCur = sc * SLOT, sNxt = sn * SLOT;
        bf16x8 a0[4], bfv[2];
#pragma unroll
        for (int m = 0; m < 4; m++) a0[m] = *(const bf16x8*)&lds[sCur + aoff0 + m * 512];
#pragma unroll
        for (int n = 0; n < 2; n++) bfv[n] = *(const bf16x8*)&lds[sCur + boff0 + n * 512];
        if (t < 30) STGA(t + 2, sNxt);
        BAR();
        __builtin_amdgcn_s_setprio(1);
#pragma unroll
        for (int m = 0; m < 4; m++)
#pragma unroll
            for (int n = 0; n < 2; n++) acc[m][n] = MFMA16(a0[m], bfv[n], acc[m][n]);
        __builtin_amdgcn_s_setprio(0);
        BAR();
        bf16x8 b2[2];
#pragma unroll
        for (int n = 0; n < 2; n++) b2[n] = *(const bf16x8*)&lds[sCur + boff0 + (n + 2) * 512];
        if (t < 30) STGB(t + 2, sNxt);
        BAR();
        __builtin_amdgcn_s_setprio(1);
#pragma unroll
        for (int m = 0; m < 4; m++)
#pragma unroll
            for (int n = 0; n < 2; n++) acc[m][n + 2] = MFMA16(a0[m], b2[n], acc[m][n + 2]);
        __builtin_amdgcn_s_setprio(0);
        if (t < 30) { WAITV(4); } else if (t == 30) { WAITV(0); }
        BAR();
        sc = (sc == 2) ? 0 : sc + 1;
        sn = (sn == 2) ? 0 : sn + 1;
    }
#undef STGA
#undef STGB

    float bv[4];
#pragma unroll
    for (int n = 0; n < 4; n++) bv[n] = b0[(n0 & 1023) + wc * 64 + n * 16 + col];
#pragma unroll
    for (int m = 0; m < 4; m++) {
#pragma unroll
        for (int rr = 0; rr < 4; rr++) {
            int row = m0 + wr * 64 + m * 16 + fg * 4 + rr;
#pragma unroll
            for (int n = 0; n < 4; n++) {
                int c = n0 + wc * 64 + n * 16 + col;
                size_t idx = (size_t)row * ldc + c;
                float v = (acc[m][n][rr] + bv[n]) * sc0;
                if constexpr (EPI == 0) ((u16*)outp)[idx] = f2b(v);
                else if constexpr (EPI == 1) ((u16*)outp)[idx] = f2b(fmaxf(v, 0.f));
                else if constexpr (EPI == 2) ((float*)outp)[idx] = v + res[idx];
            }
        }
    }
}

// ---------------- flash attention v5 (r9-best, exact): 8 waves share KVBLK=64 staging; no-max softmax ----------------
__global__ __launch_bounds__(512) void attn_k(const u16* __restrict__ Q, int ldq,
                                              const u16* __restrict__ Kc, int ldk,
                                              const u16* __restrict__ VT,   // [(b*16+h)*64+dh][1024]
                                              const int* __restrict__ mask,
                                              u16* __restrict__ O, int ldo) {
    const int S = 1024;
    int gid = blockIdx.x;
    int bq = gid >> 7, hh = (gid >> 3) & 15, bb = gid & 7;
    int tid = threadIdx.x, lane = tid & 63, w = tid >> 6;   // w 0..7
    int q = lane & 31, hl = lane >> 5;
    int q0w = bq * 256 + w * 32;

    __shared__ u16 sm[18432];   // 36864 B: [buf][ K 64x72 | V^T 64x72 ]
#define KT(b, r, c) sm[(b) * 9216 + (r) * 72 + (c)]
#define VTL(b, r, c) sm[(b) * 9216 + 4608 + (r) * 72 + (c)]

    const u16* Qrow = Q + ((size_t)bb * S + q0w + q) * ldq + hh * 64;
    bool mneg = (mask[bb * S + q0w + q] == 0);
    bf16x8 qf[4];
#pragma unroll
    for (int c = 0; c < 4; c++) {
        qf[c] = *(const bf16x8*)(Qrow + c * 16 + hl * 8);
        if (mneg) qf[c] = (bf16x8)(__bf16)0.f;   // -> sc==0 -> p==1 (uniform)
    }

    float l = 0.f;
    f32x16 oa[2];
#pragma unroll
    for (int i = 0; i < 16; i++) { oa[0][i] = 0.f; oa[1][i] = 0.f; }

    int kk = tid >> 3, ks = tid & 7;
    const u16* gK = Kc + ((size_t)bb * S + kk) * ldk + hh * 64 + ks * 8;
    const u16* gVT = VT + ((size_t)(bb * 16 + hh) * 64 + kk) * 1024 + ks * 8;
    uint4 kr0, vr0;

#define LOADT(t)                                              \
    {                                                         \
        kr0 = *(const uint4*)(gK + (size_t)(t) * 64 * ldk);   \
        vr0 = *(const uint4*)(gVT + (size_t)(t) * 64);        \
    }
#define STORET(bf)                            \
    {                                         \
        *(uint4*)&KT(bf, kk, ks * 8) = kr0;   \
        *(uint4*)&VTL(bf, kk, ks * 8) = vr0;  \
    }

    LOADT(0);
    STORET(0);

    for (int t = 0; t < 16; ++t) {
        int cur = t & 1;
        if (t < 15) LOADT(t + 1);
        __syncthreads();

        f32x16 sc[2];
#pragma unroll
        for (int i = 0; i < 16; i++) { sc[0][i] = 0.f; sc[1][i] = 0.f; }
        __builtin_amdgcn_s_setprio(1);
#pragma unroll
        for (int st = 0; st < 2; st++)
#pragma unroll
            for (int c = 0; c < 4; c++) {
                bf16x8 kf = *(const bf16x8*)&KT(cur, st * 32 + q, c * 16 + hl * 8);
                sc[st] = MFMA32(kf, qf[c], sc[st]);
            }
        __builtin_amdgcn_s_setprio(0);

#pragma unroll
        for (int st = 0; st < 2; st++)
#pragma unroll
            for (int rr = 0; rr < 16; rr++) sc[st][rr] = exp2f(sc[st][rr]);
        float ts[8];
#pragma unroll
        for (int i = 0; i < 8; i++)
            ts[i] = (sc[0][i] + sc[0][i + 8]) + (sc[1][i] + sc[1][i + 8]);
#pragma unroll
        for (int i = 0; i < 4; i++) ts[i] += ts[i + 4];
        l += (ts[0] + ts[2]) + (ts[1] + ts[3]);

        __builtin_amdgcn_s_setprio(1);
#pragma unroll
        for (int st = 0; st < 2; st++) {
            u32 wv[8];
#pragma unroll
            for (int j = 0; j < 8; j++) wv[j] = pk2(sc[st][2 * j], sc[st][2 * j + 1]);
            PLSWAP(wv[0], wv[2]); PLSWAP(wv[1], wv[3]);
            PLSWAP(wv[4], wv[6]); PLSWAP(wv[5], wv[7]);
#pragma unroll
            for (int c = 0; c < 2; c++) {
                union { u32 u[4]; bf16x8 v; } pb;
                pb.u[0] = wv[c * 4 + 0]; pb.u[1] = wv[c * 4 + 1];
                pb.u[2] = wv[c * 4 + 2]; pb.u[3] = wv[c * 4 + 3];
#pragma unroll
                for (int dd = 0; dd < 2; dd++) {
                    bf16x8 vf = *(const bf16x8*)&VTL(cur, dd * 32 + q, st * 32 + c * 16 + hl * 8);
                    oa[dd] = MFMA32(vf, pb.v, oa[dd]);
                }
            }
        }
        __builtin_amdgcn_s_setprio(0);

        if (t < 15) STORET(cur ^ 1);
    }

    l += __shfl_xor(l, 32);
    __syncthreads();
    float inv = 1.0f / l;
    u16* otw = sm + w * 2304;
#pragma unroll
    for (int dd = 0; dd < 2; dd++)
#pragma unroll
        for (int rr = 0; rr < 16; rr++) {
            int d = (rr & 3) + 8 * (rr >> 2) + 4 * hl + 32 * dd;
            otw[q * 72 + d] = f2b(oa[dd][rr] * inv);
        }
    __syncthreads();
    size_t obase = ((size_t)bb * S + q0w) * ldo + hh * 64;
#pragma unroll
    for (int i = 0; i < 4; i++) {
        int row = i * 8 + (lane >> 3);
        uint4 vdat = *(const uint4*)&otw[row * 72 + (lane & 7) * 8];
        *(uint4*)(O + obase + (size_t)row * ldo + (lane & 7) * 8) = vdat;
    }
#undef KT
#undef VTL
#undef LOADT
#undef STORET
}

extern "C" void kernel_launch(void* const* d_in, const int* in_sizes, int n_in,
                              void* d_out, int out_size, void* d_ws, size_t ws_size,
                              hipStream_t stream) {
    (void)in_sizes; (void)n_in; (void)out_size; (void)ws_size;
    const float* x = (const float*)d_in[0];
    const float* h = (const float*)d_in[1];
    const int* mask = (const int*)d_in[2];
    const float* W[10];
    const float* Bv[10];
    for (int i = 0; i < 10; i++) { W[i] = (const float*)d_in[3 + i]; Bv[i] = (const float*)d_in[13 + i]; }
    const float *ln1g = (const float*)d_in[23], *ln1b = (const float*)d_in[24];
    const float *ln2g = (const float*)d_in[25], *ln2b = (const float*)d_in[26];
    const float *ln3g = (const float*)d_in[27], *ln3b = (const float*)d_in[28];
    const float *lnhg = (const float*)d_in[29], *lnhb = (const float*)d_in[30];
    const float *flng = (const float*)d_in[31], *flnb = (const float*)d_in[32];

    const float SCLE = 0.18033688011112042f;   // log2(e)/sqrt(64)

    char* ws = (char*)d_ws;
    size_t off = 0;
    auto alloc = [&](size_t bytes) -> char* {
        char* p = ws + off;
        off += (bytes + 255) & ~(size_t)255;
        return p;
    };
    const size_t MT = (size_t)8192 * 1024;
    u16* wtb = (u16*)alloc((size_t)10 * 1048576 * 2);
    u16* wt[10];
    for (int i = 0; i < 10; i++) wt[i] = wtb + (size_t)i * 1048576;
    u16* qkv = (u16*)alloc((size_t)8192 * 3072 * 2);   // sa QKV; later ca kv + ff1
    u16* kv = qkv;
    u16* kb = qkv + (size_t)8192 * 2048;
    u16* bufA = (u16*)alloc(MT * 2);
    u16* qb   = (u16*)alloc(MT * 2);          // ca Q, then ca attention out
    float* hid_in  = (float*)alloc(MT * 4);
    float* hid_mid = (float*)alloc(MT * 4);
    float* yf      = (float*)alloc(MT * 4);
    u16* hn = (u16*)yf;                        // hn lifetime disjoint from yf (FFN)
    u16* vt_sa = bufA;                         // V^T alias: free between QKV-gemm and ln2
    u16* vt_ca = (u16*)hid_mid;                // V^T alias: free between kv-gemm and ca-wo gemm
    float* outF = (float*)d_out;

    W10 wp;
    for (int i = 0; i < 10; i++) wp.p[i] = W[i];
    tcvt_k<<<dim3(32, 32, 10), dim3(32, 8), 0, stream>>>(wp, wtb);

    // ---- self-attention block ----
    ln_k<4><<<8192, 256, 0, stream>>>(x, nullptr, ln1g, ln1b, nullptr, nullptr, bufA);
    gemm512_k<0, 2, 24><<<768, 512, 0, stream>>>(bufA, 1024, wt[0], Bv[0], Bv[1], Bv[2], SCLE, 1.f, 1.f, nullptr, qkv, 3072);
    vtr_k<<<dim3(32, 32, 8), dim3(32, 8), 0, stream>>>(qkv + 2048, 3072, vt_sa);
    attn_k<<<512, 512, 0, stream>>>(qkv, 3072, qkv + 1024, 3072, vt_sa, mask, qkv, 3072);
    gemm256_k<2, 8><<<512, 256, 0, stream>>>(qkv, 3072, wt[3], Bv[3], 1.f, x, hid_in, 1024);

    // ---- cross-attention block ----
    ln_k<4><<<8192, 256, 0, stream>>>(hid_in, nullptr, ln2g, ln2b, nullptr, nullptr, bufA);
    ln_k<4><<<8192, 256, 0, stream>>>(h, nullptr, lnhg, lnhb, nullptr, nullptr, hn);
    gemm256_k<0, 8><<<512, 256, 0, stream>>>(bufA, 1024, wt[4], Bv[4], SCLE, nullptr, qb, 1024);
    gemm512_k<0, 2, 16><<<512, 512, 0, stream>>>(hn, 1024, wt[5], Bv[5], Bv[6], Bv[6], 1.f, 1.f, 1.f, nullptr, kv, 2048);
    vtr_k<<<dim3(32, 32, 8), dim3(32, 8), 0, stream>>>(kv + 1024, 2048, vt_ca);
    attn_k<<<512, 512, 0, stream>>>(qb, 1024, kv, 2048, vt_ca, mask, qb, 1024);
    gemm256_k<2, 8><<<512, 256, 0, stream>>>(qb, 1024, wt[7], Bv[7], 1.f, hid_in, hid_mid, 1024);

    // ---- FFN block ----
    ln_k<6><<<8192, 256, 0, stream>>>(hid_mid, nullptr, ln3g, ln3b, nullptr, yf, bufA);
    gemm256_k<1, 8><<<512, 256, 0, stream>>>(bufA, 1024, wt[8], Bv[8], 1.f, nullptr, kb, 1024);
    gemm256_k<2, 8><<<512, 256, 0, stream>>>(kb, 1024, wt[9], Bv[9], 1.f, yf, hid_in, 1024);
    ln_k<10><<<8192, 256, 0, stream>>>(hid_in, nullptr, flng, flnb, hid_mid, outF, nullptr);
}

// Round 14
// 448.873 us; speedup vs baseline: 1.0335x; 1.0022x over previous
//
#include <hip/hip_runtime.h>

typedef unsigned short u16;
typedef unsigned int u32;
typedef float f32x4 __attribute__((ext_vector_type(4)));
typedef float f32x16 __attribute__((ext_vector_type(16)));
typedef __bf16 bf16x8 __attribute__((ext_vector_type(8)));

#define MFMA16(a, b, c) __builtin_amdgcn_mfma_f32_16x16x32_bf16(a, b, c, 0, 0, 0)
#define MFMA32(a, b, c) __builtin_amdgcn_mfma_f32_32x32x16_bf16(a, b, c, 0, 0, 0)
#define PLSWAP(x, y) asm volatile("v_permlane32_swap_b32 %0, %1" : "+v"(x), "+v"(y))
#define CFENCE() asm volatile("" ::: "memory")
#define BAR()                         \
    {                                 \
        CFENCE();                     \
        __builtin_amdgcn_s_barrier(); \
        CFENCE();                     \
    }
#define WAITV(n) asm volatile("s_waitcnt vmcnt(" #n ")" ::: "memory")

__device__ __forceinline__ u16 f2b(float f) {
    u32 u = __builtin_bit_cast(u32, f);
    u += 0x7fffu + ((u >> 16) & 1u);   // round-to-nearest-even
    return (u16)(u >> 16);
}

__device__ __forceinline__ u32 pk2(float a, float b) {
    union { u32 u; __bf16 h[2]; } r;
    r.h[0] = (__bf16)a; r.h[1] = (__bf16)b;
    return r.u;   // v_cvt_pk_bf16_f32
}

__device__ __forceinline__ void gload16(const u16* g, u16* l) {
    __builtin_amdgcn_global_load_lds((const __attribute__((address_space(1))) void*)g,
                                     (__attribute__((address_space(3))) void*)l, 16, 0, 0);
}

// ---------------- weight transpose + f32->bf16 convert (all 10 in one launch) ----------------
struct W10 { const float* p[10]; };
__global__ __launch_bounds__(256) void tcvt_k(W10 wp, u16* __restrict__ WT0) {
    const float* __restrict__ Wm = wp.p[blockIdx.z];
    u16* __restrict__ WT = WT0 + (size_t)blockIdx.z * 1048576;
    __shared__ float t[32][33];
    int bx = blockIdx.x, by = blockIdx.y;
    int tx = threadIdx.x, ty = threadIdx.y;   // (32,8)
#pragma unroll
    for (int j = 0; j < 32; j += 8)
        t[ty + j][tx] = Wm[(size_t)(by * 32 + ty + j) * 1024 + bx * 32 + tx];
    __syncthreads();
#pragma unroll
    for (int j = 0; j < 32; j += 8)
        WT[(size_t)(bx * 32 + ty + j) * 1024 + by * 32 + tx] = f2b(t[tx][ty + j]);
}

// ---------------- per-batch V transpose: V[b][key][c] -> VT[b][c][key]  (c = h*64+dh) ----------------
__global__ __launch_bounds__(256) void vtr_k(const u16* __restrict__ Vg, int ldv, u16* __restrict__ VT) {
    __shared__ u16 t[32][34];
    int bx = blockIdx.x, by = blockIdx.y, b = blockIdx.z;
    int tx = threadIdx.x, ty = threadIdx.y;   // (32,8)
#pragma unroll
    for (int j = 0; j < 32; j += 8)
        t[ty + j][tx] = Vg[(size_t)(b * 1024 + by * 32 + ty + j) * ldv + bx * 32 + tx];
    __syncthreads();
#pragma unroll
    for (int j = 0; j < 32; j += 8)
        VT[(size_t)(b * 1024 + bx * 32 + ty + j) * 1024 + by * 32 + tx] = t[tx][ty + j];
}

// ---------------- fused LayerNorm (block-per-row, proven) ----------------
// MODE bit0: x = in1 + in2 ; bit1: write f32 out (bit3: += post) ; bit2: write bf16 out
template <int MODE>
__global__ __launch_bounds__(256) void ln_k(const float* __restrict__ in1, const float* __restrict__ in2,
                                            const float* __restrict__ gg, const float* __restrict__ bb,
                                            const float* __restrict__ post,
                                            float* __restrict__ of, u16* __restrict__ ob) {
    int row = blockIdx.x, tid = threadIdx.x;
    size_t base = (size_t)row * 1024 + tid * 4;
    float4 x = *(const float4*)(in1 + base);
    if constexpr (MODE & 1) {
        float4 x2 = *(const float4*)(in2 + base);
        x.x += x2.x; x.y += x2.y; x.z += x2.z; x.w += x2.w;
    }
    float s1 = x.x + x.y + x.z + x.w;
    float s2 = x.x * x.x + x.y * x.y + x.z * x.z + x.w * x.w;
#pragma unroll
    for (int m = 32; m >= 1; m >>= 1) { s1 += __shfl_xor(s1, m); s2 += __shfl_xor(s2, m); }
    __shared__ float r1[4], r2[4];
    int lane = tid & 63, w = tid >> 6;
    if (lane == 0) { r1[w] = s1; r2[w] = s2; }
    __syncthreads();
    s1 = r1[0] + r1[1] + r1[2] + r1[3];
    s2 = r2[0] + r2[1] + r2[2] + r2[3];
    float mean = s1 * (1.0f / 1024.0f);
    float var = s2 * (1.0f / 1024.0f) - mean * mean;
    float rstd = rsqrtf(var + 1e-5f);
    float4 gv = *(const float4*)(gg + tid * 4);
    float4 bv = *(const float4*)(bb + tid * 4);
    float y0 = (x.x - mean) * rstd * gv.x + bv.x;
    float y1 = (x.y - mean) * rstd * gv.y + bv.y;
    float y2 = (x.z - mean) * rstd * gv.z + bv.z;
    float y3 = (x.w - mean) * rstd * gv.w + bv.w;
    if constexpr (MODE & 2) {
        float o0 = y0, o1 = y1, o2 = y2, o3 = y3;
        if constexpr (MODE & 8) {
            float4 p = *(const float4*)(post + base);
            o0 += p.x; o1 += p.y; o2 += p.z; o3 += p.w;
        }
        float4 o; o.x = o0; o.y = o1; o.z = o2; o.w = o3;
        *(float4*)(of + base) = o;
    }
    if constexpr (MODE & 4) {
        uint2 pk;
        pk.x = (u32)f2b(y0) | ((u32)f2b(y1) << 16);
        pk.y = (u32)f2b(y2) | ((u32)f2b(y3) << 16);
        *(uint2*)(ob + base) = pk;
    }
}

// ---------------- bf16 GEMM v512b: BM=256/BN=128, 8 waves, 16-MFMA single phase, 3-slot 72KB ring ----------------
// Merged phases: read all 8 frags -> stage t+2 -> BAR -> 16 MFMA -> counted WAITV -> BAR.
// 2 barriers per K-tile (was 4). Swizzle/staging/epilogue identical to r13.
template <int EPI, int NBN>
__global__ __launch_bounds__(512) void gemm512_k(const u16* __restrict__ A, int lda,
                                                 const u16* __restrict__ WT,
                                                 const float* __restrict__ b0, const float* __restrict__ b1,
                                                 const float* __restrict__ b2,
                                                 float sc0, float sc1, float sc2,
                                                 const float* __restrict__ res,
                                                 void* __restrict__ outp, int ldc) {
    constexpr int ASZ = 8192;       // u16 per A slot (256x32)
    constexpr int SLOT = ASZ + 4096;   // + B slot (128x32)
    __shared__ u16 lds[3 * SLOT];
    u16* ldsb = &lds[0];

    int id = blockIdx.x;
    constexpr int NWG = 32 * NBN;
    constexpr int CPX = NWG / 8;
    int swz = (id & 7) * CPX + (id >> 3);   // XCD-contiguous bijective remap
    int bm = swz / NBN, bn = swz % NBN;
    const int m0 = bm * 256, n0 = bn * 128;
    int tid = threadIdx.x, lane = tid & 63, w = tid >> 6;
    int col = lane & 15, fg = lane >> 4;
    int wr = w >> 1, wc = w & 1;

    int swzL = ((col * 32) + fg * 8) ^ ((col >> 1) << 3);
    int aoff0 = wr * 64 * 32 + swzL;        // + m*512 per frag
    int boff0 = ASZ + wc * 64 * 32 + swzL;  // + n*512 per frag

    int r = tid >> 2, g = tid & 3;
    int gr = r ^ ((r >> 3) & 1);
    int gc = g ^ ((r >> 1) & 3);
    const u16* pA = A + (size_t)(m0 + gr) * lda + gc * 8;
    const u16* pB = WT + (size_t)(n0 + gr) * 1024 + gc * 8;

#define STG(t2, snO)                                                                        \
    {                                                                                       \
        gload16(pA + (size_t)(t2) * 32, ldsb + (snO) + w * 512);                            \
        gload16(pA + (size_t)(t2) * 32 + (size_t)128 * lda, ldsb + (snO) + 4096 + w * 512); \
        gload16(pB + (size_t)(t2) * 32, ldsb + (snO) + ASZ + w * 512);                      \
    }
    // note: STG issues 3 loads for waves 0..7? B slot is 4096 u16 = 8KB staged by 512 thr
    // at 16B each = exactly 8KB -> 1 instr per thread. A = 2 instr. Total 3 loads/thread/tile.

    f32x4 acc[4][4];
#pragma unroll
    for (int m = 0; m < 4; m++)
#pragma unroll
        for (int n = 0; n < 4; n++) acc[m][n] = (f32x4){0.f, 0.f, 0.f, 0.f};

    // prologue: stage tiles 0,1; drain tile 0 (leave tile 1's 3 loads in flight)
    STG(0, 0);
    STG(1, SLOT);
    WAITV(3);
    BAR();

    int sc = 0, sn = 2;
    for (int t = 0; t < 32; ++t) {
        int sCur = sc * SLOT, sNxt = sn * SLOT;
        bf16x8 a0[4], bfv[4];
#pragma unroll
        for (int m = 0; m < 4; m++) a0[m] = *(const bf16x8*)&ldsb[sCur + aoff0 + m * 512];
#pragma unroll
        for (int n = 0; n < 4; n++) bfv[n] = *(const bf16x8*)&ldsb[sCur + boff0 + n * 512];
        if (t < 30) STG(t + 2, sNxt);
        BAR();
        __builtin_amdgcn_s_setprio(1);
#pragma unroll
        for (int m = 0; m < 4; m++)
#pragma unroll
            for (int n = 0; n < 4; n++) acc[m][n] = MFMA16(a0[m], bfv[n], acc[m][n]);
        __builtin_amdgcn_s_setprio(0);
        if (t < 30) { WAITV(3); } else if (t == 30) { WAITV(0); }
        BAR();
        sc = (sc == 2) ? 0 : sc + 1;
        sn = (sn == 2) ? 0 : sn + 1;
    }
#undef STG

    int seg = n0 >> 10;
    const float* bp = (seg == 0) ? b0 : (seg == 1 ? b1 : b2);
    float sg = (seg == 0) ? sc0 : (seg == 1 ? sc1 : sc2);
    int nseg = n0 & 1023;
    float bv[4];
#pragma unroll
    for (int n = 0; n < 4; n++) bv[n] = bp[nseg + wc * 64 + n * 16 + col];
#pragma unroll
    for (int m = 0; m < 4; m++) {
#pragma unroll
        for (int rr = 0; rr < 4; rr++) {
            int row = m0 + wr * 64 + m * 16 + fg * 4 + rr;
#pragma unroll
            for (int n = 0; n < 4; n++) {
                int c = n0 + wc * 64 + n * 16 + col;
                size_t idx = (size_t)row * ldc + c;
                float v = (acc[m][n][rr] + bv[n]) * sg;
                if constexpr (EPI == 0) ((u16*)outp)[idx] = f2b(v);
                else if constexpr (EPI == 1) ((u16*)outp)[idx] = f2b(fmaxf(v, 0.f));
                else if constexpr (EPI == 2) ((float*)outp)[idx] = v + res[idx];
            }
        }
    }
}

// ---------------- bf16 GEMM v256b: BM=128/BN=128, 4 waves, 16-MFMA single phase, 3-slot 48KB ring ----------------
template <int EPI, int NBN>
__global__ __launch_bounds__(256) void gemm256_k(const u16* __restrict__ A, int lda,
                                                 const u16* __restrict__ WT,
                                                 const float* __restrict__ b0,
                                                 float sc0,
                                                 const float* __restrict__ res,
                                                 void* __restrict__ outp, int ldc) {
    constexpr int SLOT = 8192;
    __shared__ u16 lds[3 * SLOT];
    int id = blockIdx.x;
    constexpr int NWG = 64 * NBN;
    constexpr int CPX = NWG / 8;
    int swz = (id & 7) * CPX + (id >> 3);
    int bm = swz / NBN, bn = swz % NBN;
    const int m0 = bm * 128, n0 = bn * 128;
    int tid = threadIdx.x, lane = tid & 63, w = tid >> 6;
    int col = lane & 15, fg = lane >> 4;
    int wr = w >> 1, wc = w & 1;

    int swzL = ((col * 32) + fg * 8) ^ ((col >> 1) << 3);
    int aoff0 = wr * 64 * 32 + swzL;
    int boff0 = 4096 + wc * 64 * 32 + swzL;

    int r = tid >> 2, g = tid & 3;
    int gr = r ^ ((r >> 3) & 1);
    int gc = g ^ ((r >> 1) & 3);
    const u16* pA = A + (size_t)(m0 + gr) * lda + gc * 8;
    const u16* pB = WT + (size_t)(n0 + gr) * 1024 + gc * 8;

#define STG(t2, snO)                                                                              \
    {                                                                                             \
        gload16(pA + (size_t)(t2) * 32, lds + (snO) + w * 512);                                   \
        gload16(pA + (size_t)(t2) * 32 + (size_t)64 * lda, lds + (snO) + 2048 + w * 512);         \
        gload16(pB + (size_t)(t2) * 32, lds + (snO) + 4096 + w * 512);                            \
        gload16(pB + (size_t)(t2) * 32 + (size_t)64 * 1024, lds + (snO) + 4096 + 2048 + w * 512); \
    }

    f32x4 acc[4][4];
#pragma unroll
    for (int m = 0; m < 4; m++)
#pragma unroll
        for (int n = 0; n < 4; n++) acc[m][n] = (f32x4){0.f, 0.f, 0.f, 0.f};

    STG(0, 0);
    STG(1, SLOT);
    WAITV(4);
    BAR();

    int sc = 0, sn = 2;
    for (int t = 0; t < 32; ++t) {
        int sCur = sc * SLOT, sNxt = sn * SLOT;
        bf16x8 a0[4], bfv[4];
#pragma unroll
        for (int m = 0; m < 4; m++) a0[m] = *(const bf16x8*)&lds[sCur + aoff0 + m * 512];
#pragma unroll
        for (int n = 0; n < 4; n++) bfv[n] = *(const bf16x8*)&lds[sCur + boff0 + n * 512];
        if (t < 30) STG(t + 2, sNxt);
        BAR();
        __builtin_amdgcn_s_setprio(1);
#pragma unroll
        for (int m = 0; m < 4; m++)
#pragma unroll
            for (int n = 0; n < 4; n++) acc[m][n] = MFMA16(a0[m], bfv[n], acc[m][n]);
        __builtin_amdgcn_s_setprio(0);
        if (t < 30) { WAITV(4); } else if (t == 30) { WAITV(0); }
        BAR();
        sc = (sc == 2) ? 0 : sc + 1;
        sn = (sn == 2) ? 0 : sn + 1;
    }
#undef STG

    float bv[4];
#pragma unroll
    for (int n = 0; n < 4; n++) bv[n] = b0[(n0 & 1023) + wc * 64 + n * 16 + col];
#pragma unroll
    for (int m = 0; m < 4; m++) {
#pragma unroll
        for (int rr = 0; rr < 4; rr++) {
            int row = m0 + wr * 64 + m * 16 + fg * 4 + rr;
#pragma unroll
            for (int n = 0; n < 4; n++) {
                int c = n0 + wc * 64 + n * 16 + col;
                size_t idx = (size_t)row * ldc + c;
                float v = (acc[m][n][rr] + bv[n]) * sc0;
                if constexpr (EPI == 0) ((u16*)outp)[idx] = f2b(v);
                else if constexpr (EPI == 1) ((u16*)outp)[idx] = f2b(fmaxf(v, 0.f));
                else if constexpr (EPI == 2) ((float*)outp)[idx] = v + res[idx];
            }
        }
    }
}

// ---------------- flash attention v5 (r9-best, exact): 8 waves share KVBLK=64 staging; no-max softmax ----------------
__global__ __launch_bounds__(512) void attn_k(const u16* __restrict__ Q, int ldq,
                                              const u16* __restrict__ Kc, int ldk,
                                              const u16* __restrict__ VT,   // [(b*16+h)*64+dh][1024]
                                              const int* __restrict__ mask,
                                              u16* __restrict__ O, int ldo) {
    const int S = 1024;
    int gid = blockIdx.x;
    int bq = gid >> 7, hh = (gid >> 3) & 15, bb = gid & 7;
    int tid = threadIdx.x, lane = tid & 63, w = tid >> 6;   // w 0..7
    int q = lane & 31, hl = lane >> 5;
    int q0w = bq * 256 + w * 32;

    __shared__ u16 sm[18432];   // 36864 B: [buf][ K 64x72 | V^T 64x72 ]
#define KT(b, r, c) sm[(b) * 9216 + (r) * 72 + (c)]
#define VTL(b, r, c) sm[(b) * 9216 + 4608 + (r) * 72 + (c)]

    const u16* Qrow = Q + ((size_t)bb * S + q0w + q) * ldq + hh * 64;
    bool mneg = (mask[bb * S + q0w + q] == 0);
    bf16x8 qf[4];
#pragma unroll
    for (int c = 0; c < 4; c++) {
        qf[c] = *(const bf16x8*)(Qrow + c * 16 + hl * 8);
        if (mneg) qf[c] = (bf16x8)(__bf16)0.f;   // -> sc==0 -> p==1 (uniform)
    }

    float l = 0.f;
    f32x16 oa[2];
#pragma unroll
    for (int i = 0; i < 16; i++) { oa[0][i] = 0.f; oa[1][i] = 0.f; }

    int kk = tid >> 3, ks = tid & 7;
    const u16* gK = Kc + ((size_t)bb * S + kk) * ldk + hh * 64 + ks * 8;
    const u16* gVT = VT + ((size_t)(bb * 16 + hh) * 64 + kk) * 1024 + ks * 8;
    uint4 kr0, vr0;

#define LOADT(t)                                              \
    {                                                         \
        kr0 = *(const uint4*)(gK + (size_t)(t) * 64 * ldk);   \
        vr0 = *(const uint4*)(gVT + (size_t)(t) * 64);        \
    }
#define STORET(bf)                            \
    {                                         \
        *(uint4*)&KT(bf, kk, ks * 8) = kr0;   \
        *(uint4*)&VTL(bf, kk, ks * 8) = vr0;  \
    }

    LOADT(0);
    STORET(0);

    for (int t = 0; t < 16; ++t) {
        int cur = t & 1;
        if (t < 15) LOADT(t + 1);
        __syncthreads();

        f32x16 sc[2];
#pragma unroll
        for (int i = 0; i < 16; i++) { sc[0][i] = 0.f; sc[1][i] = 0.f; }
        __builtin_amdgcn_s_setprio(1);
#pragma unroll
        for (int st = 0; st < 2; st++)
#pragma unroll
            for (int c = 0; c < 4; c++) {
                bf16x8 kf = *(const bf16x8*)&KT(cur, st * 32 + q, c * 16 + hl * 8);
                sc[st] = MFMA32(kf, qf[c], sc[st]);
            }
        __builtin_amdgcn_s_setprio(0);

#pragma unroll
        for (int st = 0; st < 2; st++)
#pragma unroll
            for (int rr = 0; rr < 16; rr++) sc[st][rr] = exp2f(sc[st][rr]);
        float ts[8];
#pragma unroll
        for (int i = 0; i < 8; i++)
            ts[i] = (sc[0][i] + sc[0][i + 8]) + (sc[1][i] + sc[1][i + 8]);
#pragma unroll
        for (int i = 0; i < 4; i++) ts[i] += ts[i + 4];
        l += (ts[0] + ts[2]) + (ts[1] + ts[3]);

        __builtin_amdgcn_s_setprio(1);
#pragma unroll
        for (int st = 0; st < 2; st++) {
            u32 wv[8];
#pragma unroll
            for (int j = 0; j < 8; j++) wv[j] = pk2(sc[st][2 * j], sc[st][2 * j + 1]);
            PLSWAP(wv[0], wv[2]); PLSWAP(wv[1], wv[3]);
            PLSWAP(wv[4], wv[6]); PLSWAP(wv[5], wv[7]);
#pragma unroll
            for (int c = 0; c < 2; c++) {
                union { u32 u[4]; bf16x8 v; } pb;
                pb.u[0] = wv[c * 4 + 0]; pb.u[1] = wv[c * 4 + 1];
                pb.u[2] = wv[c * 4 + 2]; pb.u[3] = wv[c * 4 + 3];
#pragma unroll
                for (int dd = 0; dd < 2; dd++) {
                    bf16x8 vf = *(const bf16x8*)&VTL(cur, dd * 32 + q, st * 32 + c * 16 + hl * 8);
                    oa[dd] = MFMA32(vf, pb.v, oa[dd]);
                }
            }
        }
        __builtin_amdgcn_s_setprio(0);

        if (t < 15) STORET(cur ^ 1);
    }

    l += __shfl_xor(l, 32);
    __syncthreads();
    float inv = 1.0f / l;
    u16* otw = sm + w * 2304;
#pragma unroll
    for (int dd = 0; dd < 2; dd++)
#pragma unroll
        for (int rr = 0; rr < 16; rr++) {
            int d = (rr & 3) + 8 * (rr >> 2) + 4 * hl + 32 * dd;
            otw[q * 72 + d] = f2b(oa[dd][rr] * inv);
        }
    __syncthreads();
    size_t obase = ((size_t)bb * S + q0w) * ldo + hh * 64;
#pragma unroll
    for (int i = 0; i < 4; i++) {
        int row = i * 8 + (lane >> 3);
        uint4 vdat = *(const uint4*)&otw[row * 72 + (lane & 7) * 8];
        *(uint4*)(O + obase + (size_t)row * ldo + (lane & 7) * 8) = vdat;
    }
#undef KT
#undef VTL
#undef LOADT
#undef STORET
}

extern "C" void kernel_launch(void* const* d_in, const int* in_sizes, int n_in,
                              void* d_out, int out_size, void* d_ws, size_t ws_size,
                              hipStream_t stream) {
    (void)in_sizes; (void)n_in; (void)out_size; (void)ws_size;
    const float* x = (const float*)d_in[0];
    const float* h = (const float*)d_in[1];
    const int* mask = (const int*)d_in[2];
    const float* W[10];
    const float* Bv[10];
    for (int i = 0; i < 10; i++) { W[i] = (const float*)d_in[3 + i]; Bv[i] = (const float*)d_in[13 + i]; }
    const float *ln1g = (const float*)d_in[23], *ln1b = (const float*)d_in[24];
    const float *ln2g = (const float*)d_in[25], *ln2b = (const float*)d_in[26];
    const float *ln3g = (const float*)d_in[27], *ln3b = (const float*)d_in[28];
    const float *lnhg = (const float*)d_in[29], *lnhb = (const float*)d_in[30];
    const float *flng = (const float*)d_in[31], *flnb = (const float*)d_in[32];

    const float SCLE = 0.18033688011112042f;   // log2(e)/sqrt(64)

    char* ws = (char*)d_ws;
    size_t off = 0;
    auto alloc = [&](size_t bytes) -> char* {
        char* p = ws + off;
        off += (bytes + 255) & ~(size_t)255;
        return p;
    };
    const size_t MT = (size_t)8192 * 1024;
    u16* wtb = (u16*)alloc((size_t)10 * 1048576 * 2);
    u16* wt[10];
    for (int i = 0; i < 10; i++) wt[i] = wtb + (size_t)i * 1048576;
    u16* qkv = (u16*)alloc((size_t)8192 * 3072 * 2);   // sa QKV; later ca kv + ff1
    u16* kv = qkv;
    u16* kb = qkv + (size_t)8192 * 2048;
    u16* bufA = (u16*)alloc(MT * 2);
    u16* qb   = (u16*)alloc(MT * 2);          // ca Q, then ca attention out
    float* hid_in  = (float*)alloc(MT * 4);
    float* hid_mid = (float*)alloc(MT * 4);
    float* yf      = (float*)alloc(MT * 4);
    u16* hn = (u16*)yf;                        // hn lifetime disjoint from yf (FFN)
    u16* vt_sa = bufA;                         // V^T alias: free between QKV-gemm and ln2
    u16* vt_ca = (u16*)hid_mid;                // V^T alias: free between kv-gemm and ca-wo gemm
    float* outF = (float*)d_out;

    W10 wp;
    for (int i = 0; i < 10; i++) wp.p[i] = W[i];
    tcvt_k<<<dim3(32, 32, 10), dim3(32, 8), 0, stream>>>(wp, wtb);

    // ---- self-attention block ----
    ln_k<4><<<8192, 256, 0, stream>>>(x, nullptr, ln1g, ln1b, nullptr, nullptr, bufA);
    gemm512_k<0, 24><<<768, 512, 0, stream>>>(bufA, 1024, wt[0], Bv[0], Bv[1], Bv[2], SCLE, 1.f, 1.f, nullptr, qkv, 3072);
    vtr_k<<<dim3(32, 32, 8), dim3(32, 8), 0, stream>>>(qkv + 2048, 3072, vt_sa);
    attn_k<<<512, 512, 0, stream>>>(qkv, 3072, qkv + 1024, 3072, vt_sa, mask, qkv, 3072);
    gemm256_k<2, 8><<<512, 256, 0, stream>>>(qkv, 3072, wt[3], Bv[3], 1.f, x, hid_in, 1024);

    // ---- cross-attention block ----
    ln_k<4><<<8192, 256, 0, stream>>>(hid_in, nullptr, ln2g, ln2b, nullptr, nullptr, bufA);
    ln_k<4><<<8192, 256, 0, stream>>>(h, nullptr, lnhg, lnhb, nullptr, nullptr, hn);
    gemm256_k<0, 8><<<512, 256, 0, stream>>>(bufA, 1024, wt[4], Bv[4], SCLE, nullptr, qb, 1024);
    gemm512_k<0, 16><<<512, 512, 0, stream>>>(hn, 1024, wt[5], Bv[5], Bv[6], Bv[6], 1.f, 1.f, 1.f, nullptr, kv, 2048);
    vtr_k<<<dim3(32, 32, 8), dim3(32, 8), 0, stream>>>(kv + 1024, 2048, vt_ca);
    attn_k<<<512, 512, 0, stream>>>(qb, 1024, kv, 2048, vt_ca, mask, qb, 1024);
    gemm256_k<2, 8><<<512, 256, 0, stream>>>(qb, 1024, wt[7], Bv[7], 1.f, hid_in, hid_mid, 1024);

    // ---- FFN block ----
    ln_k<6><<<8192, 256, 0, stream>>>(hid_mid, nullptr, ln3g, ln3b, nullptr, yf, bufA);
    gemm256_k<1, 8><<<512, 256, 0, stream>>>(bufA, 1024, wt[8], Bv[8], 1.f, nullptr, kb, 1024);
    gemm256_k<2, 8><<<512, 256, 0, stream>>>(kb, 1024, wt[9], Bv[9], 1.f, yf, hid_in, 1024);
    ln_k<10><<<8192, 256, 0, stream>>>(hid_in, nullptr, flng, flnb, hid_mid, outF, nullptr);
}

// Round 15
// 445.974 us; speedup vs baseline: 1.0402x; 1.0065x over previous
//
#include <hip/hip_runtime.h>

typedef unsigned short u16;
typedef unsigned int u32;
typedef float f32x4 __attribute__((ext_vector_type(4)));
typedef float f32x16 __attribute__((ext_vector_type(16)));
typedef __bf16 bf16x8 __attribute__((ext_vector_type(8)));

#define MFMA16(a, b, c) __builtin_amdgcn_mfma_f32_16x16x32_bf16(a, b, c, 0, 0, 0)
#define MFMA32(a, b, c) __builtin_amdgcn_mfma_f32_32x32x16_bf16(a, b, c, 0, 0, 0)
#define PLSWAP(x, y) asm volatile("v_permlane32_swap_b32 %0, %1" : "+v"(x), "+v"(y))
#define CFENCE() asm volatile("" ::: "memory")
#define BAR()                         \
    {                                 \
        CFENCE();                     \
        __builtin_amdgcn_s_barrier(); \
        CFENCE();                     \
    }
#define WAITV(n) asm volatile("s_waitcnt vmcnt(" #n ")" ::: "memory")

__device__ __forceinline__ u16 f2b(float f) {
    u32 u = __builtin_bit_cast(u32, f);
    u += 0x7fffu + ((u >> 16) & 1u);   // round-to-nearest-even
    return (u16)(u >> 16);
}

__device__ __forceinline__ u32 pk2(float a, float b) {
    union { u32 u; __bf16 h[2]; } r;
    r.h[0] = (__bf16)a; r.h[1] = (__bf16)b;
    return r.u;   // v_cvt_pk_bf16_f32
}

__device__ __forceinline__ void gload16(const u16* g, u16* l) {
    __builtin_amdgcn_global_load_lds((const __attribute__((address_space(1))) void*)g,
                                     (__attribute__((address_space(3))) void*)l, 16, 0, 0);
}

// ---------------- weight transpose + f32->bf16 convert (all 10 in one launch) ----------------
struct W10 { const float* p[10]; };
__global__ __launch_bounds__(256) void tcvt_k(W10 wp, u16* __restrict__ WT0) {
    const float* __restrict__ Wm = wp.p[blockIdx.z];
    u16* __restrict__ WT = WT0 + (size_t)blockIdx.z * 1048576;
    __shared__ float t[32][33];
    int bx = blockIdx.x, by = blockIdx.y;
    int tx = threadIdx.x, ty = threadIdx.y;   // (32,8)
#pragma unroll
    for (int j = 0; j < 32; j += 8)
        t[ty + j][tx] = Wm[(size_t)(by * 32 + ty + j) * 1024 + bx * 32 + tx];
    __syncthreads();
#pragma unroll
    for (int j = 0; j < 32; j += 8)
        WT[(size_t)(bx * 32 + ty + j) * 1024 + by * 32 + tx] = f2b(t[tx][ty + j]);
}

// ---------------- per-batch V transpose: V[b][key][c] -> VT[b][c][key]  (c = h*64+dh) ----------------
__global__ __launch_bounds__(256) void vtr_k(const u16* __restrict__ Vg, int ldv, u16* __restrict__ VT) {
    __shared__ u16 t[32][34];
    int bx = blockIdx.x, by = blockIdx.y, b = blockIdx.z;
    int tx = threadIdx.x, ty = threadIdx.y;   // (32,8)
#pragma unroll
    for (int j = 0; j < 32; j += 8)
        t[ty + j][tx] = Vg[(size_t)(b * 1024 + by * 32 + ty + j) * ldv + bx * 32 + tx];
    __syncthreads();
#pragma unroll
    for (int j = 0; j < 32; j += 8)
        VT[(size_t)(b * 1024 + bx * 32 + ty + j) * 1024 + by * 32 + tx] = t[tx][ty + j];
}

// ---------------- fused LayerNorm (block-per-row, proven) ----------------
// MODE bit0: x = in1 + in2 ; bit1: write f32 out (bit3: += post) ; bit2: write bf16 out
template <int MODE>
__global__ __launch_bounds__(256) void ln_k(const float* __restrict__ in1, const float* __restrict__ in2,
                                            const float* __restrict__ gg, const float* __restrict__ bb,
                                            const float* __restrict__ post,
                                            float* __restrict__ of, u16* __restrict__ ob) {
    int row = blockIdx.x, tid = threadIdx.x;
    size_t base = (size_t)row * 1024 + tid * 4;
    float4 x = *(const float4*)(in1 + base);
    if constexpr (MODE & 1) {
        float4 x2 = *(const float4*)(in2 + base);
        x.x += x2.x; x.y += x2.y; x.z += x2.z; x.w += x2.w;
    }
    float s1 = x.x + x.y + x.z + x.w;
    float s2 = x.x * x.x + x.y * x.y + x.z * x.z + x.w * x.w;
#pragma unroll
    for (int m = 32; m >= 1; m >>= 1) { s1 += __shfl_xor(s1, m); s2 += __shfl_xor(s2, m); }
    __shared__ float r1[4], r2[4];
    int lane = tid & 63, w = tid >> 6;
    if (lane == 0) { r1[w] = s1; r2[w] = s2; }
    __syncthreads();
    s1 = r1[0] + r1[1] + r1[2] + r1[3];
    s2 = r2[0] + r2[1] + r2[2] + r2[3];
    float mean = s1 * (1.0f / 1024.0f);
    float var = s2 * (1.0f / 1024.0f) - mean * mean;
    float rstd = rsqrtf(var + 1e-5f);
    float4 gv = *(const float4*)(gg + tid * 4);
    float4 bv = *(const float4*)(bb + tid * 4);
    float y0 = (x.x - mean) * rstd * gv.x + bv.x;
    float y1 = (x.y - mean) * rstd * gv.y + bv.y;
    float y2 = (x.z - mean) * rstd * gv.z + bv.z;
    float y3 = (x.w - mean) * rstd * gv.w + bv.w;
    if constexpr (MODE & 2) {
        float o0 = y0, o1 = y1, o2 = y2, o3 = y3;
        if constexpr (MODE & 8) {
            float4 p = *(const float4*)(post + base);
            o0 += p.x; o1 += p.y; o2 += p.z; o3 += p.w;
        }
        float4 o; o.x = o0; o.y = o1; o.z = o2; o.w = o3;
        *(float4*)(of + base) = o;
    }
    if constexpr (MODE & 4) {
        uint2 pk;
        pk.x = (u32)f2b(y0) | ((u32)f2b(y1) << 16);
        pk.y = (u32)f2b(y2) | ((u32)f2b(y3) << 16);
        *(uint2*)(ob + base) = pk;
    }
}

// ---------------- bf16 GEMM v512 (r13 phase-split — measured best for 8-wave): BM=256/BN=128 ----------------
template <int EPI, int NBN>
__global__ __launch_bounds__(512) void gemm512_k(const u16* __restrict__ A, int lda,
                                                 const u16* __restrict__ WT,
                                                 const float* __restrict__ b0, const float* __restrict__ b1,
                                                 const float* __restrict__ b2,
                                                 float sc0, float sc1, float sc2,
                                                 const float* __restrict__ res,
                                                 void* __restrict__ outp, int ldc) {
    constexpr int ASZ = 8192;
    constexpr int SLOT = ASZ + 4096;
    __shared__ u16 lds[3 * SLOT];
    u16* ldsb = &lds[0];

    int id = blockIdx.x;
    constexpr int NWG = 32 * NBN;
    constexpr int CPX = NWG / 8;
    int swz = (id & 7) * CPX + (id >> 3);   // XCD-contiguous bijective remap
    int bm = swz / NBN, bn = swz % NBN;
    const int m0 = bm * 256, n0 = bn * 128;
    int tid = threadIdx.x, lane = tid & 63, w = tid >> 6;
    int col = lane & 15, fg = lane >> 4;
    int wr = w >> 1, wc = w & 1;

    int swzL = ((col * 32) + fg * 8) ^ ((col >> 1) << 3);
    int aoff0 = wr * 64 * 32 + swzL;
    int boff0 = ASZ + wc * 64 * 32 + swzL;

    int r = tid >> 2, g = tid & 3;
    int gr = r ^ ((r >> 3) & 1);
    int gc = g ^ ((r >> 1) & 3);
    const u16* pA = A + (size_t)(m0 + gr) * lda + gc * 8;
    const u16* pB = WT + (size_t)(n0 + gr) * 1024 + gc * 8;

#define STGA(t2, snO)                                                                       \
    {                                                                                       \
        gload16(pA + (size_t)(t2) * 32, ldsb + (snO) + w * 512);                            \
        gload16(pA + (size_t)(t2) * 32 + (size_t)128 * lda, ldsb + (snO) + 4096 + w * 512); \
    }
#define STGB(t2, snO)                                                   \
    {                                                                   \
        gload16(pB + (size_t)(t2) * 32, ldsb + (snO) + ASZ + w * 512);  \
    }

    f32x4 acc[4][4];
#pragma unroll
    for (int m = 0; m < 4; m++)
#pragma unroll
        for (int n = 0; n < 4; n++) acc[m][n] = (f32x4){0.f, 0.f, 0.f, 0.f};

    STGA(0, 0); STGB(0, 0);
    STGA(1, SLOT); STGB(1, SLOT);
    WAITV(3);
    BAR();

    int sc = 0, sn = 2;
    for (int t = 0; t < 32; ++t) {
        int sCur = sc * SLOT, sNxt = sn * SLOT;
        // ---- phase 0: A-frags + first 2 B-frags, stage A of t+2, 8 MFMA ----
        bf16x8 a0[4], bfv[2];
#pragma unroll
        for (int m = 0; m < 4; m++) a0[m] = *(const bf16x8*)&ldsb[sCur + aoff0 + m * 512];
#pragma unroll
        for (int n = 0; n < 2; n++) bfv[n] = *(const bf16x8*)&ldsb[sCur + boff0 + n * 512];
        if (t < 30) STGA(t + 2, sNxt);
        BAR();
        __builtin_amdgcn_s_setprio(1);
#pragma unroll
        for (int m = 0; m < 4; m++)
#pragma unroll
            for (int n = 0; n < 2; n++) acc[m][n] = MFMA16(a0[m], bfv[n], acc[m][n]);
        __builtin_amdgcn_s_setprio(0);
        BAR();
        // ---- phase 1: last 2 B-frags, stage B of t+2, 8 MFMA, counted wait ----
        bf16x8 b2[2];
#pragma unroll
        for (int n = 0; n < 2; n++) b2[n] = *(const bf16x8*)&ldsb[sCur + boff0 + (n + 2) * 512];
        if (t < 30) STGB(t + 2, sNxt);
        BAR();
        __builtin_amdgcn_s_setprio(1);
#pragma unroll
        for (int m = 0; m < 4; m++)
#pragma unroll
            for (int n = 0; n < 2; n++) acc[m][n + 2] = MFMA16(a0[m], b2[n], acc[m][n + 2]);
        __builtin_amdgcn_s_setprio(0);
        if (t < 30) { WAITV(3); } else if (t == 30) { WAITV(0); }
        BAR();
        sc = (sc == 2) ? 0 : sc + 1;
        sn = (sn == 2) ? 0 : sn + 1;
    }
#undef STGA
#undef STGB

    int seg = n0 >> 10;
    const float* bp = (seg == 0) ? b0 : (seg == 1 ? b1 : b2);
    float sg = (seg == 0) ? sc0 : (seg == 1 ? sc1 : sc2);
    int nseg = n0 & 1023;
    float bv[4];
#pragma unroll
    for (int n = 0; n < 4; n++) bv[n] = bp[nseg + wc * 64 + n * 16 + col];
#pragma unroll
    for (int m = 0; m < 4; m++) {
#pragma unroll
        for (int rr = 0; rr < 4; rr++) {
            int row = m0 + wr * 64 + m * 16 + fg * 4 + rr;
#pragma unroll
            for (int n = 0; n < 4; n++) {
                int c = n0 + wc * 64 + n * 16 + col;
                size_t idx = (size_t)row * ldc + c;
                float v = (acc[m][n][rr] + bv[n]) * sg;
                if constexpr (EPI == 0) ((u16*)outp)[idx] = f2b(v);
                else if constexpr (EPI == 1) ((u16*)outp)[idx] = f2b(fmaxf(v, 0.f));
                else if constexpr (EPI == 2) ((float*)outp)[idx] = v + res[idx];
            }
        }
    }
}

// ---------------- bf16 GEMM v256b (r14 merged — measured best for 4-wave): BM=128/BN=128 ----------------
template <int EPI, int NBN>
__global__ __launch_bounds__(256) void gemm256_k(const u16* __restrict__ A, int lda,
                                                 const u16* __restrict__ WT,
                                                 const float* __restrict__ b0,
                                                 float sc0,
                                                 const float* __restrict__ res,
                                                 void* __restrict__ outp, int ldc) {
    constexpr int SLOT = 8192;
    __shared__ u16 lds[3 * SLOT];
    int id = blockIdx.x;
    constexpr int NWG = 64 * NBN;
    constexpr int CPX = NWG / 8;
    int swz = (id & 7) * CPX + (id >> 3);
    int bm = swz / NBN, bn = swz % NBN;
    const int m0 = bm * 128, n0 = bn * 128;
    int tid = threadIdx.x, lane = tid & 63, w = tid >> 6;
    int col = lane & 15, fg = lane >> 4;
    int wr = w >> 1, wc = w & 1;

    int swzL = ((col * 32) + fg * 8) ^ ((col >> 1) << 3);
    int aoff0 = wr * 64 * 32 + swzL;
    int boff0 = 4096 + wc * 64 * 32 + swzL;

    int r = tid >> 2, g = tid & 3;
    int gr = r ^ ((r >> 3) & 1);
    int gc = g ^ ((r >> 1) & 3);
    const u16* pA = A + (size_t)(m0 + gr) * lda + gc * 8;
    const u16* pB = WT + (size_t)(n0 + gr) * 1024 + gc * 8;

#define STG(t2, snO)                                                                              \
    {                                                                                             \
        gload16(pA + (size_t)(t2) * 32, lds + (snO) + w * 512);                                   \
        gload16(pA + (size_t)(t2) * 32 + (size_t)64 * lda, lds + (snO) + 2048 + w * 512);         \
        gload16(pB + (size_t)(t2) * 32, lds + (snO) + 4096 + w * 512);                            \
        gload16(pB + (size_t)(t2) * 32 + (size_t)64 * 1024, lds + (snO) + 4096 + 2048 + w * 512); \
    }

    f32x4 acc[4][4];
#pragma unroll
    for (int m = 0; m < 4; m++)
#pragma unroll
        for (int n = 0; n < 4; n++) acc[m][n] = (f32x4){0.f, 0.f, 0.f, 0.f};

    STG(0, 0);
    STG(1, SLOT);
    WAITV(4);
    BAR();

    int sc = 0, sn = 2;
    for (int t = 0; t < 32; ++t) {
        int sCur = sc * SLOT, sNxt = sn * SLOT;
        bf16x8 a0[4], bfv[4];
#pragma unroll
        for (int m = 0; m < 4; m++) a0[m] = *(const bf16x8*)&lds[sCur + aoff0 + m * 512];
#pragma unroll
        for (int n = 0; n < 4; n++) bfv[n] = *(const bf16x8*)&lds[sCur + boff0 + n * 512];
        if (t < 30) STG(t + 2, sNxt);
        BAR();
        __builtin_amdgcn_s_setprio(1);
#pragma unroll
        for (int m = 0; m < 4; m++)
#pragma unroll
            for (int n = 0; n < 4; n++) acc[m][n] = MFMA16(a0[m], bfv[n], acc[m][n]);
        __builtin_amdgcn_s_setprio(0);
        if (t < 30) { WAITV(4); } else if (t == 30) { WAITV(0); }
        BAR();
        sc = (sc == 2) ? 0 : sc + 1;
        sn = (sn == 2) ? 0 : sn + 1;
    }
#undef STG

    float bv[4];
#pragma unroll
    for (int n = 0; n < 4; n++) bv[n] = b0[(n0 & 1023) + wc * 64 + n * 16 + col];
#pragma unroll
    for (int m = 0; m < 4; m++) {
#pragma unroll
        for (int rr = 0; rr < 4; rr++) {
            int row = m0 + wr * 64 + m * 16 + fg * 4 + rr;
#pragma unroll
            for (int n = 0; n < 4; n++) {
                int c = n0 + wc * 64 + n * 16 + col;
                size_t idx = (size_t)row * ldc + c;
                float v = (acc[m][n][rr] + bv[n]) * sc0;
                if constexpr (EPI == 0) ((u16*)outp)[idx] = f2b(v);
                else if constexpr (EPI == 1) ((u16*)outp)[idx] = f2b(fmaxf(v, 0.f));
                else if constexpr (EPI == 2) ((float*)outp)[idx] = v + res[idx];
            }
        }
    }
}

// ---------------- flash attention v5 (r9-best, exact): 8 waves share KVBLK=64 staging; no-max softmax ----------------
__global__ __launch_bounds__(512) void attn_k(const u16* __restrict__ Q, int ldq,
                                              const u16* __restrict__ Kc, int ldk,
                                              const u16* __restrict__ VT,   // [(b*16+h)*64+dh][1024]
                                              const int* __restrict__ mask,
                                              u16* __restrict__ O, int ldo) {
    const int S = 1024;
    int gid = blockIdx.x;
    int bq = gid >> 7, hh = (gid >> 3) & 15, bb = gid & 7;
    int tid = threadIdx.x, lane = tid & 63, w = tid >> 6;   // w 0..7
    int q = lane & 31, hl = lane >> 5;
    int q0w = bq * 256 + w * 32;

    __shared__ u16 sm[18432];   // 36864 B: [buf][ K 64x72 | V^T 64x72 ]
#define KT(b, r, c) sm[(b) * 9216 + (r) * 72 + (c)]
#define VTL(b, r, c) sm[(b) * 9216 + 4608 + (r) * 72 + (c)]

    const u16* Qrow = Q + ((size_t)bb * S + q0w + q) * ldq + hh * 64;
    bool mneg = (mask[bb * S + q0w + q] == 0);
    bf16x8 qf[4];
#pragma unroll
    for (int c = 0; c < 4; c++) {
        qf[c] = *(const bf16x8*)(Qrow + c * 16 + hl * 8);
        if (mneg) qf[c] = (bf16x8)(__bf16)0.f;   // -> sc==0 -> p==1 (uniform)
    }

    float l = 0.f;
    f32x16 oa[2];
#pragma unroll
    for (int i = 0; i < 16; i++) { oa[0][i] = 0.f; oa[1][i] = 0.f; }

    int kk = tid >> 3, ks = tid & 7;
    const u16* gK = Kc + ((size_t)bb * S + kk) * ldk + hh * 64 + ks * 8;
    const u16* gVT = VT + ((size_t)(bb * 16 + hh) * 64 + kk) * 1024 + ks * 8;
    uint4 kr0, vr0;

#define LOADT(t)                                              \
    {                                                         \
        kr0 = *(const uint4*)(gK + (size_t)(t) * 64 * ldk);   \
        vr0 = *(const uint4*)(gVT + (size_t)(t) * 64);        \
    }
#define STORET(bf)                            \
    {                                         \
        *(uint4*)&KT(bf, kk, ks * 8) = kr0;   \
        *(uint4*)&VTL(bf, kk, ks * 8) = vr0;  \
    }

    LOADT(0);
    STORET(0);

    for (int t = 0; t < 16; ++t) {
        int cur = t & 1;
        if (t < 15) LOADT(t + 1);
        __syncthreads();

        f32x16 sc[2];
#pragma unroll
        for (int i = 0; i < 16; i++) { sc[0][i] = 0.f; sc[1][i] = 0.f; }
        __builtin_amdgcn_s_setprio(1);
#pragma unroll
        for (int st = 0; st < 2; st++)
#pragma unroll
            for (int c = 0; c < 4; c++) {
                bf16x8 kf = *(const bf16x8*)&KT(cur, st * 32 + q, c * 16 + hl * 8);
                sc[st] = MFMA32(kf, qf[c], sc[st]);
            }
        __builtin_amdgcn_s_setprio(0);

#pragma unroll
        for (int st = 0; st < 2; st++)
#pragma unroll
            for (int rr = 0; rr < 16; rr++) sc[st][rr] = exp2f(sc[st][rr]);
        float ts[8];
#pragma unroll
        for (int i = 0; i < 8; i++)
            ts[i] = (sc[0][i] + sc[0][i + 8]) + (sc[1][i] + sc[1][i + 8]);
#pragma unroll
        for (int i = 0; i < 4; i++) ts[i] += ts[i + 4];
        l += (ts[0] + ts[2]) + (ts[1] + ts[3]);

        __builtin_amdgcn_s_setprio(1);
#pragma unroll
        for (int st = 0; st < 2; st++) {
            u32 wv[8];
#pragma unroll
            for (int j = 0; j < 8; j++) wv[j] = pk2(sc[st][2 * j], sc[st][2 * j + 1]);
            PLSWAP(wv[0], wv[2]); PLSWAP(wv[1], wv[3]);
            PLSWAP(wv[4], wv[6]); PLSWAP(wv[5], wv[7]);
#pragma unroll
            for (int c = 0; c < 2; c++) {
                union { u32 u[4]; bf16x8 v; } pb;
                pb.u[0] = wv[c * 4 + 0]; pb.u[1] = wv[c * 4 + 1];
                pb.u[2] = wv[c * 4 + 2]; pb.u[3] = wv[c * 4 + 3];
#pragma unroll
                for (int dd = 0; dd < 2; dd++) {
                    bf16x8 vf = *(const bf16x8*)&VTL(cur, dd * 32 + q, st * 32 + c * 16 + hl * 8);
                    oa[dd] = MFMA32(vf, pb.v, oa[dd]);
                }
            }
        }
        __builtin_amdgcn_s_setprio(0);

        if (t < 15) STORET(cur ^ 1);
    }

    l += __shfl_xor(l, 32);
    __syncthreads();
    float inv = 1.0f / l;
    u16* otw = sm + w * 2304;
#pragma unroll
    for (int dd = 0; dd < 2; dd++)
#pragma unroll
        for (int rr = 0; rr < 16; rr++) {
            int d = (rr & 3) + 8 * (rr >> 2) + 4 * hl + 32 * dd;
            otw[q * 72 + d] = f2b(oa[dd][rr] * inv);
        }
    __syncthreads();
    size_t obase = ((size_t)bb * S + q0w) * ldo + hh * 64;
#pragma unroll
    for (int i = 0; i < 4; i++) {
        int row = i * 8 + (lane >> 3);
        uint4 vdat = *(const uint4*)&otw[row * 72 + (lane & 7) * 8];
        *(uint4*)(O + obase + (size_t)row * ldo + (lane & 7) * 8) = vdat;
    }
#undef KT
#undef VTL
#undef LOADT
#undef STORET
}

extern "C" void kernel_launch(void* const* d_in, const int* in_sizes, int n_in,
                              void* d_out, int out_size, void* d_ws, size_t ws_size,
                              hipStream_t stream) {
    (void)in_sizes; (void)n_in; (void)out_size; (void)ws_size;
    const float* x = (const float*)d_in[0];
    const float* h = (const float*)d_in[1];
    const int* mask = (const int*)d_in[2];
    const float* W[10];
    const float* Bv[10];
    for (int i = 0; i < 10; i++) { W[i] = (const float*)d_in[3 + i]; Bv[i] = (const float*)d_in[13 + i]; }
    const float *ln1g = (const float*)d_in[23], *ln1b = (const float*)d_in[24];
    const float *ln2g = (const float*)d_in[25], *ln2b = (const float*)d_in[26];
    const float *ln3g = (const float*)d_in[27], *ln3b = (const float*)d_in[28];
    const float *lnhg = (const float*)d_in[29], *lnhb = (const float*)d_in[30];
    const float *flng = (const float*)d_in[31], *flnb = (const float*)d_in[32];

    const float SCLE = 0.18033688011112042f;   // log2(e)/sqrt(64)

    char* ws = (char*)d_ws;
    size_t off = 0;
    auto alloc = [&](size_t bytes) -> char* {
        char* p = ws + off;
        off += (bytes + 255) & ~(size_t)255;
        return p;
    };
    const size_t MT = (size_t)8192 * 1024;
    u16* wtb = (u16*)alloc((size_t)10 * 1048576 * 2);
    u16* wt[10];
    for (int i = 0; i < 10; i++) wt[i] = wtb + (size_t)i * 1048576;
    u16* qkv = (u16*)alloc((size_t)8192 * 3072 * 2);   // sa QKV; later ca kv + ff1
    u16* kv = qkv;
    u16* kb = qkv + (size_t)8192 * 2048;
    u16* bufA = (u16*)alloc(MT * 2);
    u16* qb   = (u16*)alloc(MT * 2);          // ca Q, then ca attention out
    float* hid_in  = (float*)alloc(MT * 4);
    float* hid_mid = (float*)alloc(MT * 4);
    float* yf      = (float*)alloc(MT * 4);
    u16* hn = (u16*)yf;                        // hn lifetime disjoint from yf (FFN)
    u16* vt_sa = bufA;                         // V^T alias: free between QKV-gemm and ln2
    u16* vt_ca = (u16*)hid_mid;                // V^T alias: free between kv-gemm and ca-wo gemm
    float* outF = (float*)d_out;

    W10 wp;
    for (int i = 0; i < 10; i++) wp.p[i] = W[i];
    tcvt_k<<<dim3(32, 32, 10), dim3(32, 8), 0, stream>>>(wp, wtb);

    // ---- self-attention block ----
    ln_k<4><<<8192, 256, 0, stream>>>(x, nullptr, ln1g, ln1b, nullptr, nullptr, bufA);
    gemm512_k<0, 24><<<768, 512, 0, stream>>>(bufA, 1024, wt[0], Bv[0], Bv[1], Bv[2], SCLE, 1.f, 1.f, nullptr, qkv, 3072);
    vtr_k<<<dim3(32, 32, 8), dim3(32, 8), 0, stream>>>(qkv + 2048, 3072, vt_sa);
    attn_k<<<512, 512, 0, stream>>>(qkv, 3072, qkv + 1024, 3072, vt_sa, mask, qkv, 3072);
    gemm256_k<2, 8><<<512, 256, 0, stream>>>(qkv, 3072, wt[3], Bv[3], 1.f, x, hid_in, 1024);

    // ---- cross-attention block ----
    ln_k<4><<<8192, 256, 0, stream>>>(hid_in, nullptr, ln2g, ln2b, nullptr, nullptr, bufA);
    ln_k<4><<<8192, 256, 0, stream>>>(h, nullptr, lnhg, lnhb, nullptr, nullptr, hn);
    gemm256_k<0, 8><<<512, 256, 0, stream>>>(bufA, 1024, wt[4], Bv[4], SCLE, nullptr, qb, 1024);
    gemm512_k<0, 16><<<512, 512, 0, stream>>>(hn, 1024, wt[5], Bv[5], Bv[6], Bv[6], 1.f, 1.f, 1.f, nullptr, kv, 2048);
    vtr_k<<<dim3(32, 32, 8), dim3(32, 8), 0, stream>>>(kv + 1024, 2048, vt_ca);
    attn_k<<<512, 512, 0, stream>>>(qb, 1024, kv, 2048, vt_ca, mask, qb, 1024);
    gemm256_k<2, 8><<<512, 256, 0, stream>>>(qb, 1024, wt[7], Bv[7], 1.f, hid_in, hid_mid, 1024);

    // ---- FFN block ----
    ln_k<6><<<8192, 256, 0, stream>>>(hid_mid, nullptr, ln3g, ln3b, nullptr, yf, bufA);
    gemm256_k<1, 8><<<512, 256, 0, stream>>>(bufA, 1024, wt[8], Bv[8], 1.f, nullptr, kb, 1024);
    gemm256_k<2, 8><<<512, 256, 0, stream>>>(kb, 1024, wt[9], Bv[9], 1.f, yf, hid_in, 1024);
    ln_k<10><<<8192, 256, 0, stream>>>(hid_in, nullptr, flng, flnb, hid_mid, outF, nullptr);
}

// Round 16
// 443.545 us; speedup vs baseline: 1.0459x; 1.0055x over previous
//
#include <hip/hip_runtime.h>

typedef unsigned short u16;
typedef unsigned int u32;
typedef float f32x4 __attribute__((ext_vector_type(4)));
typedef float f32x16 __attribute__((ext_vector_type(16)));
typedef __bf16 bf16x8 __attribute__((ext_vector_type(8)));

#define MFMA16(a, b, c) __builtin_amdgcn_mfma_f32_16x16x32_bf16(a, b, c, 0, 0, 0)
#define MFMA32(a, b, c) __builtin_amdgcn_mfma_f32_32x32x16_bf16(a, b, c, 0, 0, 0)
#define PLSWAP(x, y) asm volatile("v_permlane32_swap_b32 %0, %1" : "+v"(x), "+v"(y))
#define CFENCE() asm volatile("" ::: "memory")
#define BAR()                         \
    {                                 \
        CFENCE();                     \
        __builtin_amdgcn_s_barrier(); \
        CFENCE();                     \
    }
#define WAITV(n) asm volatile("s_waitcnt vmcnt(" #n ")" ::: "memory")

__device__ __forceinline__ u16 f2b(float f) {
    u32 u = __builtin_bit_cast(u32, f);
    u += 0x7fffu + ((u >> 16) & 1u);   // round-to-nearest-even
    return (u16)(u >> 16);
}

__device__ __forceinline__ u32 pk2(float a, float b) {
    union { u32 u; __bf16 h[2]; } r;
    r.h[0] = (__bf16)a; r.h[1] = (__bf16)b;
    return r.u;   // v_cvt_pk_bf16_f32
}

__device__ __forceinline__ void gload16(const u16* g, u16* l) {
    __builtin_amdgcn_global_load_lds((const __attribute__((address_space(1))) void*)g,
                                     (__attribute__((address_space(3))) void*)l, 16, 0, 0);
}

// ---------------- weight transpose + f32->bf16 convert (all 10 in one launch) ----------------
struct W10 { const float* p[10]; };
__global__ __launch_bounds__(256) void tcvt_k(W10 wp, u16* __restrict__ WT0) {
    const float* __restrict__ Wm = wp.p[blockIdx.z];
    u16* __restrict__ WT = WT0 + (size_t)blockIdx.z * 1048576;
    __shared__ float t[32][33];
    int bx = blockIdx.x, by = blockIdx.y;
    int tx = threadIdx.x, ty = threadIdx.y;   // (32,8)
#pragma unroll
    for (int j = 0; j < 32; j += 8)
        t[ty + j][tx] = Wm[(size_t)(by * 32 + ty + j) * 1024 + bx * 32 + tx];
    __syncthreads();
#pragma unroll
    for (int j = 0; j < 32; j += 8)
        WT[(size_t)(bx * 32 + ty + j) * 1024 + by * 32 + tx] = f2b(t[tx][ty + j]);
}

// ---------------- per-batch V transpose: V[b][key][c] -> VT[b][c][key]  (c = h*64+dh) ----------------
__global__ __launch_bounds__(256) void vtr_k(const u16* __restrict__ Vg, int ldv, u16* __restrict__ VT) {
    __shared__ u16 t[32][34];
    int bx = blockIdx.x, by = blockIdx.y, b = blockIdx.z;
    int tx = threadIdx.x, ty = threadIdx.y;   // (32,8)
#pragma unroll
    for (int j = 0; j < 32; j += 8)
        t[ty + j][tx] = Vg[(size_t)(b * 1024 + by * 32 + ty + j) * ldv + bx * 32 + tx];
    __syncthreads();
#pragma unroll
    for (int j = 0; j < 32; j += 8)
        VT[(size_t)(b * 1024 + bx * 32 + ty + j) * 1024 + by * 32 + tx] = t[tx][ty + j];
}

// ---------------- fused LayerNorm (block-per-row, proven) ----------------
// MODE bit0: x = in1 + in2 ; bit1: write f32 out (bit3: += post) ; bit2: write bf16 out
template <int MODE>
__global__ __launch_bounds__(256) void ln_k(const float* __restrict__ in1, const float* __restrict__ in2,
                                            const float* __restrict__ gg, const float* __restrict__ bb,
                                            const float* __restrict__ post,
                                            float* __restrict__ of, u16* __restrict__ ob) {
    int row = blockIdx.x, tid = threadIdx.x;
    size_t base = (size_t)row * 1024 + tid * 4;
    float4 x = *(const float4*)(in1 + base);
    if constexpr (MODE & 1) {
        float4 x2 = *(const float4*)(in2 + base);
        x.x += x2.x; x.y += x2.y; x.z += x2.z; x.w += x2.w;
    }
    float s1 = x.x + x.y + x.z + x.w;
    float s2 = x.x * x.x + x.y * x.y + x.z * x.z + x.w * x.w;
#pragma unroll
    for (int m = 32; m >= 1; m >>= 1) { s1 += __shfl_xor(s1, m); s2 += __shfl_xor(s2, m); }
    __shared__ float r1[4], r2[4];
    int lane = tid & 63, w = tid >> 6;
    if (lane == 0) { r1[w] = s1; r2[w] = s2; }
    __syncthreads();
    s1 = r1[0] + r1[1] + r1[2] + r1[3];
    s2 = r2[0] + r2[1] + r2[2] + r2[3];
    float mean = s1 * (1.0f / 1024.0f);
    float var = s2 * (1.0f / 1024.0f) - mean * mean;
    float rstd = rsqrtf(var + 1e-5f);
    float4 gv = *(const float4*)(gg + tid * 4);
    float4 bv = *(const float4*)(bb + tid * 4);
    float y0 = (x.x - mean) * rstd * gv.x + bv.x;
    float y1 = (x.y - mean) * rstd * gv.y + bv.y;
    float y2 = (x.z - mean) * rstd * gv.z + bv.z;
    float y3 = (x.w - mean) * rstd * gv.w + bv.w;
    if constexpr (MODE & 2) {
        float o0 = y0, o1 = y1, o2 = y2, o3 = y3;
        if constexpr (MODE & 8) {
            float4 p = *(const float4*)(post + base);
            o0 += p.x; o1 += p.y; o2 += p.z; o3 += p.w;
        }
        float4 o; o.x = o0; o.y = o1; o.z = o2; o.w = o3;
        *(float4*)(of + base) = o;
    }
    if constexpr (MODE & 4) {
        uint2 pk;
        pk.x = (u32)f2b(y0) | ((u32)f2b(y1) << 16);
        pk.y = (u32)f2b(y2) | ((u32)f2b(y3) << 16);
        *(uint2*)(ob + base) = pk;
    }
}

// ---------------- dual LayerNorm: two independent MODE-4 LNs in one launch ----------------
// grid 16384: blocks [0,8192) -> (inA -> obA), [8192,16384) -> (inB -> obB)
__global__ __launch_bounds__(256) void ln2x_k(const float* __restrict__ inA, const float* __restrict__ gA,
                                              const float* __restrict__ bA, u16* __restrict__ obA,
                                              const float* __restrict__ inB, const float* __restrict__ gB,
                                              const float* __restrict__ bB, u16* __restrict__ obB) {
    int sel = blockIdx.x >> 13;
    int row = blockIdx.x & 8191;
    const float* in1 = sel ? inB : inA;
    const float* gg = sel ? gB : gA;
    const float* bb = sel ? bB : bA;
    u16* ob = sel ? obB : obA;
    int tid = threadIdx.x;
    size_t base = (size_t)row * 1024 + tid * 4;
    float4 x = *(const float4*)(in1 + base);
    float s1 = x.x + x.y + x.z + x.w;
    float s2 = x.x * x.x + x.y * x.y + x.z * x.z + x.w * x.w;
#pragma unroll
    for (int m = 32; m >= 1; m >>= 1) { s1 += __shfl_xor(s1, m); s2 += __shfl_xor(s2, m); }
    __shared__ float r1[4], r2[4];
    int lane = tid & 63, w = tid >> 6;
    if (lane == 0) { r1[w] = s1; r2[w] = s2; }
    __syncthreads();
    s1 = r1[0] + r1[1] + r1[2] + r1[3];
    s2 = r2[0] + r2[1] + r2[2] + r2[3];
    float mean = s1 * (1.0f / 1024.0f);
    float var = s2 * (1.0f / 1024.0f) - mean * mean;
    float rstd = rsqrtf(var + 1e-5f);
    float4 gv = *(const float4*)(gg + tid * 4);
    float4 bv = *(const float4*)(bb + tid * 4);
    uint2 pk;
    pk.x = pk2((x.x - mean) * rstd * gv.x + bv.x, (x.y - mean) * rstd * gv.y + bv.y);
    pk.y = pk2((x.z - mean) * rstd * gv.z + bv.z, (x.w - mean) * rstd * gv.w + bv.w);
    *(uint2*)(ob + base) = pk;
}

// ---------------- bf16 GEMM v512 (phase-split — measured best for 8-wave): BM=256/BN=128 ----------------
template <int EPI, int NBN>
__global__ __launch_bounds__(512) void gemm512_k(const u16* __restrict__ A, int lda,
                                                 const u16* __restrict__ WT,
                                                 const float* __restrict__ b0, const float* __restrict__ b1,
                                                 const float* __restrict__ b2,
                                                 float sc0, float sc1, float sc2,
                                                 const float* __restrict__ res,
                                                 void* __restrict__ outp, int ldc) {
    constexpr int ASZ = 8192;
    constexpr int SLOT = ASZ + 4096;
    __shared__ u16 lds[3 * SLOT];
    u16* ldsb = &lds[0];

    int id = blockIdx.x;
    constexpr int NWG = 32 * NBN;
    constexpr int CPX = NWG / 8;
    int swz = (id & 7) * CPX + (id >> 3);   // XCD-contiguous bijective remap
    int bm = swz / NBN, bn = swz % NBN;
    const int m0 = bm * 256, n0 = bn * 128;
    int tid = threadIdx.x, lane = tid & 63, w = tid >> 6;
    int col = lane & 15, fg = lane >> 4;
    int wr = w >> 1, wc = w & 1;

    int swzL = ((col * 32) + fg * 8) ^ ((col >> 1) << 3);
    int aoff0 = wr * 64 * 32 + swzL;
    int boff0 = ASZ + wc * 64 * 32 + swzL;

    int r = tid >> 2, g = tid & 3;
    int gr = r ^ ((r >> 3) & 1);
    int gc = g ^ ((r >> 1) & 3);
    const u16* pA = A + (size_t)(m0 + gr) * lda + gc * 8;
    const u16* pB = WT + (size_t)(n0 + gr) * 1024 + gc * 8;

#define STGA(t2, snO)                                                                       \
    {                                                                                       \
        gload16(pA + (size_t)(t2) * 32, ldsb + (snO) + w * 512);                            \
        gload16(pA + (size_t)(t2) * 32 + (size_t)128 * lda, ldsb + (snO) + 4096 + w * 512); \
    }
#define STGB(t2, snO)                                                   \
    {                                                                   \
        gload16(pB + (size_t)(t2) * 32, ldsb + (snO) + ASZ + w * 512);  \
    }

    f32x4 acc[4][4];
#pragma unroll
    for (int m = 0; m < 4; m++)
#pragma unroll
        for (int n = 0; n < 4; n++) acc[m][n] = (f32x4){0.f, 0.f, 0.f, 0.f};

    STGA(0, 0); STGB(0, 0);
    STGA(1, SLOT); STGB(1, SLOT);
    WAITV(3);
    BAR();

    int sc = 0, sn = 2;
    for (int t = 0; t < 32; ++t) {
        int sCur = sc * SLOT, sNxt = sn * SLOT;
        // ---- phase 0: A-frags + first 2 B-frags, stage A of t+2, 8 MFMA ----
        bf16x8 a0[4], bfv[2];
#pragma unroll
        for (int m = 0; m < 4; m++) a0[m] = *(const bf16x8*)&ldsb[sCur + aoff0 + m * 512];
#pragma unroll
        for (int n = 0; n < 2; n++) bfv[n] = *(const bf16x8*)&ldsb[sCur + boff0 + n * 512];
        if (t < 30) STGA(t + 2, sNxt);
        BAR();
        __builtin_amdgcn_s_setprio(1);
#pragma unroll
        for (int m = 0; m < 4; m++)
#pragma unroll
            for (int n = 0; n < 2; n++) acc[m][n] = MFMA16(a0[m], bfv[n], acc[m][n]);
        __builtin_amdgcn_s_setprio(0);
        BAR();
        // ---- phase 1: last 2 B-frags, stage B of t+2, 8 MFMA, counted wait ----
        bf16x8 b2[2];
#pragma unroll
        for (int n = 0; n < 2; n++) b2[n] = *(const bf16x8*)&ldsb[sCur + boff0 + (n + 2) * 512];
        if (t < 30) STGB(t + 2, sNxt);
        BAR();
        __builtin_amdgcn_s_setprio(1);
#pragma unroll
        for (int m = 0; m < 4; m++)
#pragma unroll
            for (int n = 0; n < 2; n++) acc[m][n + 2] = MFMA16(a0[m], b2[n], acc[m][n + 2]);
        __builtin_amdgcn_s_setprio(0);
        if (t < 30) { WAITV(3); } else if (t == 30) { WAITV(0); }
        BAR();
        sc = (sc == 2) ? 0 : sc + 1;
        sn = (sn == 2) ? 0 : sn + 1;
    }
#undef STGA
#undef STGB

    int seg = n0 >> 10;
    const float* bp = (seg == 0) ? b0 : (seg == 1 ? b1 : b2);
    float sg = (seg == 0) ? sc0 : (seg == 1 ? sc1 : sc2);
    int nseg = n0 & 1023;
    float bv[4];
#pragma unroll
    for (int n = 0; n < 4; n++) bv[n] = bp[nseg + wc * 64 + n * 16 + col];
#pragma unroll
    for (int m = 0; m < 4; m++) {
#pragma unroll
        for (int rr = 0; rr < 4; rr++) {
            int row = m0 + wr * 64 + m * 16 + fg * 4 + rr;
#pragma unroll
            for (int n = 0; n < 4; n++) {
                int c = n0 + wc * 64 + n * 16 + col;
                size_t idx = (size_t)row * ldc + c;
                float v = (acc[m][n][rr] + bv[n]) * sg;
                if constexpr (EPI == 0) ((u16*)outp)[idx] = f2b(v);
                else if constexpr (EPI == 1) ((u16*)outp)[idx] = f2b(fmaxf(v, 0.f));
                else if constexpr (EPI == 2) ((float*)outp)[idx] = v + res[idx];
            }
        }
    }
}

// ---------------- bf16 GEMM v256b (merged — measured best for 4-wave): BM=128/BN=128 ----------------
template <int EPI, int NBN>
__global__ __launch_bounds__(256) void gemm256_k(const u16* __restrict__ A, int lda,
                                                 const u16* __restrict__ WT,
                                                 const float* __restrict__ b0,
                                                 float sc0,
                                                 const float* __restrict__ res,
                                                 void* __restrict__ outp, int ldc) {
    constexpr int SLOT = 8192;
    __shared__ u16 lds[3 * SLOT];
    int id = blockIdx.x;
    constexpr int NWG = 64 * NBN;
    constexpr int CPX = NWG / 8;
    int swz = (id & 7) * CPX + (id >> 3);
    int bm = swz / NBN, bn = swz % NBN;
    const int m0 = bm * 128, n0 = bn * 128;
    int tid = threadIdx.x, lane = tid & 63, w = tid >> 6;
    int col = lane & 15, fg = lane >> 4;
    int wr = w >> 1, wc = w & 1;

    int swzL = ((col * 32) + fg * 8) ^ ((col >> 1) << 3);
    int aoff0 = wr * 64 * 32 + swzL;
    int boff0 = 4096 + wc * 64 * 32 + swzL;

    int r = tid >> 2, g = tid & 3;
    int gr = r ^ ((r >> 3) & 1);
    int gc = g ^ ((r >> 1) & 3);
    const u16* pA = A + (size_t)(m0 + gr) * lda + gc * 8;
    const u16* pB = WT + (size_t)(n0 + gr) * 1024 + gc * 8;

#define STG(t2, snO)                                                                              \
    {                                                                                             \
        gload16(pA + (size_t)(t2) * 32, lds + (snO) + w * 512);                                   \
        gload16(pA + (size_t)(t2) * 32 + (size_t)64 * lda, lds + (snO) + 2048 + w * 512);         \
        gload16(pB + (size_t)(t2) * 32, lds + (snO) + 4096 + w * 512);                            \
        gload16(pB + (size_t)(t2) * 32 + (size_t)64 * 1024, lds + (snO) + 4096 + 2048 + w * 512); \
    }

    f32x4 acc[4][4];
#pragma unroll
    for (int m = 0; m < 4; m++)
#pragma unroll
        for (int n = 0; n < 4; n++) acc[m][n] = (f32x4){0.f, 0.f, 0.f, 0.f};

    STG(0, 0);
    STG(1, SLOT);
    WAITV(4);
    BAR();

    int sc = 0, sn = 2;
    for (int t = 0; t < 32; ++t) {
        int sCur = sc * SLOT, sNxt = sn * SLOT;
        bf16x8 a0[4], bfv[4];
#pragma unroll
        for (int m = 0; m < 4; m++) a0[m] = *(const bf16x8*)&lds[sCur + aoff0 + m * 512];
#pragma unroll
        for (int n = 0; n < 4; n++) bfv[n] = *(const bf16x8*)&lds[sCur + boff0 + n * 512];
        if (t < 30) STG(t + 2, sNxt);
        BAR();
        __builtin_amdgcn_s_setprio(1);
#pragma unroll
        for (int m = 0; m < 4; m++)
#pragma unroll
            for (int n = 0; n < 4; n++) acc[m][n] = MFMA16(a0[m], bfv[n], acc[m][n]);
        __builtin_amdgcn_s_setprio(0);
        if (t < 30) { WAITV(4); } else if (t == 30) { WAITV(0); }
        BAR();
        sc = (sc == 2) ? 0 : sc + 1;
        sn = (sn == 2) ? 0 : sn + 1;
    }
#undef STG

    float bv[4];
#pragma unroll
    for (int n = 0; n < 4; n++) bv[n] = b0[(n0 & 1023) + wc * 64 + n * 16 + col];
#pragma unroll
    for (int m = 0; m < 4; m++) {
#pragma unroll
        for (int rr = 0; rr < 4; rr++) {
            int row = m0 + wr * 64 + m * 16 + fg * 4 + rr;
#pragma unroll
            for (int n = 0; n < 4; n++) {
                int c = n0 + wc * 64 + n * 16 + col;
                size_t idx = (size_t)row * ldc + c;
                float v = (acc[m][n][rr] + bv[n]) * sc0;
                if constexpr (EPI == 0) ((u16*)outp)[idx] = f2b(v);
                else if constexpr (EPI == 1) ((u16*)outp)[idx] = f2b(fmaxf(v, 0.f));
                else if constexpr (EPI == 2) ((float*)outp)[idx] = v + res[idx];
            }
        }
    }
}

// ---------------- flash attention v5 (r9-best, exact): 8 waves share KVBLK=64 staging; no-max softmax ----------------
__global__ __launch_bounds__(512) void attn_k(const u16* __restrict__ Q, int ldq,
                                              const u16* __restrict__ Kc, int ldk,
                                              const u16* __restrict__ VT,   // [(b*16+h)*64+dh][1024]
                                              const int* __restrict__ mask,
                                              u16* __restrict__ O, int ldo) {
    const int S = 1024;
    int gid = blockIdx.x;
    int bq = gid >> 7, hh = (gid >> 3) & 15, bb = gid & 7;
    int tid = threadIdx.x, lane = tid & 63, w = tid >> 6;   // w 0..7
    int q = lane & 31, hl = lane >> 5;
    int q0w = bq * 256 + w * 32;

    __shared__ u16 sm[18432];   // 36864 B: [buf][ K 64x72 | V^T 64x72 ]
#define KT(b, r, c) sm[(b) * 9216 + (r) * 72 + (c)]
#define VTL(b, r, c) sm[(b) * 9216 + 4608 + (r) * 72 + (c)]

    const u16* Qrow = Q + ((size_t)bb * S + q0w + q) * ldq + hh * 64;
    bool mneg = (mask[bb * S + q0w + q] == 0);
    bf16x8 qf[4];
#pragma unroll
    for (int c = 0; c < 4; c++) {
        qf[c] = *(const bf16x8*)(Qrow + c * 16 + hl * 8);
        if (mneg) qf[c] = (bf16x8)(__bf16)0.f;   // -> sc==0 -> p==1 (uniform)
    }

    float l = 0.f;
    f32x16 oa[2];
#pragma unroll
    for (int i = 0; i < 16; i++) { oa[0][i] = 0.f; oa[1][i] = 0.f; }

    int kk = tid >> 3, ks = tid & 7;
    const u16* gK = Kc + ((size_t)bb * S + kk) * ldk + hh * 64 + ks * 8;
    const u16* gVT = VT + ((size_t)(bb * 16 + hh) * 64 + kk) * 1024 + ks * 8;
    uint4 kr0, vr0;

#define LOADT(t)                                              \
    {                                                         \
        kr0 = *(const uint4*)(gK + (size_t)(t) * 64 * ldk);   \
        vr0 = *(const uint4*)(gVT + (size_t)(t) * 64);        \
    }
#define STORET(bf)                            \
    {                                         \
        *(uint4*)&KT(bf, kk, ks * 8) = kr0;   \
        *(uint4*)&VTL(bf, kk, ks * 8) = vr0;  \
    }

    LOADT(0);
    STORET(0);

    for (int t = 0; t < 16; ++t) {
        int cur = t & 1;
        if (t < 15) LOADT(t + 1);
        __syncthreads();

        f32x16 sc[2];
#pragma unroll
        for (int i = 0; i < 16; i++) { sc[0][i] = 0.f; sc[1][i] = 0.f; }
        __builtin_amdgcn_s_setprio(1);
#pragma unroll
        for (int st = 0; st < 2; st++)
#pragma unroll
            for (int c = 0; c < 4; c++) {
                bf16x8 kf = *(const bf16x8*)&KT(cur, st * 32 + q, c * 16 + hl * 8);
                sc[st] = MFMA32(kf, qf[c], sc[st]);
            }
        __builtin_amdgcn_s_setprio(0);

#pragma unroll
        for (int st = 0; st < 2; st++)
#pragma unroll
            for (int rr = 0; rr < 16; rr++) sc[st][rr] = exp2f(sc[st][rr]);
        float ts[8];
#pragma unroll
        for (int i = 0; i < 8; i++)
            ts[i] = (sc[0][i] + sc[0][i + 8]) + (sc[1][i] + sc[1][i + 8]);
#pragma unroll
        for (int i = 0; i < 4; i++) ts[i] += ts[i + 4];
        l += (ts[0] + ts[2]) + (ts[1] + ts[3]);

        __builtin_amdgcn_s_setprio(1);
#pragma unroll
        for (int st = 0; st < 2; st++) {
            u32 wv[8];
#pragma unroll
            for (int j = 0; j < 8; j++) wv[j] = pk2(sc[st][2 * j], sc[st][2 * j + 1]);
            PLSWAP(wv[0], wv[2]); PLSWAP(wv[1], wv[3]);
            PLSWAP(wv[4], wv[6]); PLSWAP(wv[5], wv[7]);
#pragma unroll
            for (int c = 0; c < 2; c++) {
                union { u32 u[4]; bf16x8 v; } pb;
                pb.u[0] = wv[c * 4 + 0]; pb.u[1] = wv[c * 4 + 1];
                pb.u[2] = wv[c * 4 + 2]; pb.u[3] = wv[c * 4 + 3];
#pragma unroll
                for (int dd = 0; dd < 2; dd++) {
                    bf16x8 vf = *(const bf16x8*)&VTL(cur, dd * 32 + q, st * 32 + c * 16 + hl * 8);
                    oa[dd] = MFMA32(vf, pb.v, oa[dd]);
                }
            }
        }
        __builtin_amdgcn_s_setprio(0);

        if (t < 15) STORET(cur ^ 1);
    }

    l += __shfl_xor(l, 32);
    __syncthreads();
    float inv = 1.0f / l;
    u16* otw = sm + w * 2304;
#pragma unroll
    for (int dd = 0; dd < 2; dd++)
#pragma unroll
        for (int rr = 0; rr < 16; rr++) {
            int d = (rr & 3) + 8 * (rr >> 2) + 4 * hl + 32 * dd;
            otw[q * 72 + d] = f2b(oa[dd][rr] * inv);
        }
    __syncthreads();
    size_t obase = ((size_t)bb * S + q0w) * ldo + hh * 64;
#pragma unroll
    for (int i = 0; i < 4; i++) {
        int row = i * 8 + (lane >> 3);
        uint4 vdat = *(const uint4*)&otw[row * 72 + (lane & 7) * 8];
        *(uint4*)(O + obase + (size_t)row * ldo + (lane & 7) * 8) = vdat;
    }
#undef KT
#undef VTL
#undef LOADT
#undef STORET
}

extern "C" void kernel_launch(void* const* d_in, const int* in_sizes, int n_in,
                              void* d_out, int out_size, void* d_ws, size_t ws_size,
                              hipStream_t stream) {
    (void)in_sizes; (void)n_in; (void)out_size; (void)ws_size;
    const float* x = (const float*)d_in[0];
    const float* h = (const float*)d_in[1];
    const int* mask = (const int*)d_in[2];
    const float* W[10];
    const float* Bv[10];
    for (int i = 0; i < 10; i++) { W[i] = (const float*)d_in[3 + i]; Bv[i] = (const float*)d_in[13 + i]; }
    const float *ln1g = (const float*)d_in[23], *ln1b = (const float*)d_in[24];
    const float *ln2g = (const float*)d_in[25], *ln2b = (const float*)d_in[26];
    const float *ln3g = (const float*)d_in[27], *ln3b = (const float*)d_in[28];
    const float *lnhg = (const float*)d_in[29], *lnhb = (const float*)d_in[30];
    const float *flng = (const float*)d_in[31], *flnb = (const float*)d_in[32];

    const float SCLE = 0.18033688011112042f;   // log2(e)/sqrt(64)

    char* ws = (char*)d_ws;
    size_t off = 0;
    auto alloc = [&](size_t bytes) -> char* {
        char* p = ws + off;
        off += (bytes + 255) & ~(size_t)255;
        return p;
    };
    const size_t MT = (size_t)8192 * 1024;
    u16* wtb = (u16*)alloc((size_t)10 * 1048576 * 2);
    u16* wt[10];
    for (int i = 0; i < 10; i++) wt[i] = wtb + (size_t)i * 1048576;
    u16* qkv = (u16*)alloc((size_t)8192 * 3072 * 2);   // sa QKV; later ca kv + ff1
    u16* kv = qkv;
    u16* kb = qkv + (size_t)8192 * 2048;
    u16* bufA = (u16*)alloc(MT * 2);
    u16* qb   = (u16*)alloc(MT * 2);          // ca Q, then ca attention out
    float* hid_in  = (float*)alloc(MT * 4);
    float* hid_mid = (float*)alloc(MT * 4);
    float* yf      = (float*)alloc(MT * 4);
    u16* hn = (u16*)yf;                        // hn lifetime disjoint from yf (FFN)
    u16* vt_sa = bufA;                         // V^T alias: free between QKV-gemm and ln2
    u16* vt_ca = (u16*)hid_mid;                // V^T alias: free between kv-gemm and ca-wo gemm
    float* outF = (float*)d_out;

    W10 wp;
    for (int i = 0; i < 10; i++) wp.p[i] = W[i];
    tcvt_k<<<dim3(32, 32, 10), dim3(32, 8), 0, stream>>>(wp, wtb);

    // ---- self-attention block ----
    ln_k<4><<<8192, 256, 0, stream>>>(x, nullptr, ln1g, ln1b, nullptr, nullptr, bufA);
    gemm512_k<0, 24><<<768, 512, 0, stream>>>(bufA, 1024, wt[0], Bv[0], Bv[1], Bv[2], SCLE, 1.f, 1.f, nullptr, qkv, 3072);
    vtr_k<<<dim3(32, 32, 8), dim3(32, 8), 0, stream>>>(qkv + 2048, 3072, vt_sa);
    attn_k<<<512, 512, 0, stream>>>(qkv, 3072, qkv + 1024, 3072, vt_sa, mask, qkv, 3072);
    gemm256_k<2, 8><<<512, 256, 0, stream>>>(qkv, 3072, wt[3], Bv[3], 1.f, x, hid_in, 1024);

    // ---- cross-attention block ----
    ln2x_k<<<16384, 256, 0, stream>>>(hid_in, ln2g, ln2b, bufA, h, lnhg, lnhb, hn);
    gemm256_k<0, 8><<<512, 256, 0, stream>>>(bufA, 1024, wt[4], Bv[4], SCLE, nullptr, qb, 1024);
    gemm512_k<0, 16><<<512, 512, 0, stream>>>(hn, 1024, wt[5], Bv[5], Bv[6], Bv[6], 1.f, 1.f, 1.f, nullptr, kv, 2048);
    vtr_k<<<dim3(32, 32, 8), dim3(32, 8), 0, stream>>>(kv + 1024, 2048, vt_ca);
    attn_k<<<512, 512, 0, stream>>>(qb, 1024, kv, 2048, vt_ca, mask, qb, 1024);
    gemm256_k<2, 8><<<512, 256, 0, stream>>>(qb, 1024, wt[7], Bv[7], 1.f, hid_in, hid_mid, 1024);

    // ---- FFN block ----
    ln_k<6><<<8192, 256, 0, stream>>>(hid_mid, nullptr, ln3g, ln3b, nullptr, yf, bufA);
    gemm256_k<1, 8><<<512, 256, 0, stream>>>(bufA, 1024, wt[8], Bv[8], 1.f, nullptr, kb, 1024);
    gemm256_k<2, 8><<<512, 256, 0, stream>>>(kb, 1024, wt[9], Bv[9], 1.f, yf, hid_in, 1024);
    ln_k<10><<<8192, 256, 0, stream>>>(hid_in, nullptr, flng, flnb, hid_mid, outF, nullptr);
}

// Round 17
// 429.345 us; speedup vs baseline: 1.0805x; 1.0331x over previous
//
#include <hip/hip_runtime.h>

typedef unsigned short u16;
typedef unsigned int u32;
typedef float f32x4 __attribute__((ext_vector_type(4)));
typedef float f32x16 __attribute__((ext_vector_type(16)));
typedef __bf16 bf16x8 __attribute__((ext_vector_type(8)));

#define MFMA16(a, b, c) __builtin_amdgcn_mfma_f32_16x16x32_bf16(a, b, c, 0, 0, 0)
#define MFMA32(a, b, c) __builtin_amdgcn_mfma_f32_32x32x16_bf16(a, b, c, 0, 0, 0)
#define PLSWAP(x, y) asm volatile("v_permlane32_swap_b32 %0, %1" : "+v"(x), "+v"(y))
#define CFENCE() asm volatile("" ::: "memory")
#define BAR()                         \
    {                                 \
        CFENCE();                     \
        __builtin_amdgcn_s_barrier(); \
        CFENCE();                     \
    }
#define WAITV(n) asm volatile("s_waitcnt vmcnt(" #n ")" ::: "memory")

__device__ __forceinline__ u16 f2b(float f) {
    u32 u = __builtin_bit_cast(u32, f);
    u += 0x7fffu + ((u >> 16) & 1u);   // round-to-nearest-even
    return (u16)(u >> 16);
}

__device__ __forceinline__ u32 pk2(float a, float b) {
    union { u32 u; __bf16 h[2]; } r;
    r.h[0] = (__bf16)a; r.h[1] = (__bf16)b;
    return r.u;   // v_cvt_pk_bf16_f32
}

__device__ __forceinline__ void gload16(const u16* g, u16* l) {
    __builtin_amdgcn_global_load_lds((const __attribute__((address_space(1))) void*)g,
                                     (__attribute__((address_space(3))) void*)l, 16, 0, 0);
}

// ---------------- weight transpose + f32->bf16 convert (all 10 in one launch) ----------------
struct W10 { const float* p[10]; };
__global__ __launch_bounds__(256) void tcvt_k(W10 wp, u16* __restrict__ WT0) {
    const float* __restrict__ Wm = wp.p[blockIdx.z];
    u16* __restrict__ WT = WT0 + (size_t)blockIdx.z * 1048576;
    __shared__ float t[32][33];
    int bx = blockIdx.x, by = blockIdx.y;
    int tx = threadIdx.x, ty = threadIdx.y;   // (32,8)
#pragma unroll
    for (int j = 0; j < 32; j += 8)
        t[ty + j][tx] = Wm[(size_t)(by * 32 + ty + j) * 1024 + bx * 32 + tx];
    __syncthreads();
#pragma unroll
    for (int j = 0; j < 32; j += 8)
        WT[(size_t)(bx * 32 + ty + j) * 1024 + by * 32 + tx] = f2b(t[tx][ty + j]);
}

// ---------------- fused LayerNorm (block-per-row, proven) ----------------
// MODE bit0: x = in1 + in2 ; bit1: write f32 out (bit3: += post) ; bit2: write bf16 out
template <int MODE>
__global__ __launch_bounds__(256) void ln_k(const float* __restrict__ in1, const float* __restrict__ in2,
                                            const float* __restrict__ gg, const float* __restrict__ bb,
                                            const float* __restrict__ post,
                                            float* __restrict__ of, u16* __restrict__ ob) {
    int row = blockIdx.x, tid = threadIdx.x;
    size_t base = (size_t)row * 1024 + tid * 4;
    float4 x = *(const float4*)(in1 + base);
    if constexpr (MODE & 1) {
        float4 x2 = *(const float4*)(in2 + base);
        x.x += x2.x; x.y += x2.y; x.z += x2.z; x.w += x2.w;
    }
    float s1 = x.x + x.y + x.z + x.w;
    float s2 = x.x * x.x + x.y * x.y + x.z * x.z + x.w * x.w;
#pragma unroll
    for (int m = 32; m >= 1; m >>= 1) { s1 += __shfl_xor(s1, m); s2 += __shfl_xor(s2, m); }
    __shared__ float r1[4], r2[4];
    int lane = tid & 63, w = tid >> 6;
    if (lane == 0) { r1[w] = s1; r2[w] = s2; }
    __syncthreads();
    s1 = r1[0] + r1[1] + r1[2] + r1[3];
    s2 = r2[0] + r2[1] + r2[2] + r2[3];
    float mean = s1 * (1.0f / 1024.0f);
    float var = s2 * (1.0f / 1024.0f) - mean * mean;
    float rstd = rsqrtf(var + 1e-5f);
    float4 gv = *(const float4*)(gg + tid * 4);
    float4 bv = *(const float4*)(bb + tid * 4);
    float y0 = (x.x - mean) * rstd * gv.x + bv.x;
    float y1 = (x.y - mean) * rstd * gv.y + bv.y;
    float y2 = (x.z - mean) * rstd * gv.z + bv.z;
    float y3 = (x.w - mean) * rstd * gv.w + bv.w;
    if constexpr (MODE & 2) {
        float o0 = y0, o1 = y1, o2 = y2, o3 = y3;
        if constexpr (MODE & 8) {
            float4 p = *(const float4*)(post + base);
            o0 += p.x; o1 += p.y; o2 += p.z; o3 += p.w;
        }
        float4 o; o.x = o0; o.y = o1; o.z = o2; o.w = o3;
        *(float4*)(of + base) = o;
    }
    if constexpr (MODE & 4) {
        uint2 pk;
        pk.x = (u32)f2b(y0) | ((u32)f2b(y1) << 16);
        pk.y = (u32)f2b(y2) | ((u32)f2b(y3) << 16);
        *(uint2*)(ob + base) = pk;
    }
}

// ---------------- dual LayerNorm: two independent MODE-4 LNs in one launch ----------------
__global__ __launch_bounds__(256) void ln2x_k(const float* __restrict__ inA, const float* __restrict__ gA,
                                              const float* __restrict__ bA, u16* __restrict__ obA,
                                              const float* __restrict__ inB, const float* __restrict__ gB,
                                              const float* __restrict__ bB, u16* __restrict__ obB) {
    int sel = blockIdx.x >> 13;
    int row = blockIdx.x & 8191;
    const float* in1 = sel ? inB : inA;
    const float* gg = sel ? gB : gA;
    const float* bb = sel ? bB : bA;
    u16* ob = sel ? obB : obA;
    int tid = threadIdx.x;
    size_t base = (size_t)row * 1024 + tid * 4;
    float4 x = *(const float4*)(in1 + base);
    float s1 = x.x + x.y + x.z + x.w;
    float s2 = x.x * x.x + x.y * x.y + x.z * x.z + x.w * x.w;
#pragma unroll
    for (int m = 32; m >= 1; m >>= 1) { s1 += __shfl_xor(s1, m); s2 += __shfl_xor(s2, m); }
    __shared__ float r1[4], r2[4];
    int lane = tid & 63, w = tid >> 6;
    if (lane == 0) { r1[w] = s1; r2[w] = s2; }
    __syncthreads();
    s1 = r1[0] + r1[1] + r1[2] + r1[3];
    s2 = r2[0] + r2[1] + r2[2] + r2[3];
    float mean = s1 * (1.0f / 1024.0f);
    float var = s2 * (1.0f / 1024.0f) - mean * mean;
    float rstd = rsqrtf(var + 1e-5f);
    float4 gv = *(const float4*)(gg + tid * 4);
    float4 bv = *(const float4*)(bb + tid * 4);
    uint2 pk;
    pk.x = pk2((x.x - mean) * rstd * gv.x + bv.x, (x.y - mean) * rstd * gv.y + bv.y);
    pk.y = pk2((x.z - mean) * rstd * gv.z + bv.z, (x.w - mean) * rstd * gv.w + bv.w);
    *(uint2*)(ob + base) = pk;
}

// ---------------- bf16 GEMM v512 (phase-split) + fused V-transpose epilogue ----------------
// BM=256/BN=128, 8 waves. VSEG >= 0: blocks with seg==VSEG write C transposed to
// vt[(b*1024 + ch)][key] (b = row>>10, ch = col-within-V, key = row&1023) as packed 8B stores.
template <int EPI, int NBN, int VSEG>
__global__ __launch_bounds__(512) void gemm512_k(const u16* __restrict__ A, int lda,
                                                 const u16* __restrict__ WT,
                                                 const float* __restrict__ b0, const float* __restrict__ b1,
                                                 const float* __restrict__ b2,
                                                 float sc0, float sc1, float sc2,
                                                 const float* __restrict__ res,
                                                 void* __restrict__ outp, int ldc,
                                                 u16* __restrict__ vt) {
    constexpr int ASZ = 8192;
    constexpr int SLOT = ASZ + 4096;
    __shared__ u16 lds[3 * SLOT];
    u16* ldsb = &lds[0];

    int id = blockIdx.x;
    constexpr int NWG = 32 * NBN;
    constexpr int CPX = NWG / 8;
    int swz = (id & 7) * CPX + (id >> 3);   // XCD-contiguous bijective remap
    int bm = swz / NBN, bn = swz % NBN;
    const int m0 = bm * 256, n0 = bn * 128;
    int tid = threadIdx.x, lane = tid & 63, w = tid >> 6;
    int col = lane & 15, fg = lane >> 4;
    int wr = w >> 1, wc = w & 1;

    int swzL = ((col * 32) + fg * 8) ^ ((col >> 1) << 3);
    int aoff0 = wr * 64 * 32 + swzL;
    int boff0 = ASZ + wc * 64 * 32 + swzL;

    int r = tid >> 2, g = tid & 3;
    int gr = r ^ ((r >> 3) & 1);
    int gc = g ^ ((r >> 1) & 3);
    const u16* pA = A + (size_t)(m0 + gr) * lda + gc * 8;
    const u16* pB = WT + (size_t)(n0 + gr) * 1024 + gc * 8;

#define STGA(t2, snO)                                                                       \
    {                                                                                       \
        gload16(pA + (size_t)(t2) * 32, ldsb + (snO) + w * 512);                            \
        gload16(pA + (size_t)(t2) * 32 + (size_t)128 * lda, ldsb + (snO) + 4096 + w * 512); \
    }
#define STGB(t2, snO)                                                   \
    {                                                                   \
        gload16(pB + (size_t)(t2) * 32, ldsb + (snO) + ASZ + w * 512);  \
    }

    f32x4 acc[4][4];
#pragma unroll
    for (int m = 0; m < 4; m++)
#pragma unroll
        for (int n = 0; n < 4; n++) acc[m][n] = (f32x4){0.f, 0.f, 0.f, 0.f};

    STGA(0, 0); STGB(0, 0);
    STGA(1, SLOT); STGB(1, SLOT);
    WAITV(3);
    BAR();

    int sc = 0, sn = 2;
    for (int t = 0; t < 32; ++t) {
        int sCur = sc * SLOT, sNxt = sn * SLOT;
        // ---- phase 0: A-frags + first 2 B-frags, stage A of t+2, 8 MFMA ----
        bf16x8 a0[4], bfv[2];
#pragma unroll
        for (int m = 0; m < 4; m++) a0[m] = *(const bf16x8*)&ldsb[sCur + aoff0 + m * 512];
#pragma unroll
        for (int n = 0; n < 2; n++) bfv[n] = *(const bf16x8*)&ldsb[sCur + boff0 + n * 512];
        if (t < 30) STGA(t + 2, sNxt);
        BAR();
        __builtin_amdgcn_s_setprio(1);
#pragma unroll
        for (int m = 0; m < 4; m++)
#pragma unroll
            for (int n = 0; n < 2; n++) acc[m][n] = MFMA16(a0[m], bfv[n], acc[m][n]);
        __builtin_amdgcn_s_setprio(0);
        BAR();
        // ---- phase 1: last 2 B-frags, stage B of t+2, 8 MFMA, counted wait ----
        bf16x8 b2[2];
#pragma unroll
        for (int n = 0; n < 2; n++) b2[n] = *(const bf16x8*)&ldsb[sCur + boff0 + (n + 2) * 512];
        if (t < 30) STGB(t + 2, sNxt);
        BAR();
        __builtin_amdgcn_s_setprio(1);
#pragma unroll
        for (int m = 0; m < 4; m++)
#pragma unroll
            for (int n = 0; n < 2; n++) acc[m][n + 2] = MFMA16(a0[m], b2[n], acc[m][n + 2]);
        __builtin_amdgcn_s_setprio(0);
        if (t < 30) { WAITV(3); } else if (t == 30) { WAITV(0); }
        BAR();
        sc = (sc == 2) ? 0 : sc + 1;
        sn = (sn == 2) ? 0 : sn + 1;
    }
#undef STGA
#undef STGB

    int seg = n0 >> 10;
    const float* bp = (seg == 0) ? b0 : (seg == 1 ? b1 : b2);
    float sg = (seg == 0) ? sc0 : (seg == 1 ? sc1 : sc2);
    int nseg = n0 & 1023;
    float bv[4];
#pragma unroll
    for (int n = 0; n < 4; n++) bv[n] = bp[nseg + wc * 64 + n * 16 + col];

    if constexpr (VSEG >= 0) {
        if (seg == VSEG) {
            // transposed V write: vt[(b*1024 + ch)][key], 4 consecutive keys per (m,n) -> 8B store
            int bidx = m0 >> 10;
            int key0 = (m0 & 1023) + wr * 64 + fg * 4;
#pragma unroll
            for (int m = 0; m < 4; m++) {
#pragma unroll
                for (int n = 0; n < 4; n++) {
                    int ch = nseg + wc * 64 + n * 16 + col;
                    uint2 pk;
                    pk.x = pk2(acc[m][n][0] + bv[n], acc[m][n][1] + bv[n]);
                    pk.y = pk2(acc[m][n][2] + bv[n], acc[m][n][3] + bv[n]);
                    *(uint2*)(vt + ((size_t)(bidx * 1024 + ch) << 10) + key0 + m * 16) = pk;
                }
            }
            return;
        }
    }
#pragma unroll
    for (int m = 0; m < 4; m++) {
#pragma unroll
        for (int rr = 0; rr < 4; rr++) {
            int row = m0 + wr * 64 + m * 16 + fg * 4 + rr;
#pragma unroll
            for (int n = 0; n < 4; n++) {
                int c = n0 + wc * 64 + n * 16 + col;
                size_t idx = (size_t)row * ldc + c;
                float v = (acc[m][n][rr] + bv[n]) * sg;
                if constexpr (EPI == 0) ((u16*)outp)[idx] = f2b(v);
                else if constexpr (EPI == 1) ((u16*)outp)[idx] = f2b(fmaxf(v, 0.f));
                else if constexpr (EPI == 2) ((float*)outp)[idx] = v + res[idx];
            }
        }
    }
}

// ---------------- bf16 GEMM v256b (merged — measured best for 4-wave): BM=128/BN=128 ----------------
template <int EPI, int NBN>
__global__ __launch_bounds__(256) void gemm256_k(const u16* __restrict__ A, int lda,
                                                 const u16* __restrict__ WT,
                                                 const float* __restrict__ b0,
                                                 float sc0,
                                                 const float* __restrict__ res,
                                                 void* __restrict__ outp, int ldc) {
    constexpr int SLOT = 8192;
    __shared__ u16 lds[3 * SLOT];
    int id = blockIdx.x;
    constexpr int NWG = 64 * NBN;
    constexpr int CPX = NWG / 8;
    int swz = (id & 7) * CPX + (id >> 3);
    int bm = swz / NBN, bn = swz % NBN;
    const int m0 = bm * 128, n0 = bn * 128;
    int tid = threadIdx.x, lane = tid & 63, w = tid >> 6;
    int col = lane & 15, fg = lane >> 4;
    int wr = w >> 1, wc = w & 1;

    int swzL = ((col * 32) + fg * 8) ^ ((col >> 1) << 3);
    int aoff0 = wr * 64 * 32 + swzL;
    int boff0 = 4096 + wc * 64 * 32 + swzL;

    int r = tid >> 2, g = tid & 3;
    int gr = r ^ ((r >> 3) & 1);
    int gc = g ^ ((r >> 1) & 3);
    const u16* pA = A + (size_t)(m0 + gr) * lda + gc * 8;
    const u16* pB = WT + (size_t)(n0 + gr) * 1024 + gc * 8;

#define STG(t2, snO)                                                                              \
    {                                                                                             \
        gload16(pA + (size_t)(t2) * 32, lds + (snO) + w * 512);                                   \
        gload16(pA + (size_t)(t2) * 32 + (size_t)64 * lda, lds + (snO) + 2048 + w * 512);         \
        gload16(pB + (size_t)(t2) * 32, lds + (snO) + 4096 + w * 512);                            \
        gload16(pB + (size_t)(t2) * 32 + (size_t)64 * 1024, lds + (snO) + 4096 + 2048 + w * 512); \
    }

    f32x4 acc[4][4];
#pragma unroll
    for (int m = 0; m < 4; m++)
#pragma unroll
        for (int n = 0; n < 4; n++) acc[m][n] = (f32x4){0.f, 0.f, 0.f, 0.f};

    STG(0, 0);
    STG(1, SLOT);
    WAITV(4);
    BAR();

    int sc = 0, sn = 2;
    for (int t = 0; t < 32; ++t) {
        int sCur = sc * SLOT, sNxt = sn * SLOT;
        bf16x8 a0[4], bfv[4];
#pragma unroll
        for (int m = 0; m < 4; m++) a0[m] = *(const bf16x8*)&lds[sCur + aoff0 + m * 512];
#pragma unroll
        for (int n = 0; n < 4; n++) bfv[n] = *(const bf16x8*)&lds[sCur + boff0 + n * 512];
        if (t < 30) STG(t + 2, sNxt);
        BAR();
        __builtin_amdgcn_s_setprio(1);
#pragma unroll
        for (int m = 0; m < 4; m++)
#pragma unroll
            for (int n = 0; n < 4; n++) acc[m][n] = MFMA16(a0[m], bfv[n], acc[m][n]);
        __builtin_amdgcn_s_setprio(0);
        if (t < 30) { WAITV(4); } else if (t == 30) { WAITV(0); }
        BAR();
        sc = (sc == 2) ? 0 : sc + 1;
        sn = (sn == 2) ? 0 : sn + 1;
    }
#undef STG

    float bv[4];
#pragma unroll
    for (int n = 0; n < 4; n++) bv[n] = b0[(n0 & 1023) + wc * 64 + n * 16 + col];
#pragma unroll
    for (int m = 0; m < 4; m++) {
#pragma unroll
        for (int rr = 0; rr < 4; rr++) {
            int row = m0 + wr * 64 + m * 16 + fg * 4 + rr;
#pragma unroll
            for (int n = 0; n < 4; n++) {
                int c = n0 + wc * 64 + n * 16 + col;
                size_t idx = (size_t)row * ldc + c;
                float v = (acc[m][n][rr] + bv[n]) * sc0;
                if constexpr (EPI == 0) ((u16*)outp)[idx] = f2b(v);
                else if constexpr (EPI == 1) ((u16*)outp)[idx] = f2b(fmaxf(v, 0.f));
                else if constexpr (EPI == 2) ((float*)outp)[idx] = v + res[idx];
            }
        }
    }
}

// ---------------- flash attention v5 (r9-best, exact): 8 waves share KVBLK=64 staging; no-max softmax ----------------
__global__ __launch_bounds__(512) void attn_k(const u16* __restrict__ Q, int ldq,
                                              const u16* __restrict__ Kc, int ldk,
                                              const u16* __restrict__ VT,   // [(b*16+h)*64+dh][1024]
                                              const int* __restrict__ mask,
                                              u16* __restrict__ O, int ldo) {
    const int S = 1024;
    int gid = blockIdx.x;
    int bq = gid >> 7, hh = (gid >> 3) & 15, bb = gid & 7;
    int tid = threadIdx.x, lane = tid & 63, w = tid >> 6;   // w 0..7
    int q = lane & 31, hl = lane >> 5;
    int q0w = bq * 256 + w * 32;

    __shared__ u16 sm[18432];   // 36864 B: [buf][ K 64x72 | V^T 64x72 ]
#define KT(b, r, c) sm[(b) * 9216 + (r) * 72 + (c)]
#define VTL(b, r, c) sm[(b) * 9216 + 4608 + (r) * 72 + (c)]

    const u16* Qrow = Q + ((size_t)bb * S + q0w + q) * ldq + hh * 64;
    bool mneg = (mask[bb * S + q0w + q] == 0);
    bf16x8 qf[4];
#pragma unroll
    for (int c = 0; c < 4; c++) {
        qf[c] = *(const bf16x8*)(Qrow + c * 16 + hl * 8);
        if (mneg) qf[c] = (bf16x8)(__bf16)0.f;   // -> sc==0 -> p==1 (uniform)
    }

    float l = 0.f;
    f32x16 oa[2];
#pragma unroll
    for (int i = 0; i < 16; i++) { oa[0][i] = 0.f; oa[1][i] = 0.f; }

    int kk = tid >> 3, ks = tid & 7;
    const u16* gK = Kc + ((size_t)bb * S + kk) * ldk + hh * 64 + ks * 8;
    const u16* gVT = VT + ((size_t)(bb * 16 + hh) * 64 + kk) * 1024 + ks * 8;
    uint4 kr0, vr0;

#define LOADT(t)                                              \
    {                                                         \
        kr0 = *(const uint4*)(gK + (size_t)(t) * 64 * ldk);   \
        vr0 = *(const uint4*)(gVT + (size_t)(t) * 64);        \
    }
#define STORET(bf)                            \
    {                                         \
        *(uint4*)&KT(bf, kk, ks * 8) = kr0;   \
        *(uint4*)&VTL(bf, kk, ks * 8) = vr0;  \
    }

    LOADT(0);
    STORET(0);

    for (int t = 0; t < 16; ++t) {
        int cur = t & 1;
        if (t < 15) LOADT(t + 1);
        __syncthreads();

        f32x16 sc[2];
#pragma unroll
        for (int i = 0; i < 16; i++) { sc[0][i] = 0.f; sc[1][i] = 0.f; }
        __builtin_amdgcn_s_setprio(1);
#pragma unroll
        for (int st = 0; st < 2; st++)
#pragma unroll
            for (int c = 0; c < 4; c++) {
                bf16x8 kf = *(const bf16x8*)&KT(cur, st * 32 + q, c * 16 + hl * 8);
                sc[st] = MFMA32(kf, qf[c], sc[st]);
            }
        __builtin_amdgcn_s_setprio(0);

#pragma unroll
        for (int st = 0; st < 2; st++)
#pragma unroll
            for (int rr = 0; rr < 16; rr++) sc[st][rr] = exp2f(sc[st][rr]);
        float ts[8];
#pragma unroll
        for (int i = 0; i < 8; i++)
            ts[i] = (sc[0][i] + sc[0][i + 8]) + (sc[1][i] + sc[1][i + 8]);
#pragma unroll
        for (int i = 0; i < 4; i++) ts[i] += ts[i + 4];
        l += (ts[0] + ts[2]) + (ts[1] + ts[3]);

        __builtin_amdgcn_s_setprio(1);
#pragma unroll
        for (int st = 0; st < 2; st++) {
            u32 wv[8];
#pragma unroll
            for (int j = 0; j < 8; j++) wv[j] = pk2(sc[st][2 * j], sc[st][2 * j + 1]);
            PLSWAP(wv[0], wv[2]); PLSWAP(wv[1], wv[3]);
            PLSWAP(wv[4], wv[6]); PLSWAP(wv[5], wv[7]);
#pragma unroll
            for (int c = 0; c < 2; c++) {
                union { u32 u[4]; bf16x8 v; } pb;
                pb.u[0] = wv[c * 4 + 0]; pb.u[1] = wv[c * 4 + 1];
                pb.u[2] = wv[c * 4 + 2]; pb.u[3] = wv[c * 4 + 3];
#pragma unroll
                for (int dd = 0; dd < 2; dd++) {
                    bf16x8 vf = *(const bf16x8*)&VTL(cur, dd * 32 + q, st * 32 + c * 16 + hl * 8);
                    oa[dd] = MFMA32(vf, pb.v, oa[dd]);
                }
            }
        }
        __builtin_amdgcn_s_setprio(0);

        if (t < 15) STORET(cur ^ 1);
    }

    l += __shfl_xor(l, 32);
    __syncthreads();
    float inv = 1.0f / l;
    u16* otw = sm + w * 2304;
#pragma unroll
    for (int dd = 0; dd < 2; dd++)
#pragma unroll
        for (int rr = 0; rr < 16; rr++) {
            int d = (rr & 3) + 8 * (rr >> 2) + 4 * hl + 32 * dd;
            otw[q * 72 + d] = f2b(oa[dd][rr] * inv);
        }
    __syncthreads();
    size_t obase = ((size_t)bb * S + q0w) * ldo + hh * 64;
#pragma unroll
    for (int i = 0; i < 4; i++) {
        int row = i * 8 + (lane >> 3);
        uint4 vdat = *(const uint4*)&otw[row * 72 + (lane & 7) * 8];
        *(uint4*)(O + obase + (size_t)row * ldo + (lane & 7) * 8) = vdat;
    }
#undef KT
#undef VTL
#undef LOADT
#undef STORET
}

extern "C" void kernel_launch(void* const* d_in, const int* in_sizes, int n_in,
                              void* d_out, int out_size, void* d_ws, size_t ws_size,
                              hipStream_t stream) {
    (void)in_sizes; (void)n_in; (void)out_size; (void)ws_size;
    const float* x = (const float*)d_in[0];
    const float* h = (const float*)d_in[1];
    const int* mask = (const int*)d_in[2];
    const float* W[10];
    const float* Bv[10];
    for (int i = 0; i < 10; i++) { W[i] = (const float*)d_in[3 + i]; Bv[i] = (const float*)d_in[13 + i]; }
    const float *ln1g = (const float*)d_in[23], *ln1b = (const float*)d_in[24];
    const float *ln2g = (const float*)d_in[25], *ln2b = (const float*)d_in[26];
    const float *ln3g = (const float*)d_in[27], *ln3b = (const float*)d_in[28];
    const float *lnhg = (const float*)d_in[29], *lnhb = (const float*)d_in[30];
    const float *flng = (const float*)d_in[31], *flnb = (const float*)d_in[32];

    const float SCLE = 0.18033688011112042f;   // log2(e)/sqrt(64)

    char* ws = (char*)d_ws;
    size_t off = 0;
    auto alloc = [&](size_t bytes) -> char* {
        char* p = ws + off;
        off += (bytes + 255) & ~(size_t)255;
        return p;
    };
    const size_t MT = (size_t)8192 * 1024;
    u16* wtb = (u16*)alloc((size_t)10 * 1048576 * 2);
    u16* wt[10];
    for (int i = 0; i < 10; i++) wt[i] = wtb + (size_t)i * 1048576;
    u16* qkv = (u16*)alloc((size_t)8192 * 3072 * 2);   // sa QK(+dead V cols); later ca kv + ff1
    u16* kv = qkv;
    u16* kb = qkv + (size_t)8192 * 2048;
    u16* bufA = (u16*)alloc(MT * 2);
    u16* qb   = (u16*)alloc(MT * 2);          // ca Q, then ca attention out
    float* hid_in  = (float*)alloc(MT * 4);
    float* hid_mid = (float*)alloc(MT * 4);
    float* yf      = (float*)alloc(MT * 4);
    u16* hn = (u16*)yf;                        // hn lifetime disjoint from yf (FFN)
    u16* vtb = (u16*)hid_mid;                  // V^T buffer: hid_mid free until ca-WO gemm
    float* outF = (float*)d_out;

    W10 wp;
    for (int i = 0; i < 10; i++) wp.p[i] = W[i];
    tcvt_k<<<dim3(32, 32, 10), dim3(32, 8), 0, stream>>>(wp, wtb);

    // ---- self-attention block ----
    ln_k<4><<<8192, 256, 0, stream>>>(x, nullptr, ln1g, ln1b, nullptr, nullptr, bufA);
    gemm512_k<0, 24, 2><<<768, 512, 0, stream>>>(bufA, 1024, wt[0], Bv[0], Bv[1], Bv[2], SCLE, 1.f, 1.f, nullptr, qkv, 3072, vtb);
    attn_k<<<512, 512, 0, stream>>>(qkv, 3072, qkv + 1024, 3072, vtb, mask, qkv, 3072);
    gemm256_k<2, 8><<<512, 256, 0, stream>>>(qkv, 3072, wt[3], Bv[3], 1.f, x, hid_in, 1024);

    // ---- cross-attention block ----
    ln2x_k<<<16384, 256, 0, stream>>>(hid_in, ln2g, ln2b, bufA, h, lnhg, lnhb, hn);
    gemm256_k<0, 8><<<512, 256, 0, stream>>>(bufA, 1024, wt[4], Bv[4], SCLE, nullptr, qb, 1024);
    gemm512_k<0, 16, 1><<<512, 512, 0, stream>>>(hn, 1024, wt[5], Bv[5], Bv[6], Bv[6], 1.f, 1.f, 1.f, nullptr, kv, 2048, vtb);
    attn_k<<<512, 512, 0, stream>>>(qb, 1024, kv, 2048, vtb, mask, qb, 1024);
    gemm256_k<2, 8><<<512, 256, 0, stream>>>(qb, 1024, wt[7], Bv[7], 1.f, hid_in, hid_mid, 1024);

    // ---- FFN block ----
    ln_k<6><<<8192, 256, 0, stream>>>(hid_mid, nullptr, ln3g, ln3b, nullptr, yf, bufA);
    gemm256_k<1, 8><<<512, 256, 0, stream>>>(bufA, 1024, wt[8], Bv[8], 1.f, nullptr, kb, 1024);
    gemm256_k<2, 8><<<512, 256, 0, stream>>>(kb, 1024, wt[9], Bv[9], 1.f, yf, hid_in, 1024);
    ln_k<10><<<8192, 256, 0, stream>>>(hid_in, nullptr, flng, flnb, hid_mid, outF, nullptr);
}

// Round 18
// 420.016 us; speedup vs baseline: 1.1045x; 1.0222x over previous
//
#include <hip/hip_runtime.h>

typedef unsigned short u16;
typedef unsigned int u32;
typedef float f32x4 __attribute__((ext_vector_type(4)));
typedef float f32x16 __attribute__((ext_vector_type(16)));
typedef __bf16 bf16x8 __attribute__((ext_vector_type(8)));

#define MFMA16(a, b, c) __builtin_amdgcn_mfma_f32_16x16x32_bf16(a, b, c, 0, 0, 0)
#define MFMA32(a, b, c) __builtin_amdgcn_mfma_f32_32x32x16_bf16(a, b, c, 0, 0, 0)
#define PLSWAP(x, y) asm volatile("v_permlane32_swap_b32 %0, %1" : "+v"(x), "+v"(y))
#define CFENCE() asm volatile("" ::: "memory")
#define BAR()                         \
    {                                 \
        CFENCE();                     \
        __builtin_amdgcn_s_barrier(); \
        CFENCE();                     \
    }
#define WAITV(n) asm volatile("s_waitcnt vmcnt(" #n ")" ::: "memory")

__device__ __forceinline__ u16 f2b(float f) {
    u32 u = __builtin_bit_cast(u32, f);
    u += 0x7fffu + ((u >> 16) & 1u);   // round-to-nearest-even
    return (u16)(u >> 16);
}

__device__ __forceinline__ float b2f(u16 v) {
    u32 u = ((u32)v) << 16;
    return __builtin_bit_cast(float, u);
}

__device__ __forceinline__ u32 pk2(float a, float b) {
    union { u32 u; __bf16 h[2]; } r;
    r.h[0] = (__bf16)a; r.h[1] = (__bf16)b;
    return r.u;   // v_cvt_pk_bf16_f32
}

__device__ __forceinline__ void gload16(const u16* g, u16* l) {
    __builtin_amdgcn_global_load_lds((const __attribute__((address_space(1))) void*)g,
                                     (__attribute__((address_space(3))) void*)l, 16, 0, 0);
}

// ---------------- weight transpose + f32->bf16 convert (all 10 in one launch) ----------------
struct W10 { const float* p[10]; };
__global__ __launch_bounds__(256) void tcvt_k(W10 wp, u16* __restrict__ WT0) {
    const float* __restrict__ Wm = wp.p[blockIdx.z];
    u16* __restrict__ WT = WT0 + (size_t)blockIdx.z * 1048576;
    __shared__ float t[32][33];
    int bx = blockIdx.x, by = blockIdx.y;
    int tx = threadIdx.x, ty = threadIdx.y;   // (32,8)
#pragma unroll
    for (int j = 0; j < 32; j += 8)
        t[ty + j][tx] = Wm[(size_t)(by * 32 + ty + j) * 1024 + bx * 32 + tx];
    __syncthreads();
#pragma unroll
    for (int j = 0; j < 32; j += 8)
        WT[(size_t)(bx * 32 + ty + j) * 1024 + by * 32 + tx] = f2b(t[tx][ty + j]);
}

// ---------------- fused LayerNorm (block-per-row, proven) ----------------
// MODE bit0: x = in1 + in2 ; bit1: write f32 out (bit3: += post) ; bit2: write bf16 out
template <int MODE>
__global__ __launch_bounds__(256) void ln_k(const float* __restrict__ in1, const float* __restrict__ in2,
                                            const float* __restrict__ gg, const float* __restrict__ bb,
                                            const float* __restrict__ post,
                                            float* __restrict__ of, u16* __restrict__ ob) {
    int row = blockIdx.x, tid = threadIdx.x;
    size_t base = (size_t)row * 1024 + tid * 4;
    float4 x = *(const float4*)(in1 + base);
    if constexpr (MODE & 1) {
        float4 x2 = *(const float4*)(in2 + base);
        x.x += x2.x; x.y += x2.y; x.z += x2.z; x.w += x2.w;
    }
    float s1 = x.x + x.y + x.z + x.w;
    float s2 = x.x * x.x + x.y * x.y + x.z * x.z + x.w * x.w;
#pragma unroll
    for (int m = 32; m >= 1; m >>= 1) { s1 += __shfl_xor(s1, m); s2 += __shfl_xor(s2, m); }
    __shared__ float r1[4], r2[4];
    int lane = tid & 63, w = tid >> 6;
    if (lane == 0) { r1[w] = s1; r2[w] = s2; }
    __syncthreads();
    s1 = r1[0] + r1[1] + r1[2] + r1[3];
    s2 = r2[0] + r2[1] + r2[2] + r2[3];
    float mean = s1 * (1.0f / 1024.0f);
    float var = s2 * (1.0f / 1024.0f) - mean * mean;
    float rstd = rsqrtf(var + 1e-5f);
    float4 gv = *(const float4*)(gg + tid * 4);
    float4 bv = *(const float4*)(bb + tid * 4);
    float y0 = (x.x - mean) * rstd * gv.x + bv.x;
    float y1 = (x.y - mean) * rstd * gv.y + bv.y;
    float y2 = (x.z - mean) * rstd * gv.z + bv.z;
    float y3 = (x.w - mean) * rstd * gv.w + bv.w;
    if constexpr (MODE & 2) {
        float o0 = y0, o1 = y1, o2 = y2, o3 = y3;
        if constexpr (MODE & 8) {
            float4 p = *(const float4*)(post + base);
            o0 += p.x; o1 += p.y; o2 += p.z; o3 += p.w;
        }
        float4 o; o.x = o0; o.y = o1; o.z = o2; o.w = o3;
        *(float4*)(of + base) = o;
    }
    if constexpr (MODE & 4) {
        uint2 pk;
        pk.x = (u32)f2b(y0) | ((u32)f2b(y1) << 16);
        pk.y = (u32)f2b(y2) | ((u32)f2b(y3) << 16);
        *(uint2*)(ob + base) = pk;
    }
}

// ---------------- dual LayerNorm: two independent MODE-4 LNs in one launch ----------------
__global__ __launch_bounds__(256) void ln2x_k(const float* __restrict__ inA, const float* __restrict__ gA,
                                              const float* __restrict__ bA, u16* __restrict__ obA,
                                              const float* __restrict__ inB, const float* __restrict__ gB,
                                              const float* __restrict__ bB, u16* __restrict__ obB) {
    int sel = blockIdx.x >> 13;
    int row = blockIdx.x & 8191;
    const float* in1 = sel ? inB : inA;
    const float* gg = sel ? gB : gA;
    const float* bb = sel ? bB : bA;
    u16* ob = sel ? obB : obA;
    int tid = threadIdx.x;
    size_t base = (size_t)row * 1024 + tid * 4;
    float4 x = *(const float4*)(in1 + base);
    float s1 = x.x + x.y + x.z + x.w;
    float s2 = x.x * x.x + x.y * x.y + x.z * x.z + x.w * x.w;
#pragma unroll
    for (int m = 32; m >= 1; m >>= 1) { s1 += __shfl_xor(s1, m); s2 += __shfl_xor(s2, m); }
    __shared__ float r1[4], r2[4];
    int lane = tid & 63, w = tid >> 6;
    if (lane == 0) { r1[w] = s1; r2[w] = s2; }
    __syncthreads();
    s1 = r1[0] + r1[1] + r1[2] + r1[3];
    s2 = r2[0] + r2[1] + r2[2] + r2[3];
    float mean = s1 * (1.0f / 1024.0f);
    float var = s2 * (1.0f / 1024.0f) - mean * mean;
    float rstd = rsqrtf(var + 1e-5f);
    float4 gv = *(const float4*)(gg + tid * 4);
    float4 bv = *(const float4*)(bb + tid * 4);
    uint2 pk;
    pk.x = pk2((x.x - mean) * rstd * gv.x + bv.x, (x.y - mean) * rstd * gv.y + bv.y);
    pk.y = pk2((x.z - mean) * rstd * gv.z + bv.z, (x.w - mean) * rstd * gv.w + bv.w);
    *(uint2*)(ob + base) = pk;
}

// ---------------- bf16 GEMM v512 (phase-split) + fused V-transpose epilogue ----------------
template <int EPI, int NBN, int VSEG>
__global__ __launch_bounds__(512) void gemm512_k(const u16* __restrict__ A, int lda,
                                                 const u16* __restrict__ WT,
                                                 const float* __restrict__ b0, const float* __restrict__ b1,
                                                 const float* __restrict__ b2,
                                                 float sc0, float sc1, float sc2,
                                                 const float* __restrict__ res,
                                                 void* __restrict__ outp, int ldc,
                                                 u16* __restrict__ vt) {
    constexpr int ASZ = 8192;
    constexpr int SLOT = ASZ + 4096;
    __shared__ u16 lds[3 * SLOT];
    u16* ldsb = &lds[0];

    int id = blockIdx.x;
    constexpr int NWG = 32 * NBN;
    constexpr int CPX = NWG / 8;
    int swz = (id & 7) * CPX + (id >> 3);   // XCD-contiguous bijective remap
    int bm = swz / NBN, bn = swz % NBN;
    const int m0 = bm * 256, n0 = bn * 128;
    int tid = threadIdx.x, lane = tid & 63, w = tid >> 6;
    int col = lane & 15, fg = lane >> 4;
    int wr = w >> 1, wc = w & 1;

    int swzL = ((col * 32) + fg * 8) ^ ((col >> 1) << 3);
    int aoff0 = wr * 64 * 32 + swzL;
    int boff0 = ASZ + wc * 64 * 32 + swzL;

    int r = tid >> 2, g = tid & 3;
    int gr = r ^ ((r >> 3) & 1);
    int gc = g ^ ((r >> 1) & 3);
    const u16* pA = A + (size_t)(m0 + gr) * lda + gc * 8;
    const u16* pB = WT + (size_t)(n0 + gr) * 1024 + gc * 8;

#define STGA(t2, snO)                                                                       \
    {                                                                                       \
        gload16(pA + (size_t)(t2) * 32, ldsb + (snO) + w * 512);                            \
        gload16(pA + (size_t)(t2) * 32 + (size_t)128 * lda, ldsb + (snO) + 4096 + w * 512); \
    }
#define STGB(t2, snO)                                                   \
    {                                                                   \
        gload16(pB + (size_t)(t2) * 32, ldsb + (snO) + ASZ + w * 512);  \
    }

    f32x4 acc[4][4];
#pragma unroll
    for (int m = 0; m < 4; m++)
#pragma unroll
        for (int n = 0; n < 4; n++) acc[m][n] = (f32x4){0.f, 0.f, 0.f, 0.f};

    STGA(0, 0); STGB(0, 0);
    STGA(1, SLOT); STGB(1, SLOT);
    WAITV(3);
    BAR();

    int sc = 0, sn = 2;
    for (int t = 0; t < 32; ++t) {
        int sCur = sc * SLOT, sNxt = sn * SLOT;
        // ---- phase 0: A-frags + first 2 B-frags, stage A of t+2, 8 MFMA ----
        bf16x8 a0[4], bfv[2];
#pragma unroll
        for (int m = 0; m < 4; m++) a0[m] = *(const bf16x8*)&ldsb[sCur + aoff0 + m * 512];
#pragma unroll
        for (int n = 0; n < 2; n++) bfv[n] = *(const bf16x8*)&ldsb[sCur + boff0 + n * 512];
        if (t < 30) STGA(t + 2, sNxt);
        BAR();
        __builtin_amdgcn_s_setprio(1);
#pragma unroll
        for (int m = 0; m < 4; m++)
#pragma unroll
            for (int n = 0; n < 2; n++) acc[m][n] = MFMA16(a0[m], bfv[n], acc[m][n]);
        __builtin_amdgcn_s_setprio(0);
        BAR();
        // ---- phase 1: last 2 B-frags, stage B of t+2, 8 MFMA, counted wait ----
        bf16x8 b2[2];
#pragma unroll
        for (int n = 0; n < 2; n++) b2[n] = *(const bf16x8*)&ldsb[sCur + boff0 + (n + 2) * 512];
        if (t < 30) STGB(t + 2, sNxt);
        BAR();
        __builtin_amdgcn_s_setprio(1);
#pragma unroll
        for (int m = 0; m < 4; m++)
#pragma unroll
            for (int n = 0; n < 2; n++) acc[m][n + 2] = MFMA16(a0[m], b2[n], acc[m][n + 2]);
        __builtin_amdgcn_s_setprio(0);
        if (t < 30) { WAITV(3); } else if (t == 30) { WAITV(0); }
        BAR();
        sc = (sc == 2) ? 0 : sc + 1;
        sn = (sn == 2) ? 0 : sn + 1;
    }
#undef STGA
#undef STGB

    int seg = n0 >> 10;
    const float* bp = (seg == 0) ? b0 : (seg == 1 ? b1 : b2);
    float sg = (seg == 0) ? sc0 : (seg == 1 ? sc1 : sc2);
    int nseg = n0 & 1023;
    float bv[4];
#pragma unroll
    for (int n = 0; n < 4; n++) bv[n] = bp[nseg + wc * 64 + n * 16 + col];

    if constexpr (VSEG >= 0) {
        if (seg == VSEG) {
            // transposed V write: vt[(b*1024 + ch)][key], 4 consecutive keys -> 8B packed store
            int bidx = m0 >> 10;
            int key0 = (m0 & 1023) + wr * 64 + fg * 4;
#pragma unroll
            for (int m = 0; m < 4; m++) {
#pragma unroll
                for (int n = 0; n < 4; n++) {
                    int ch = nseg + wc * 64 + n * 16 + col;
                    uint2 pk;
                    pk.x = pk2(acc[m][n][0] + bv[n], acc[m][n][1] + bv[n]);
                    pk.y = pk2(acc[m][n][2] + bv[n], acc[m][n][3] + bv[n]);
                    *(uint2*)(vt + ((size_t)(bidx * 1024 + ch) << 10) + key0 + m * 16) = pk;
                }
            }
            return;
        }
    }
#pragma unroll
    for (int m = 0; m < 4; m++) {
#pragma unroll
        for (int rr = 0; rr < 4; rr++) {
            int row = m0 + wr * 64 + m * 16 + fg * 4 + rr;
#pragma unroll
            for (int n = 0; n < 4; n++) {
                int c = n0 + wc * 64 + n * 16 + col;
                size_t idx = (size_t)row * ldc + c;
                float v = (acc[m][n][rr] + bv[n]) * sg;
                if constexpr (EPI == 0) ((u16*)outp)[idx] = f2b(v);
                else if constexpr (EPI == 1) ((u16*)outp)[idx] = f2b(fmaxf(v, 0.f));
                else if constexpr (EPI == 2) ((float*)outp)[idx] = v + res[idx];
            }
        }
    }
}

// ---------------- bf16 GEMM v256b (merged — measured best for 4-wave): BM=128/BN=128 ----------------
// EPI: 0 = bias -> bf16 ; 1 = bias+relu -> bf16 ; 2 = bias + f32 res -> f32 ; 3 = bias + bf16 res -> f32
template <int EPI, int NBN>
__global__ __launch_bounds__(256) void gemm256_k(const u16* __restrict__ A, int lda,
                                                 const u16* __restrict__ WT,
                                                 const float* __restrict__ b0,
                                                 float sc0,
                                                 const void* __restrict__ res,
                                                 void* __restrict__ outp, int ldc) {
    constexpr int SLOT = 8192;
    __shared__ u16 lds[3 * SLOT];
    int id = blockIdx.x;
    constexpr int NWG = 64 * NBN;
    constexpr int CPX = NWG / 8;
    int swz = (id & 7) * CPX + (id >> 3);
    int bm = swz / NBN, bn = swz % NBN;
    const int m0 = bm * 128, n0 = bn * 128;
    int tid = threadIdx.x, lane = tid & 63, w = tid >> 6;
    int col = lane & 15, fg = lane >> 4;
    int wr = w >> 1, wc = w & 1;

    int swzL = ((col * 32) + fg * 8) ^ ((col >> 1) << 3);
    int aoff0 = wr * 64 * 32 + swzL;
    int boff0 = 4096 + wc * 64 * 32 + swzL;

    int r = tid >> 2, g = tid & 3;
    int gr = r ^ ((r >> 3) & 1);
    int gc = g ^ ((r >> 1) & 3);
    const u16* pA = A + (size_t)(m0 + gr) * lda + gc * 8;
    const u16* pB = WT + (size_t)(n0 + gr) * 1024 + gc * 8;

#define STG(t2, snO)                                                                              \
    {                                                                                             \
        gload16(pA + (size_t)(t2) * 32, lds + (snO) + w * 512);                                   \
        gload16(pA + (size_t)(t2) * 32 + (size_t)64 * lda, lds + (snO) + 2048 + w * 512);         \
        gload16(pB + (size_t)(t2) * 32, lds + (snO) + 4096 + w * 512);                            \
        gload16(pB + (size_t)(t2) * 32 + (size_t)64 * 1024, lds + (snO) + 4096 + 2048 + w * 512); \
    }

    f32x4 acc[4][4];
#pragma unroll
    for (int m = 0; m < 4; m++)
#pragma unroll
        for (int n = 0; n < 4; n++) acc[m][n] = (f32x4){0.f, 0.f, 0.f, 0.f};

    STG(0, 0);
    STG(1, SLOT);
    WAITV(4);
    BAR();

    int sc = 0, sn = 2;
    for (int t = 0; t < 32; ++t) {
        int sCur = sc * SLOT, sNxt = sn * SLOT;
        bf16x8 a0[4], bfv[4];
#pragma unroll
        for (int m = 0; m < 4; m++) a0[m] = *(const bf16x8*)&lds[sCur + aoff0 + m * 512];
#pragma unroll
        for (int n = 0; n < 4; n++) bfv[n] = *(const bf16x8*)&lds[sCur + boff0 + n * 512];
        if (t < 30) STG(t + 2, sNxt);
        BAR();
        __builtin_amdgcn_s_setprio(1);
#pragma unroll
        for (int m = 0; m < 4; m++)
#pragma unroll
            for (int n = 0; n < 4; n++) acc[m][n] = MFMA16(a0[m], bfv[n], acc[m][n]);
        __builtin_amdgcn_s_setprio(0);
        if (t < 30) { WAITV(4); } else if (t == 30) { WAITV(0); }
        BAR();
        sc = (sc == 2) ? 0 : sc + 1;
        sn = (sn == 2) ? 0 : sn + 1;
    }
#undef STG

    float bv[4];
#pragma unroll
    for (int n = 0; n < 4; n++) bv[n] = b0[(n0 & 1023) + wc * 64 + n * 16 + col];
#pragma unroll
    for (int m = 0; m < 4; m++) {
#pragma unroll
        for (int rr = 0; rr < 4; rr++) {
            int row = m0 + wr * 64 + m * 16 + fg * 4 + rr;
#pragma unroll
            for (int n = 0; n < 4; n++) {
                int c = n0 + wc * 64 + n * 16 + col;
                size_t idx = (size_t)row * ldc + c;
                float v = (acc[m][n][rr] + bv[n]) * sc0;
                if constexpr (EPI == 0) ((u16*)outp)[idx] = f2b(v);
                else if constexpr (EPI == 1) ((u16*)outp)[idx] = f2b(fmaxf(v, 0.f));
                else if constexpr (EPI == 2) ((float*)outp)[idx] = v + ((const float*)res)[idx];
                else if constexpr (EPI == 3) ((float*)outp)[idx] = v + b2f(((const u16*)res)[idx]);
            }
        }
    }
}

// ---------------- flash attention v5 (r9-best, exact): 8 waves share KVBLK=64 staging; no-max softmax ----------------
__global__ __launch_bounds__(512) void attn_k(const u16* __restrict__ Q, int ldq,
                                              const u16* __restrict__ Kc, int ldk,
                                              const u16* __restrict__ VT,   // [(b*16+h)*64+dh][1024]
                                              const int* __restrict__ mask,
                                              u16* __restrict__ O, int ldo) {
    const int S = 1024;
    int gid = blockIdx.x;
    int bq = gid >> 7, hh = (gid >> 3) & 15, bb = gid & 7;
    int tid = threadIdx.x, lane = tid & 63, w = tid >> 6;   // w 0..7
    int q = lane & 31, hl = lane >> 5;
    int q0w = bq * 256 + w * 32;

    __shared__ u16 sm[18432];   // 36864 B: [buf][ K 64x72 | V^T 64x72 ]
#define KT(b, r, c) sm[(b) * 9216 + (r) * 72 + (c)]
#define VTL(b, r, c) sm[(b) * 9216 + 4608 + (r) * 72 + (c)]

    const u16* Qrow = Q + ((size_t)bb * S + q0w + q) * ldq + hh * 64;
    bool mneg = (mask[bb * S + q0w + q] == 0);
    bf16x8 qf[4];
#pragma unroll
    for (int c = 0; c < 4; c++) {
        qf[c] = *(const bf16x8*)(Qrow + c * 16 + hl * 8);
        if (mneg) qf[c] = (bf16x8)(__bf16)0.f;   // -> sc==0 -> p==1 (uniform)
    }

    float l = 0.f;
    f32x16 oa[2];
#pragma unroll
    for (int i = 0; i < 16; i++) { oa[0][i] = 0.f; oa[1][i] = 0.f; }

    int kk = tid >> 3, ks = tid & 7;
    const u16* gK = Kc + ((size_t)bb * S + kk) * ldk + hh * 64 + ks * 8;
    const u16* gVT = VT + ((size_t)(bb * 16 + hh) * 64 + kk) * 1024 + ks * 8;
    uint4 kr0, vr0;

#define LOADT(t)                                              \
    {                                                         \
        kr0 = *(const uint4*)(gK + (size_t)(t) * 64 * ldk);   \
        vr0 = *(const uint4*)(gVT + (size_t)(t) * 64);        \
    }
#define STORET(bf)                            \
    {                                         \
        *(uint4*)&KT(bf, kk, ks * 8) = kr0;   \
        *(uint4*)&VTL(bf, kk, ks * 8) = vr0;  \
    }

    LOADT(0);
    STORET(0);

    for (int t = 0; t < 16; ++t) {
        int cur = t & 1;
        if (t < 15) LOADT(t + 1);
        __syncthreads();

        f32x16 sc[2];
#pragma unroll
        for (int i = 0; i < 16; i++) { sc[0][i] = 0.f; sc[1][i] = 0.f; }
        __builtin_amdgcn_s_setprio(1);
#pragma unroll
        for (int st = 0; st < 2; st++)
#pragma unroll
            for (int c = 0; c < 4; c++) {
                bf16x8 kf = *(const bf16x8*)&KT(cur, st * 32 + q, c * 16 + hl * 8);
                sc[st] = MFMA32(kf, qf[c], sc[st]);
            }
        __builtin_amdgcn_s_setprio(0);

#pragma unroll
        for (int st = 0; st < 2; st++)
#pragma unroll
            for (int rr = 0; rr < 16; rr++) sc[st][rr] = exp2f(sc[st][rr]);
        float ts[8];
#pragma unroll
        for (int i = 0; i < 8; i++)
            ts[i] = (sc[0][i] + sc[0][i + 8]) + (sc[1][i] + sc[1][i + 8]);
#pragma unroll
        for (int i = 0; i < 4; i++) ts[i] += ts[i + 4];
        l += (ts[0] + ts[2]) + (ts[1] + ts[3]);

        __builtin_amdgcn_s_setprio(1);
#pragma unroll
        for (int st = 0; st < 2; st++) {
            u32 wv[8];
#pragma unroll
            for (int j = 0; j < 8; j++) wv[j] = pk2(sc[st][2 * j], sc[st][2 * j + 1]);
            PLSWAP(wv[0], wv[2]); PLSWAP(wv[1], wv[3]);
            PLSWAP(wv[4], wv[6]); PLSWAP(wv[5], wv[7]);
#pragma unroll
            for (int c = 0; c < 2; c++) {
                union { u32 u[4]; bf16x8 v; } pb;
                pb.u[0] = wv[c * 4 + 0]; pb.u[1] = wv[c * 4 + 1];
                pb.u[2] = wv[c * 4 + 2]; pb.u[3] = wv[c * 4 + 3];
#pragma unroll
                for (int dd = 0; dd < 2; dd++) {
                    bf16x8 vf = *(const bf16x8*)&VTL(cur, dd * 32 + q, st * 32 + c * 16 + hl * 8);
                    oa[dd] = MFMA32(vf, pb.v, oa[dd]);
                }
            }
        }
        __builtin_amdgcn_s_setprio(0);

        if (t < 15) STORET(cur ^ 1);
    }

    l += __shfl_xor(l, 32);
    __syncthreads();
    float inv = 1.0f / l;
    u16* otw = sm + w * 2304;
#pragma unroll
    for (int dd = 0; dd < 2; dd++)
#pragma unroll
        for (int rr = 0; rr < 16; rr++) {
            int d = (rr & 3) + 8 * (rr >> 2) + 4 * hl + 32 * dd;
            otw[q * 72 + d] = f2b(oa[dd][rr] * inv);
        }
    __syncthreads();
    size_t obase = ((size_t)bb * S + q0w) * ldo + hh * 64;
#pragma unroll
    for (int i = 0; i < 4; i++) {
        int row = i * 8 + (lane >> 3);
        uint4 vdat = *(const uint4*)&otw[row * 72 + (lane & 7) * 8];
        *(uint4*)(O + obase + (size_t)row * ldo + (lane & 7) * 8) = vdat;
    }
#undef KT
#undef VTL
#undef LOADT
#undef STORET
}

extern "C" void kernel_launch(void* const* d_in, const int* in_sizes, int n_in,
                              void* d_out, int out_size, void* d_ws, size_t ws_size,
                              hipStream_t stream) {
    (void)in_sizes; (void)n_in; (void)out_size; (void)ws_size;
    const float* x = (const float*)d_in[0];
    const float* h = (const float*)d_in[1];
    const int* mask = (const int*)d_in[2];
    const float* W[10];
    const float* Bv[10];
    for (int i = 0; i < 10; i++) { W[i] = (const float*)d_in[3 + i]; Bv[i] = (const float*)d_in[13 + i]; }
    const float *ln1g = (const float*)d_in[23], *ln1b = (const float*)d_in[24];
    const float *ln2g = (const float*)d_in[25], *ln2b = (const float*)d_in[26];
    const float *ln3g = (const float*)d_in[27], *ln3b = (const float*)d_in[28];
    const float *lnhg = (const float*)d_in[29], *lnhb = (const float*)d_in[30];
    const float *flng = (const float*)d_in[31], *flnb = (const float*)d_in[32];

    const float SCLE = 0.18033688011112042f;   // log2(e)/sqrt(64)

    char* ws = (char*)d_ws;
    size_t off = 0;
    auto alloc = [&](size_t bytes) -> char* {
        char* p = ws + off;
        off += (bytes + 255) & ~(size_t)255;
        return p;
    };
    const size_t MT = (size_t)8192 * 1024;
    u16* wtb = (u16*)alloc((size_t)10 * 1048576 * 2);
    u16* wt[10];
    for (int i = 0; i < 10; i++) wt[i] = wtb + (size_t)i * 1048576;
    u16* qkv = (u16*)alloc((size_t)8192 * 3072 * 2);   // sa QK(+dead V cols); later ca kv + ff1
    u16* kv = qkv;
    u16* kb = qkv + (size_t)8192 * 2048;
    u16* bufA = (u16*)alloc(MT * 2);
    u16* qb   = (u16*)alloc(MT * 2);          // ca Q, then ca attention out
    float* hid_in  = (float*)alloc(MT * 4);
    float* hid_mid = (float*)alloc(MT * 4);
    float* yf      = (float*)alloc(MT * 4);
    u16* hn = (u16*)yf;                        // hn lifetime disjoint from FFN
    u16* vtb = (u16*)hid_mid;                  // V^T buffer: hid_mid free until ca-WO gemm
    float* outF = (float*)d_out;

    W10 wp;
    for (int i = 0; i < 10; i++) wp.p[i] = W[i];
    tcvt_k<<<dim3(32, 32, 10), dim3(32, 8), 0, stream>>>(wp, wtb);

    // ---- self-attention block ----
    ln_k<4><<<8192, 256, 0, stream>>>(x, nullptr, ln1g, ln1b, nullptr, nullptr, bufA);
    gemm512_k<0, 24, 2><<<768, 512, 0, stream>>>(bufA, 1024, wt[0], Bv[0], Bv[1], Bv[2], SCLE, 1.f, 1.f, nullptr, qkv, 3072, vtb);
    attn_k<<<512, 512, 0, stream>>>(qkv, 3072, qkv + 1024, 3072, vtb, mask, qkv, 3072);
    gemm256_k<2, 8><<<512, 256, 0, stream>>>(qkv, 3072, wt[3], Bv[3], 1.f, x, hid_in, 1024);

    // ---- cross-attention block ----
    ln2x_k<<<16384, 256, 0, stream>>>(hid_in, ln2g, ln2b, bufA, h, lnhg, lnhb, hn);
    gemm256_k<0, 8><<<512, 256, 0, stream>>>(bufA, 1024, wt[4], Bv[4], SCLE, nullptr, qb, 1024);
    gemm512_k<0, 16, 1><<<512, 512, 0, stream>>>(hn, 1024, wt[5], Bv[5], Bv[6], Bv[6], 1.f, 1.f, 1.f, nullptr, kv, 2048, vtb);
    attn_k<<<512, 512, 0, stream>>>(qb, 1024, kv, 2048, vtb, mask, qb, 1024);
    gemm256_k<2, 8><<<512, 256, 0, stream>>>(qb, 1024, wt[7], Bv[7], 1.f, hid_in, hid_mid, 1024);

    // ---- FFN block ----
    // y stored once as bf16 (bufA); reused as ff1 input AND ff2's residual (bf16 round of y).
    ln_k<4><<<8192, 256, 0, stream>>>(hid_mid, nullptr, ln3g, ln3b, nullptr, nullptr, bufA);
    gemm256_k<1, 8><<<512, 256, 0, stream>>>(bufA, 1024, wt[8], Bv[8], 1.f, nullptr, kb, 1024);
    gemm256_k<3, 8><<<512, 256, 0, stream>>>(kb, 1024, wt[9], Bv[9], 1.f, bufA, hid_in, 1024);
    ln_k<10><<<8192, 256, 0, stream>>>(hid_in, nullptr, flng, flnb, hid_mid, outF, nullptr);
}

// Round 19
// 418.129 us; speedup vs baseline: 1.1094x; 1.0045x over previous
//
#include <hip/hip_runtime.h>

typedef unsigned short u16;
typedef unsigned int u32;
typedef float f32x4 __attribute__((ext_vector_type(4)));
typedef float f32x16 __attribute__((ext_vector_type(16)));
typedef __bf16 bf16x8 __attribute__((ext_vector_type(8)));

#define MFMA16(a, b, c) __builtin_amdgcn_mfma_f32_16x16x32_bf16(a, b, c, 0, 0, 0)
#define MFMA32(a, b, c) __builtin_amdgcn_mfma_f32_32x32x16_bf16(a, b, c, 0, 0, 0)
#define PLSWAP(x, y) asm volatile("v_permlane32_swap_b32 %0, %1" : "+v"(x), "+v"(y))
#define CFENCE() asm volatile("" ::: "memory")
#define BAR()                         \
    {                                 \
        CFENCE();                     \
        __builtin_amdgcn_s_barrier(); \
        CFENCE();                     \
    }
#define WAITV(n) asm volatile("s_waitcnt vmcnt(" #n ")" ::: "memory")

__device__ __forceinline__ u16 f2b(float f) {
    u32 u = __builtin_bit_cast(u32, f);
    u += 0x7fffu + ((u >> 16) & 1u);   // round-to-nearest-even
    return (u16)(u >> 16);
}

__device__ __forceinline__ float b2f(u16 v) {
    u32 u = ((u32)v) << 16;
    return __builtin_bit_cast(float, u);
}

__device__ __forceinline__ u32 pk2(float a, float b) {
    union { u32 u; __bf16 h[2]; } r;
    r.h[0] = (__bf16)a; r.h[1] = (__bf16)b;
    return r.u;   // v_cvt_pk_bf16_f32
}

__device__ __forceinline__ void gload16(const u16* g, u16* l) {
    __builtin_amdgcn_global_load_lds((const __attribute__((address_space(1))) void*)g,
                                     (__attribute__((address_space(3))) void*)l, 16, 0, 0);
}

// ---------------- weight transpose + f32->bf16 convert (all 10 in one launch) ----------------
struct W10 { const float* p[10]; };
__global__ __launch_bounds__(256) void tcvt_k(W10 wp, u16* __restrict__ WT0) {
    const float* __restrict__ Wm = wp.p[blockIdx.z];
    u16* __restrict__ WT = WT0 + (size_t)blockIdx.z * 1048576;
    __shared__ float t[32][33];
    int bx = blockIdx.x, by = blockIdx.y;
    int tx = threadIdx.x, ty = threadIdx.y;   // (32,8)
#pragma unroll
    for (int j = 0; j < 32; j += 8)
        t[ty + j][tx] = Wm[(size_t)(by * 32 + ty + j) * 1024 + bx * 32 + tx];
    __syncthreads();
#pragma unroll
    for (int j = 0; j < 32; j += 8)
        WT[(size_t)(bx * 32 + ty + j) * 1024 + by * 32 + tx] = f2b(t[tx][ty + j]);
}

// ---------------- fused LayerNorm (block-per-row, proven) ----------------
// MODE bit0: x = in1 + in2 ; bit1: write f32 out (bit3: += post) ; bit2: write bf16 out
template <int MODE>
__global__ __launch_bounds__(256) void ln_k(const float* __restrict__ in1, const float* __restrict__ in2,
                                            const float* __restrict__ gg, const float* __restrict__ bb,
                                            const float* __restrict__ post,
                                            float* __restrict__ of, u16* __restrict__ ob) {
    int row = blockIdx.x, tid = threadIdx.x;
    size_t base = (size_t)row * 1024 + tid * 4;
    float4 x = *(const float4*)(in1 + base);
    if constexpr (MODE & 1) {
        float4 x2 = *(const float4*)(in2 + base);
        x.x += x2.x; x.y += x2.y; x.z += x2.z; x.w += x2.w;
    }
    float s1 = x.x + x.y + x.z + x.w;
    float s2 = x.x * x.x + x.y * x.y + x.z * x.z + x.w * x.w;
#pragma unroll
    for (int m = 32; m >= 1; m >>= 1) { s1 += __shfl_xor(s1, m); s2 += __shfl_xor(s2, m); }
    __shared__ float r1[4], r2[4];
    int lane = tid & 63, w = tid >> 6;
    if (lane == 0) { r1[w] = s1; r2[w] = s2; }
    __syncthreads();
    s1 = r1[0] + r1[1] + r1[2] + r1[3];
    s2 = r2[0] + r2[1] + r2[2] + r2[3];
    float mean = s1 * (1.0f / 1024.0f);
    float var = s2 * (1.0f / 1024.0f) - mean * mean;
    float rstd = rsqrtf(var + 1e-5f);
    float4 gv = *(const float4*)(gg + tid * 4);
    float4 bv = *(const float4*)(bb + tid * 4);
    float y0 = (x.x - mean) * rstd * gv.x + bv.x;
    float y1 = (x.y - mean) * rstd * gv.y + bv.y;
    float y2 = (x.z - mean) * rstd * gv.z + bv.z;
    float y3 = (x.w - mean) * rstd * gv.w + bv.w;
    if constexpr (MODE & 2) {
        float o0 = y0, o1 = y1, o2 = y2, o3 = y3;
        if constexpr (MODE & 8) {
            float4 p = *(const float4*)(post + base);
            o0 += p.x; o1 += p.y; o2 += p.z; o3 += p.w;
        }
        float4 o; o.x = o0; o.y = o1; o.z = o2; o.w = o3;
        *(float4*)(of + base) = o;
    }
    if constexpr (MODE & 4) {
        uint2 pk;
        pk.x = (u32)f2b(y0) | ((u32)f2b(y1) << 16);
        pk.y = (u32)f2b(y2) | ((u32)f2b(y3) << 16);
        *(uint2*)(ob + base) = pk;
    }
}

// ---------------- dual LayerNorm: two independent MODE-4 LNs in one launch ----------------
__global__ __launch_bounds__(256) void ln2x_k(const float* __restrict__ inA, const float* __restrict__ gA,
                                              const float* __restrict__ bA, u16* __restrict__ obA,
                                              const float* __restrict__ inB, const float* __restrict__ gB,
                                              const float* __restrict__ bB, u16* __restrict__ obB) {
    int sel = blockIdx.x >> 13;
    int row = blockIdx.x & 8191;
    const float* in1 = sel ? inB : inA;
    const float* gg = sel ? gB : gA;
    const float* bb = sel ? bB : bA;
    u16* ob = sel ? obB : obA;
    int tid = threadIdx.x;
    size_t base = (size_t)row * 1024 + tid * 4;
    float4 x = *(const float4*)(in1 + base);
    float s1 = x.x + x.y + x.z + x.w;
    float s2 = x.x * x.x + x.y * x.y + x.z * x.z + x.w * x.w;
#pragma unroll
    for (int m = 32; m >= 1; m >>= 1) { s1 += __shfl_xor(s1, m); s2 += __shfl_xor(s2, m); }
    __shared__ float r1[4], r2[4];
    int lane = tid & 63, w = tid >> 6;
    if (lane == 0) { r1[w] = s1; r2[w] = s2; }
    __syncthreads();
    s1 = r1[0] + r1[1] + r1[2] + r1[3];
    s2 = r2[0] + r2[1] + r2[2] + r2[3];
    float mean = s1 * (1.0f / 1024.0f);
    float var = s2 * (1.0f / 1024.0f) - mean * mean;
    float rstd = rsqrtf(var + 1e-5f);
    float4 gv = *(const float4*)(gg + tid * 4);
    float4 bv = *(const float4*)(bb + tid * 4);
    uint2 pk;
    pk.x = pk2((x.x - mean) * rstd * gv.x + bv.x, (x.y - mean) * rstd * gv.y + bv.y);
    pk.y = pk2((x.z - mean) * rstd * gv.z + bv.z, (x.w - mean) * rstd * gv.w + bv.w);
    *(uint2*)(ob + base) = pk;
}

// ---------------- bf16 GEMM v512 (phase-split) + fused V-transpose epilogue (LDS-staged) ----------------
template <int EPI, int NBN, int VSEG>
__global__ __launch_bounds__(512) void gemm512_k(const u16* __restrict__ A, int lda,
                                                 const u16* __restrict__ WT,
                                                 const float* __restrict__ b0, const float* __restrict__ b1,
                                                 const float* __restrict__ b2,
                                                 float sc0, float sc1, float sc2,
                                                 const float* __restrict__ res,
                                                 void* __restrict__ outp, int ldc,
                                                 u16* __restrict__ vt) {
    constexpr int ASZ = 8192;
    constexpr int SLOT = ASZ + 4096;
    __shared__ u16 lds[3 * SLOT];
    u16* ldsb = &lds[0];

    int id = blockIdx.x;
    constexpr int NWG = 32 * NBN;
    constexpr int CPX = NWG / 8;
    int swz = (id & 7) * CPX + (id >> 3);   // XCD-contiguous bijective remap
    int bm = swz / NBN, bn = swz % NBN;
    const int m0 = bm * 256, n0 = bn * 128;
    int tid = threadIdx.x, lane = tid & 63, w = tid >> 6;
    int col = lane & 15, fg = lane >> 4;
    int wr = w >> 1, wc = w & 1;

    int swzL = ((col * 32) + fg * 8) ^ ((col >> 1) << 3);
    int aoff0 = wr * 64 * 32 + swzL;
    int boff0 = ASZ + wc * 64 * 32 + swzL;

    int r = tid >> 2, g = tid & 3;
    int gr = r ^ ((r >> 3) & 1);
    int gc = g ^ ((r >> 1) & 3);
    const u16* pA = A + (size_t)(m0 + gr) * lda + gc * 8;
    const u16* pB = WT + (size_t)(n0 + gr) * 1024 + gc * 8;

#define STGA(t2, snO)                                                                       \
    {                                                                                       \
        gload16(pA + (size_t)(t2) * 32, ldsb + (snO) + w * 512);                            \
        gload16(pA + (size_t)(t2) * 32 + (size_t)128 * lda, ldsb + (snO) + 4096 + w * 512); \
    }
#define STGB(t2, snO)                                                   \
    {                                                                   \
        gload16(pB + (size_t)(t2) * 32, ldsb + (snO) + ASZ + w * 512);  \
    }

    f32x4 acc[4][4];
#pragma unroll
    for (int m = 0; m < 4; m++)
#pragma unroll
        for (int n = 0; n < 4; n++) acc[m][n] = (f32x4){0.f, 0.f, 0.f, 0.f};

    STGA(0, 0); STGB(0, 0);
    STGA(1, SLOT); STGB(1, SLOT);
    WAITV(3);
    BAR();

    int sc = 0, sn = 2;
    for (int t = 0; t < 32; ++t) {
        int sCur = sc * SLOT, sNxt = sn * SLOT;
        // ---- phase 0: A-frags + first 2 B-frags, stage A of t+2, 8 MFMA ----
        bf16x8 a0[4], bfv[2];
#pragma unroll
        for (int m = 0; m < 4; m++) a0[m] = *(const bf16x8*)&ldsb[sCur + aoff0 + m * 512];
#pragma unroll
        for (int n = 0; n < 2; n++) bfv[n] = *(const bf16x8*)&ldsb[sCur + boff0 + n * 512];
        if (t < 30) STGA(t + 2, sNxt);
        BAR();
        __builtin_amdgcn_s_setprio(1);
#pragma unroll
        for (int m = 0; m < 4; m++)
#pragma unroll
            for (int n = 0; n < 2; n++) acc[m][n] = MFMA16(a0[m], bfv[n], acc[m][n]);
        __builtin_amdgcn_s_setprio(0);
        BAR();
        // ---- phase 1: last 2 B-frags, stage B of t+2, 8 MFMA, counted wait ----
        bf16x8 b2[2];
#pragma unroll
        for (int n = 0; n < 2; n++) b2[n] = *(const bf16x8*)&ldsb[sCur + boff0 + (n + 2) * 512];
        if (t < 30) STGB(t + 2, sNxt);
        BAR();
        __builtin_amdgcn_s_setprio(1);
#pragma unroll
        for (int m = 0; m < 4; m++)
#pragma unroll
            for (int n = 0; n < 2; n++) acc[m][n + 2] = MFMA16(a0[m], b2[n], acc[m][n + 2]);
        __builtin_amdgcn_s_setprio(0);
        if (t < 30) { WAITV(3); } else if (t == 30) { WAITV(0); }
        BAR();
        sc = (sc == 2) ? 0 : sc + 1;
        sn = (sn == 2) ? 0 : sn + 1;
    }
#undef STGA
#undef STGB

    int seg = n0 >> 10;
    const float* bp = (seg == 0) ? b0 : (seg == 1 ? b1 : b2);
    float sg = (seg == 0) ? sc0 : (seg == 1 ? sc1 : sc2);
    int nseg = n0 & 1023;
    float bv[4];
#pragma unroll
    for (int n = 0; n < 4; n++) bv[n] = bp[nseg + wc * 64 + n * 16 + col];

    if constexpr (VSEG >= 0) {
        if (seg == VSEG) {
            // V-transpose via LDS (ring is dead): tile [128 ch][264 pad] u16 = 67584 B.
            // Write acc transposed (<=2-way bank conflicts), BAR, 8 coalesced 16B-store passes.
            int chl = wc * 64 + col;
            int keyl = wr * 64 + fg * 4;
#pragma unroll
            for (int m = 0; m < 4; m++)
#pragma unroll
                for (int n = 0; n < 4; n++) {
                    uint2 pk;
                    pk.x = pk2(acc[m][n][0] + bv[n], acc[m][n][1] + bv[n]);
                    pk.y = pk2(acc[m][n][2] + bv[n], acc[m][n][3] + bv[n]);
                    *(uint2*)&ldsb[(chl + n * 16) * 264 + keyl + m * 16] = pk;
                }
            BAR();
            int bidx = m0 >> 10;
            int keyg = m0 & 1023;
            int rowt = tid >> 5, cht = tid & 31;   // 16 ch-rows x 32 x 16B per pass
#pragma unroll
            for (int p = 0; p < 8; p++) {
                int ch = p * 16 + rowt;
                uint4 v4 = *(const uint4*)&ldsb[ch * 264 + cht * 8];
                *(uint4*)(vt + ((size_t)(bidx * 1024 + nseg + ch) << 10) + keyg + cht * 8) = v4;
            }
            return;
        }
    }
#pragma unroll
    for (int m = 0; m < 4; m++) {
#pragma unroll
        for (int rr = 0; rr < 4; rr++) {
            int row = m0 + wr * 64 + m * 16 + fg * 4 + rr;
#pragma unroll
            for (int n = 0; n < 4; n++) {
                int c = n0 + wc * 64 + n * 16 + col;
                size_t idx = (size_t)row * ldc + c;
                float v = (acc[m][n][rr] + bv[n]) * sg;
                if constexpr (EPI == 0) ((u16*)outp)[idx] = f2b(v);
                else if constexpr (EPI == 1) ((u16*)outp)[idx] = f2b(fmaxf(v, 0.f));
                else if constexpr (EPI == 2) ((float*)outp)[idx] = v + res[idx];
            }
        }
    }
}

// ---------------- bf16 GEMM v256b (merged — measured best for 4-wave): BM=128/BN=128 ----------------
// EPI: 0 = bias -> bf16 ; 1 = bias+relu -> bf16 ; 2 = bias + f32 res -> f32 ; 3 = bias + bf16 res -> f32
template <int EPI, int NBN>
__global__ __launch_bounds__(256) void gemm256_k(const u16* __restrict__ A, int lda,
                                                 const u16* __restrict__ WT,
                                                 const float* __restrict__ b0,
                                                 float sc0,
                                                 const void* __restrict__ res,
                                                 void* __restrict__ outp, int ldc) {
    constexpr int SLOT = 8192;
    __shared__ u16 lds[3 * SLOT];
    int id = blockIdx.x;
    constexpr int NWG = 64 * NBN;
    constexpr int CPX = NWG / 8;
    int swz = (id & 7) * CPX + (id >> 3);
    int bm = swz / NBN, bn = swz % NBN;
    const int m0 = bm * 128, n0 = bn * 128;
    int tid = threadIdx.x, lane = tid & 63, w = tid >> 6;
    int col = lane & 15, fg = lane >> 4;
    int wr = w >> 1, wc = w & 1;

    int swzL = ((col * 32) + fg * 8) ^ ((col >> 1) << 3);
    int aoff0 = wr * 64 * 32 + swzL;
    int boff0 = 4096 + wc * 64 * 32 + swzL;

    int r = tid >> 2, g = tid & 3;
    int gr = r ^ ((r >> 3) & 1);
    int gc = g ^ ((r >> 1) & 3);
    const u16* pA = A + (size_t)(m0 + gr) * lda + gc * 8;
    const u16* pB = WT + (size_t)(n0 + gr) * 1024 + gc * 8;

#define STG(t2, snO)                                                                              \
    {                                                                                             \
        gload16(pA + (size_t)(t2) * 32, lds + (snO) + w * 512);                                   \
        gload16(pA + (size_t)(t2) * 32 + (size_t)64 * lda, lds + (snO) + 2048 + w * 512);         \
        gload16(pB + (size_t)(t2) * 32, lds + (snO) + 4096 + w * 512);                            \
        gload16(pB + (size_t)(t2) * 32 + (size_t)64 * 1024, lds + (snO) + 4096 + 2048 + w * 512); \
    }

    f32x4 acc[4][4];
#pragma unroll
    for (int m = 0; m < 4; m++)
#pragma unroll
        for (int n = 0; n < 4; n++) acc[m][n] = (f32x4){0.f, 0.f, 0.f, 0.f};

    STG(0, 0);
    STG(1, SLOT);
    WAITV(4);
    BAR();

    int sc = 0, sn = 2;
    for (int t = 0; t < 32; ++t) {
        int sCur = sc * SLOT, sNxt = sn * SLOT;
        bf16x8 a0[4], bfv[4];
#pragma unroll
        for (int m = 0; m < 4; m++) a0[m] = *(const bf16x8*)&lds[sCur + aoff0 + m * 512];
#pragma unroll
        for (int n = 0; n < 4; n++) bfv[n] = *(const bf16x8*)&lds[sCur + boff0 + n * 512];
        if (t < 30) STG(t + 2, sNxt);
        BAR();
        __builtin_amdgcn_s_setprio(1);
#pragma unroll
        for (int m = 0; m < 4; m++)
#pragma unroll
            for (int n = 0; n < 4; n++) acc[m][n] = MFMA16(a0[m], bfv[n], acc[m][n]);
        __builtin_amdgcn_s_setprio(0);
        if (t < 30) { WAITV(4); } else if (t == 30) { WAITV(0); }
        BAR();
        sc = (sc == 2) ? 0 : sc + 1;
        sn = (sn == 2) ? 0 : sn + 1;
    }
#undef STG

    float bv[4];
#pragma unroll
    for (int n = 0; n < 4; n++) bv[n] = b0[(n0 & 1023) + wc * 64 + n * 16 + col];
#pragma unroll
    for (int m = 0; m < 4; m++) {
#pragma unroll
        for (int rr = 0; rr < 4; rr++) {
            int row = m0 + wr * 64 + m * 16 + fg * 4 + rr;
#pragma unroll
            for (int n = 0; n < 4; n++) {
                int c = n0 + wc * 64 + n * 16 + col;
                size_t idx = (size_t)row * ldc + c;
                float v = (acc[m][n][rr] + bv[n]) * sc0;
                if constexpr (EPI == 0) ((u16*)outp)[idx] = f2b(v);
                else if constexpr (EPI == 1) ((u16*)outp)[idx] = f2b(fmaxf(v, 0.f));
                else if constexpr (EPI == 2) ((float*)outp)[idx] = v + ((const float*)res)[idx];
                else if constexpr (EPI == 3) ((float*)outp)[idx] = v + b2f(((const u16*)res)[idx]);
            }
        }
    }
}

// ---------------- flash attention v5 (r9-best, exact): 8 waves share KVBLK=64 staging; no-max softmax ----------------
__global__ __launch_bounds__(512) void attn_k(const u16* __restrict__ Q, int ldq,
                                              const u16* __restrict__ Kc, int ldk,
                                              const u16* __restrict__ VT,   // [(b*16+h)*64+dh][1024]
                                              const int* __restrict__ mask,
                                              u16* __restrict__ O, int ldo) {
    const int S = 1024;
    int gid = blockIdx.x;
    int bq = gid >> 7, hh = (gid >> 3) & 15, bb = gid & 7;
    int tid = threadIdx.x, lane = tid & 63, w = tid >> 6;   // w 0..7
    int q = lane & 31, hl = lane >> 5;
    int q0w = bq * 256 + w * 32;

    __shared__ u16 sm[18432];   // 36864 B: [buf][ K 64x72 | V^T 64x72 ]
#define KT(b, r, c) sm[(b) * 9216 + (r) * 72 + (c)]
#define VTL(b, r, c) sm[(b) * 9216 + 4608 + (r) * 72 + (c)]

    const u16* Qrow = Q + ((size_t)bb * S + q0w + q) * ldq + hh * 64;
    bool mneg = (mask[bb * S + q0w + q] == 0);
    bf16x8 qf[4];
#pragma unroll
    for (int c = 0; c < 4; c++) {
        qf[c] = *(const bf16x8*)(Qrow + c * 16 + hl * 8);
        if (mneg) qf[c] = (bf16x8)(__bf16)0.f;   // -> sc==0 -> p==1 (uniform)
    }

    float l = 0.f;
    f32x16 oa[2];
#pragma unroll
    for (int i = 0; i < 16; i++) { oa[0][i] = 0.f; oa[1][i] = 0.f; }

    int kk = tid >> 3, ks = tid & 7;
    const u16* gK = Kc + ((size_t)bb * S + kk) * ldk + hh * 64 + ks * 8;
    const u16* gVT = VT + ((size_t)(bb * 16 + hh) * 64 + kk) * 1024 + ks * 8;
    uint4 kr0, vr0;

#define LOADT(t)                                              \
    {                                                         \
        kr0 = *(const uint4*)(gK + (size_t)(t) * 64 * ldk);   \
        vr0 = *(const uint4*)(gVT + (size_t)(t) * 64);        \
    }
#define STORET(bf)                            \
    {                                         \
        *(uint4*)&KT(bf, kk, ks * 8) = kr0;   \
        *(uint4*)&VTL(bf, kk, ks * 8) = vr0;  \
    }

    LOADT(0);
    STORET(0);

    for (int t = 0; t < 16; ++t) {
        int cur = t & 1;
        if (t < 15) LOADT(t + 1);
        __syncthreads();

        f32x16 sc[2];
#pragma unroll
        for (int i = 0; i < 16; i++) { sc[0][i] = 0.f; sc[1][i] = 0.f; }
        __builtin_amdgcn_s_setprio(1);
#pragma unroll
        for (int st = 0; st < 2; st++)
#pragma unroll
            for (int c = 0; c < 4; c++) {
                bf16x8 kf = *(const bf16x8*)&KT(cur, st * 32 + q, c * 16 + hl * 8);
                sc[st] = MFMA32(kf, qf[c], sc[st]);
            }
        __builtin_amdgcn_s_setprio(0);

#pragma unroll
        for (int st = 0; st < 2; st++)
#pragma unroll
            for (int rr = 0; rr < 16; rr++) sc[st][rr] = exp2f(sc[st][rr]);
        float ts[8];
#pragma unroll
        for (int i = 0; i < 8; i++)
            ts[i] = (sc[0][i] + sc[0][i + 8]) + (sc[1][i] + sc[1][i + 8]);
#pragma unroll
        for (int i = 0; i < 4; i++) ts[i] += ts[i + 4];
        l += (ts[0] + ts[2]) + (ts[1] + ts[3]);

        __builtin_amdgcn_s_setprio(1);
#pragma unroll
        for (int st = 0; st < 2; st++) {
            u32 wv[8];
#pragma unroll
            for (int j = 0; j < 8; j++) wv[j] = pk2(sc[st][2 * j], sc[st][2 * j + 1]);
            PLSWAP(wv[0], wv[2]); PLSWAP(wv[1], wv[3]);
            PLSWAP(wv[4], wv[6]); PLSWAP(wv[5], wv[7]);
#pragma unroll
            for (int c = 0; c < 2; c++) {
                union { u32 u[4]; bf16x8 v; } pb;
                pb.u[0] = wv[c * 4 + 0]; pb.u[1] = wv[c * 4 + 1];
                pb.u[2] = wv[c * 4 + 2]; pb.u[3] = wv[c * 4 + 3];
#pragma unroll
                for (int dd = 0; dd < 2; dd++) {
                    bf16x8 vf = *(const bf16x8*)&VTL(cur, dd * 32 + q, st * 32 + c * 16 + hl * 8);
                    oa[dd] = MFMA32(vf, pb.v, oa[dd]);
                }
            }
        }
        __builtin_amdgcn_s_setprio(0);

        if (t < 15) STORET(cur ^ 1);
    }

    l += __shfl_xor(l, 32);
    __syncthreads();
    float inv = 1.0f / l;
    u16* otw = sm + w * 2304;
#pragma unroll
    for (int dd = 0; dd < 2; dd++)
#pragma unroll
        for (int rr = 0; rr < 16; rr++) {
            int d = (rr & 3) + 8 * (rr >> 2) + 4 * hl + 32 * dd;
            otw[q * 72 + d] = f2b(oa[dd][rr] * inv);
        }
    __syncthreads();
    size_t obase = ((size_t)bb * S + q0w) * ldo + hh * 64;
#pragma unroll
    for (int i = 0; i < 4; i++) {
        int row = i * 8 + (lane >> 3);
        uint4 vdat = *(const uint4*)&otw[row * 72 + (lane & 7) * 8];
        *(uint4*)(O + obase + (size_t)row * ldo + (lane & 7) * 8) = vdat;
    }
#undef KT
#undef VTL
#undef LOADT
#undef STORET
}

extern "C" void kernel_launch(void* const* d_in, const int* in_sizes, int n_in,
                              void* d_out, int out_size, void* d_ws, size_t ws_size,
                              hipStream_t stream) {
    (void)in_sizes; (void)n_in; (void)out_size; (void)ws_size;
    const float* x = (const float*)d_in[0];
    const float* h = (const float*)d_in[1];
    const int* mask = (const int*)d_in[2];
    const float* W[10];
    const float* Bv[10];
    for (int i = 0; i < 10; i++) { W[i] = (const float*)d_in[3 + i]; Bv[i] = (const float*)d_in[13 + i]; }
    const float *ln1g = (const float*)d_in[23], *ln1b = (const float*)d_in[24];
    const float *ln2g = (const float*)d_in[25], *ln2b = (const float*)d_in[26];
    const float *ln3g = (const float*)d_in[27], *ln3b = (const float*)d_in[28];
    const float *lnhg = (const float*)d_in[29], *lnhb = (const float*)d_in[30];
    const float *flng = (const float*)d_in[31], *flnb = (const float*)d_in[32];

    const float SCLE = 0.18033688011112042f;   // log2(e)/sqrt(64)

    char* ws = (char*)d_ws;
    size_t off = 0;
    auto alloc = [&](size_t bytes) -> char* {
        char* p = ws + off;
        off += (bytes + 255) & ~(size_t)255;
        return p;
    };
    const size_t MT = (size_t)8192 * 1024;
    u16* wtb = (u16*)alloc((size_t)10 * 1048576 * 2);
    u16* wt[10];
    for (int i = 0; i < 10; i++) wt[i] = wtb + (size_t)i * 1048576;
    u16* qkv = (u16*)alloc((size_t)8192 * 3072 * 2);   // sa QK(+dead V cols); later ca kv + ff1
    u16* kv = qkv;
    u16* kb = qkv + (size_t)8192 * 2048;
    u16* bufA = (u16*)alloc(MT * 2);
    u16* qb   = (u16*)alloc(MT * 2);          // ca Q, then ca attention out
    float* hid_in  = (float*)alloc(MT * 4);
    float* hid_mid = (float*)alloc(MT * 4);
    float* yf      = (float*)alloc(MT * 4);
    u16* hn = (u16*)yf;                        // hn lifetime disjoint from FFN
    u16* vtb = (u16*)hid_mid;                  // V^T buffer: hid_mid free until ca-WO gemm
    float* outF = (float*)d_out;

    W10 wp;
    for (int i = 0; i < 10; i++) wp.p[i] = W[i];
    tcvt_k<<<dim3(32, 32, 10), dim3(32, 8), 0, stream>>>(wp, wtb);

    // ---- self-attention block ----
    ln_k<4><<<8192, 256, 0, stream>>>(x, nullptr, ln1g, ln1b, nullptr, nullptr, bufA);
    gemm512_k<0, 24, 2><<<768, 512, 0, stream>>>(bufA, 1024, wt[0], Bv[0], Bv[1], Bv[2], SCLE, 1.f, 1.f, nullptr, qkv, 3072, vtb);
    attn_k<<<512, 512, 0, stream>>>(qkv, 3072, qkv + 1024, 3072, vtb, mask, qkv, 3072);
    gemm256_k<2, 8><<<512, 256, 0, stream>>>(qkv, 3072, wt[3], Bv[3], 1.f, x, hid_in, 1024);

    // ---- cross-attention block ----
    ln2x_k<<<16384, 256, 0, stream>>>(hid_in, ln2g, ln2b, bufA, h, lnhg, lnhb, hn);
    gemm256_k<0, 8><<<512, 256, 0, stream>>>(bufA, 1024, wt[4], Bv[4], SCLE, nullptr, qb, 1024);
    gemm512_k<0, 16, 1><<<512, 512, 0, stream>>>(hn, 1024, wt[5], Bv[5], Bv[6], Bv[6], 1.f, 1.f, 1.f, nullptr, kv, 2048, vtb);
    attn_k<<<512, 512, 0, stream>>>(qb, 1024, kv, 2048, vtb, mask, qb, 1024);
    gemm256_k<2, 8><<<512, 256, 0, stream>>>(qb, 1024, wt[7], Bv[7], 1.f, hid_in, hid_mid, 1024);

    // ---- FFN block ----
    // y stored once as bf16 (bufA); reused as ff1 input AND ff2's residual (bf16 round of y).
    ln_k<4><<<8192, 256, 0, stream>>>(hid_mid, nullptr, ln3g, ln3b, nullptr, nullptr, bufA);
    gemm256_k<1, 8><<<512, 256, 0, stream>>>(bufA, 1024, wt[8], Bv[8], 1.f, nullptr, kb, 1024);
    gemm256_k<3, 8><<<512, 256, 0, stream>>>(kb, 1024, wt[9], Bv[9], 1.f, bufA, hid_in, 1024);
    ln_k<10><<<8192, 256, 0, stream>>>(hid_in, nullptr, flng, flnb, hid_mid, outF, nullptr);
}